// Round 7
// baseline (360.701 us; speedup 1.0000x reference)
//
#include <hip/hip_runtime.h>
#include <hip/hip_bf16.h>
#include <math.h>

typedef __bf16 bf16;
typedef __bf16 bf16x8 __attribute__((ext_vector_type(8)));
typedef __bf16 bf16x4 __attribute__((ext_vector_type(4)));
typedef float  f32x4  __attribute__((ext_vector_type(4)));
typedef float  f32x16 __attribute__((ext_vector_type(16)));
typedef unsigned int u32x2 __attribute__((ext_vector_type(2)));

#define DEVI __device__ __forceinline__

DEVI void async16(bf16* lds, const bf16* g) {
    __builtin_amdgcn_global_load_lds(
        (const __attribute__((address_space(1))) unsigned int*)g,
        (__attribute__((address_space(3))) unsigned int*)lds, 16, 0, 0);
}
DEVI f32x4 mfma16(bf16x8 a, bf16x8 b, f32x4 c) {
    return __builtin_amdgcn_mfma_f32_16x16x32_bf16(a, b, c, 0, 0, 0);
}
DEVI f32x16 mfma32(bf16x8 a, bf16x8 b, f32x16 c) {
    return __builtin_amdgcn_mfma_f32_32x32x16_bf16(a, b, c, 0, 0, 0);
}
DEVI unsigned cvtpk(float lo, float hi) {
    unsigned r;
    asm("v_cvt_pk_bf16_f32 %0, %1, %2" : "=v"(r) : "v"(lo), "v"(hi));
    return r;
}
// v_permlane32_swap_b32: a' = [a.lo32, b.lo32], b' = [a.hi32, b.hi32]
DEVI void pl32(unsigned &a, unsigned &b) {
    u32x2 r = __builtin_amdgcn_permlane32_swap(a, b, false, false);
    a = r.x; b = r.y;
}
DEVI bf16x8 mk8(unsigned a0, unsigned a1, unsigned b0, unsigned b1) {
    union { unsigned u[4]; bf16x8 v; } U;
    U.u[0] = a0; U.u[1] = a1; U.u[2] = b0; U.u[3] = b1;
    return U.v;
}

// ---------------- fused prep: cvt_x + cvt_w + wo_t + bias_comb ----------------
__global__ __launch_bounds__(256) void prep(
    const float* __restrict__ x0, const float* __restrict__ x1, bf16* __restrict__ Xbf,
    const float* __restrict__ Wqk, const float* __restrict__ Wv,
    const float* __restrict__ Wf1, const float* __restrict__ Wf2,
    bf16* __restrict__ Wqkv, bf16* __restrict__ Wbig, bf16* __restrict__ Wf1Rb,
    bf16* __restrict__ Wf2b,
    const float* __restrict__ Wo, bf16* __restrict__ WoT,
    const float* __restrict__ bo, const float* __restrict__ bf1,
    float* __restrict__ bf1p)
{
    __shared__ float Ls[64][65];
    const int bid = blockIdx.x, t = threadIdx.x;
    if (bid < 8192) {
        long i = (long)bid * 256 + t;
        long r = i >> 7, c = (i & 127) * 4;
        const float* src = (r < 8192) ? (x0 + r * 512 + c) : (x1 + (r - 8192) * 512 + c);
        float4 v = *(const float4*)src;
        bf16x4 o;
        o[0] = (bf16)v.x; o[1] = (bf16)v.y; o[2] = (bf16)v.z; o[3] = (bf16)v.w;
        *(bf16x4*)(Xbf + r * 1024 + c) = o;
    } else if (bid < 10240) {
        long i = (long)(bid - 8192) * 256 + t;
        const float* s; bf16* d;
        if (i < 131072) {
            s = (i < 65536) ? Wqk + i * 4 : Wv + (i - 65536) * 4;
            d = Wqkv + i * 4;
        } else if (i < 393216) {
            long e = (i - 131072) * 4, r = e >> 10, c = e & 1023;
            s = Wf1 + e;
            d = (c < 512) ? (Wbig + r * 1024 + c) : (Wf1Rb + r * 512 + (c - 512));
        } else {
            s = Wf2 + (i - 393216) * 4;
            d = Wf2b + (i - 393216) * 4;
        }
        float4 v = *(const float4*)s;
        bf16x4 o;
        o[0] = (bf16)v.x; o[1] = (bf16)v.y; o[2] = (bf16)v.z; o[3] = (bf16)v.w;
        *(bf16x4*)d = o;
    } else if (bid < 10304) {
        const int bb = bid - 10240;
        const int bi = bb & 7, bj = bb >> 3;
        const int i0 = bi * 64, j0 = bj * 64;
        const int r0 = t >> 4, c4 = (t & 15) * 4;
#pragma unroll
        for (int it = 0; it < 4; it++) {
            int row = r0 + 16 * it;
            float4 v = *(const float4*)(Wo + (long)(i0 + row) * 512 + j0 + c4);
            Ls[row][c4] = v.x; Ls[row][c4 + 1] = v.y;
            Ls[row][c4 + 2] = v.z; Ls[row][c4 + 3] = v.w;
        }
        __syncthreads();
#pragma unroll
        for (int it = 0; it < 4; it++) {
            int orow = r0 + 16 * it;
            bf16x4 o;
#pragma unroll
            for (int k = 0; k < 4; k++) o[k] = (bf16)Ls[c4 + k][orow];
            *(bf16x4*)(WoT + (long)(j0 + orow) * 512 + i0 + c4) = o;
        }
    } else {
        const int w = t >> 6, lane = t & 63;
        const int row = (bid - 10304) * 4 + w;
        const float* rp = Wf1 + (long)row * 1024 + 512 + lane * 8;
        float4 a = *(const float4*)rp;
        float4 b = *(const float4*)(rp + 4);
        const float* bp = bo + lane * 8;
        float4 c = *(const float4*)bp;
        float4 d = *(const float4*)(bp + 4);
        float s = a.x * c.x + a.y * c.y + a.z * c.z + a.w * c.w +
                  b.x * d.x + b.y * d.y + b.z * d.z + b.w * d.w;
#pragma unroll
        for (int k = 1; k < 64; k <<= 1) s += __shfl_xor(s, k);
        if (lane == 0) bf1p[row] = bf1[row] + s;
    }
}

// ---------------- bf16 GEMM: C = A @ B^T, BK=64 swizzled (small/odd shapes) ----
template <int MODE>
__global__ __launch_bounds__(256) void gemm_bt(
    const bf16* __restrict__ A, long lda,
    const bf16* __restrict__ B, long ldb,
    const float* __restrict__ bias,
    void* __restrict__ Cout, long ldc,
    const float* __restrict__ res0, const float* __restrict__ res1,
    const float* __restrict__ bias2, void* __restrict__ Cout2,
    int M, int N, int K, float scale)
{
    __shared__ bf16 As[128 * 64];
    __shared__ bf16 Bs[128 * 64];
    const int t = threadIdx.x;
    const int w = t >> 6, lane = t & 63, quad = lane >> 4, m15 = lane & 15;
    const int wm = w >> 1, wn = w & 1;
    const int nbx = N >> 7;
    const int xcd = blockIdx.x & 7, local = blockIdx.x >> 3;
    const int mtiles_per_xcd = (int)(gridDim.x >> 3) / nbx;
    const int by = xcd * mtiles_per_xcd + local / nbx;
    const int bx = local % nbx;
    const long m0 = (long)by * 128, n0 = (long)bx * 128;

    f32x4 acc[4][4] = {};

    for (int k0 = 0; k0 < K; k0 += 64) {
#pragma unroll
        for (int i = 0; i < 4; i++) {
            int idx = i * 256 + t, row = idx >> 3, p = idx & 7;
            int gc = k0 + ((p ^ (row & 7)) * 8);
            async16(As + idx * 8, A + (m0 + row) * lda + gc);
            async16(Bs + idx * 8, B + (n0 + row) * ldb + gc);
        }
        __syncthreads();
#pragma unroll
        for (int kk = 0; kk < 2; kk++) {
            bf16x8 af[4], bfr[4];
#pragma unroll
            for (int mt = 0; mt < 4; mt++) {
                int row = wm * 64 + mt * 16 + m15;
                af[mt] = *(const bf16x8*)(As + row * 64 + (((kk * 4 + quad) ^ (row & 7)) * 8));
            }
#pragma unroll
            for (int nt = 0; nt < 4; nt++) {
                int row = wn * 64 + nt * 16 + m15;
                bfr[nt] = *(const bf16x8*)(Bs + row * 64 + (((kk * 4 + quad) ^ (row & 7)) * 8));
            }
#pragma unroll
            for (int mt = 0; mt < 4; mt++)
#pragma unroll
                for (int nt = 0; nt < 4; nt++)
                    acc[mt][nt] = mfma16(af[mt], bfr[nt], acc[mt][nt]);
        }
        __syncthreads();
    }

#pragma unroll
    for (int nt = 0; nt < 4; nt++) {
        long col = n0 + wn * 64 + nt * 16 + m15;
#pragma unroll
        for (int mt = 0; mt < 4; mt++) {
            long row = m0 + wm * 64 + mt * 16 + quad * 4;
            if (MODE == 0) {
                bf16* C = (bf16*)Cout;
                float bs = bias[col];
#pragma unroll
                for (int r = 0; r < 4; r++)
                    C[(row + r) * ldc + col] = (bf16)(acc[mt][nt][r] + bs);
            } else if (MODE == 4) {
                bf16* C = (bf16*)Cout;
#pragma unroll
                for (int r = 0; r < 4; r++)
                    C[(row + r) * ldc + col] = (bf16)acc[mt][nt][r];
            } else {  // MODE 1
                float* C = (float*)Cout;
                float bs = bias[col];
#pragma unroll
                for (int r = 0; r < 4; r++) {
                    long grow = row + r;
                    const float* rs = (grow < 8192) ? (res0 + grow * 512)
                                                    : (res1 + (grow - 8192) * 512);
                    C[grow * ldc + col] = acc[mt][nt][r] + bs + rs[col];
                }
            }
        }
    }
}

// ---------------- pipelined 256x256 GEMM: 2-tile-deep counted-vmcnt (T3/T4) ---
// 512 threads = 8 waves (2M x 4N), BM=BN=256, BK=64, LDS 128 KiB (2 slots).
// vmcnt(8) at entry: tile t resident, t+1 in flight. Grid 256, N%256==0.
template <int MODE>
__global__ __launch_bounds__(512, 2) void pipe_gemm(
    const bf16* __restrict__ A, long lda,
    const bf16* __restrict__ B, long ldb,
    const float* __restrict__ bias,
    void* __restrict__ Cout, long ldc,
    const float* __restrict__ bias2, void* __restrict__ Cout2,
    int M, int N, int K, float scale)
{
    __shared__ bf16 lds[65536];          // 128 KiB: As[2][16384] | Bs[2][16384]
    bf16* As = lds;
    bf16* Bs = lds + 32768;

    const int t = threadIdx.x;
    const int w = t >> 6, lane = t & 63, quad = lane >> 4, m15 = lane & 15;
    const int wm = w >> 2, wn = w & 3;
    const int nbx = N >> 8;
    const int xcd = blockIdx.x & 7, local = blockIdx.x >> 3;
    const int mtiles_per_xcd = (int)(gridDim.x >> 3) / nbx;
    const int by = xcd * mtiles_per_xcd + local / nbx;
    const int bx = local % nbx;
    const long m0 = (long)by * 256, n0 = (long)bx * 256;
    const int nt = K >> 6;

    f32x4 acc[8][4] = {};

    auto stage = [&](int kt) {
        const int slot = kt & 1;
        bf16* Ad = As + slot * 16384;
        bf16* Bd = Bs + slot * 16384;
        const int k0 = kt * 64;
#pragma unroll
        for (int i = 0; i < 4; i++) {
            int idx = i * 512 + t, row = idx >> 3, p = idx & 7;
            int gc = k0 + ((p ^ (row & 7)) * 8);
            async16(Ad + idx * 8, A + (m0 + row) * lda + gc);
        }
#pragma unroll
        for (int i = 0; i < 4; i++) {
            int idx = i * 512 + t, row = idx >> 3, p = idx & 7;
            int gc = k0 + ((p ^ (row & 7)) * 8);
            async16(Bd + idx * 8, B + (n0 + row) * ldb + gc);
        }
    };

    stage(0);
    stage(1);

    for (int kt = 0; kt < nt; kt++) {
        if (kt + 1 < nt) {
            asm volatile("s_waitcnt vmcnt(8)" ::: "memory");
        } else {
            asm volatile("s_waitcnt vmcnt(0)" ::: "memory");
        }
        __builtin_amdgcn_s_barrier();
        __builtin_amdgcn_sched_barrier(0);

        const bf16* Asl = As + (kt & 1) * 16384;
        const bf16* Bsl = Bs + (kt & 1) * 16384;
#pragma unroll
        for (int ksub = 0; ksub < 2; ksub++) {
            bf16x8 af[8], bfr[4];
#pragma unroll
            for (int mf = 0; mf < 8; mf++) {
                int row = wm * 128 + mf * 16 + m15;
                af[mf] = *(const bf16x8*)(Asl + row * 64 + (((ksub * 4 + quad) ^ (row & 7)) * 8));
            }
#pragma unroll
            for (int nf = 0; nf < 4; nf++) {
                int row = wn * 64 + nf * 16 + m15;
                bfr[nf] = *(const bf16x8*)(Bsl + row * 64 + (((ksub * 4 + quad) ^ (row & 7)) * 8));
            }
            __builtin_amdgcn_s_setprio(1);
#pragma unroll
            for (int mf = 0; mf < 8; mf++)
#pragma unroll
                for (int nf = 0; nf < 4; nf++)
                    acc[mf][nf] = mfma16(af[mf], bfr[nf], acc[mf][nf]);
            __builtin_amdgcn_s_setprio(0);
        }

        __builtin_amdgcn_sched_barrier(0);
        __builtin_amdgcn_s_barrier();
        __builtin_amdgcn_sched_barrier(0);
        if (kt + 2 < nt) stage(kt + 2);
    }

#pragma unroll
    for (int nf = 0; nf < 4; nf++) {
        long col = n0 + wn * 64 + nf * 16 + m15;
#pragma unroll
        for (int mf = 0; mf < 8; mf++) {
            long row = m0 + wm * 128 + mf * 16 + quad * 4;
            if (MODE == 0) {
                bf16* C = (bf16*)Cout;
                float bs = bias[col];
#pragma unroll
                for (int r = 0; r < 4; r++)
                    C[(row + r) * ldc + col] = (bf16)(acc[mf][nf][r] + bs);
            } else {  // MODE 5
                if (col < 512) {
                    bf16* C = (bf16*)Cout;
                    float bs = bias[col];
#pragma unroll
                    for (int r = 0; r < 4; r++)
                        C[(row + r) * ldc + col] = (bf16)((acc[mf][nf][r] + bs) * scale);
                } else {
                    bf16* V = (bf16*)Cout2;
                    long v = col - 512;
                    float bs = bias2[v];
                    bf16x4 pv;
#pragma unroll
                    for (int r = 0; r < 4; r++) pv[r] = (bf16)(acc[mf][nf][r] + bs);
                    *(bf16x4*)(V + v * 16384 + row) = pv;
                }
            }
        }
    }
}

// ---------------- pipelined FFN2: BM=128 BN=256, fp32 out + residual ----------
// 512 threads = 8 waves (2M x 4N), LDS 96 KiB. Grid 256 = 1 block/CU.
// vmcnt(6) counted waits (stage = 2 A-loads + 4 B-loads per thread).
__global__ __launch_bounds__(512, 2) void pipe_ffn2(
    const bf16* __restrict__ A, long lda,
    const bf16* __restrict__ B, long ldb,
    const float* __restrict__ bias,
    float* __restrict__ C, long ldc,
    const float* __restrict__ res0, const float* __restrict__ res1,
    int M, int N, int K)
{
    __shared__ bf16 lds[49152];          // 96 KiB: As[2][8192] | Bs[2][16384]
    bf16* As = lds;                      // 128 x 64 per slot
    bf16* Bs = lds + 16384;              // 256 x 64 per slot

    const int t = threadIdx.x;
    const int w = t >> 6, lane = t & 63, quad = lane >> 4, m15 = lane & 15;
    const int wm = w >> 2, wn = w & 3;
    const int nbx = N >> 8;              // 2
    const int xcd = blockIdx.x & 7, local = blockIdx.x >> 3;
    const int mtiles_per_xcd = (int)(gridDim.x >> 3) / nbx;
    const int by = xcd * mtiles_per_xcd + local / nbx;
    const int bx = local % nbx;
    const long m0 = (long)by * 128, n0 = (long)bx * 256;
    const int nt = K >> 6;

    f32x4 acc[4][4] = {};

    auto stage = [&](int kt) {
        const int slot = kt & 1;
        bf16* Ad = As + slot * 8192;
        bf16* Bd = Bs + slot * 16384;
        const int k0 = kt * 64;
#pragma unroll
        for (int i = 0; i < 2; i++) {
            int idx = i * 512 + t, row = idx >> 3, p = idx & 7;
            int gc = k0 + ((p ^ (row & 7)) * 8);
            async16(Ad + idx * 8, A + (m0 + row) * lda + gc);
        }
#pragma unroll
        for (int i = 0; i < 4; i++) {
            int idx = i * 512 + t, row = idx >> 3, p = idx & 7;
            int gc = k0 + ((p ^ (row & 7)) * 8);
            async16(Bd + idx * 8, B + (n0 + row) * ldb + gc);
        }
    };

    stage(0);
    stage(1);

    for (int kt = 0; kt < nt; kt++) {
        if (kt + 1 < nt) {
            asm volatile("s_waitcnt vmcnt(6)" ::: "memory");
        } else {
            asm volatile("s_waitcnt vmcnt(0)" ::: "memory");
        }
        __builtin_amdgcn_s_barrier();
        __builtin_amdgcn_sched_barrier(0);

        const bf16* Asl = As + (kt & 1) * 8192;
        const bf16* Bsl = Bs + (kt & 1) * 16384;
#pragma unroll
        for (int ksub = 0; ksub < 2; ksub++) {
            bf16x8 af[4], bfr[4];
#pragma unroll
            for (int mf = 0; mf < 4; mf++) {
                int row = wm * 64 + mf * 16 + m15;
                af[mf] = *(const bf16x8*)(Asl + row * 64 + (((ksub * 4 + quad) ^ (row & 7)) * 8));
            }
#pragma unroll
            for (int nf = 0; nf < 4; nf++) {
                int row = wn * 64 + nf * 16 + m15;
                bfr[nf] = *(const bf16x8*)(Bsl + row * 64 + (((ksub * 4 + quad) ^ (row & 7)) * 8));
            }
            __builtin_amdgcn_s_setprio(1);
#pragma unroll
            for (int mf = 0; mf < 4; mf++)
#pragma unroll
                for (int nf = 0; nf < 4; nf++)
                    acc[mf][nf] = mfma16(af[mf], bfr[nf], acc[mf][nf]);
            __builtin_amdgcn_s_setprio(0);
        }

        __builtin_amdgcn_sched_barrier(0);
        __builtin_amdgcn_s_barrier();
        __builtin_amdgcn_sched_barrier(0);
        if (kt + 2 < nt) stage(kt + 2);
    }

#pragma unroll
    for (int nf = 0; nf < 4; nf++) {
        long col = n0 + wn * 64 + nf * 16 + m15;
        float bs = bias[col];
#pragma unroll
        for (int mf = 0; mf < 4; mf++) {
            long row = m0 + wm * 64 + mf * 16 + quad * 4;
#pragma unroll
            for (int r = 0; r < 4; r++) {
                long grow = row + r;
                const float* rs = (grow < 8192) ? (res0 + grow * 512)
                                                : (res1 + (grow - 8192) * 512);
                C[grow * ldc + col] = acc[mf][nf][r] + bs + rs[col];
            }
        }
    }
}

// ---------------- flash attention: 32x32 MFMA, in-reg P, T15 deferred SM ------
// QK: [16384][512] bf16, pre-scaled by sqrt((1/8)*log2(e)). VT: [512][16384] bf16.
// o:  [16384][1024] bf16 (head cols into concat right half).
// 4 waves x 32 q, 128 q/block, 64 keys/iter in two 32-key subtiles.
// T15: softmax+PV of subtile B deferred into next iter -> overlaps next QK^T.
// V TRIPLE-buffered (slots kb%3): deferred PV reads V(kb-1)=slot (kb+2)%3,
// staging writes V(kb+1)=slot (kb+1)%3, current PV reads slot kb%3 - disjoint.
// LDS 40 KiB: K dbuf 2x8K | V tbuf 3x8K -> 4 blocks/CU.
__global__ __launch_bounds__(256, 4) void flash_attn(const bf16* __restrict__ QK,
                                                     const bf16* __restrict__ VT,
                                                     bf16* __restrict__ o)
{
    __shared__ bf16 lds[20480];          // 40 KiB
    bf16* Ks = lds;                      // 2 slots x 4096 bf16
    bf16* Vs = lds + 8192;               // 3 slots x 4096 bf16

    const int t = threadIdx.x, w = t >> 6, lane = t & 63;
    const int l31 = lane & 31, hi = lane >> 5;
    const int j = blockIdx.x;
    const int hs = j & 63;               // head-set id (shares K/V)
    const int qt = j >> 6;               // 0..15 q-tile
    const int h = hs & 7, b = (hs >> 3) & 3, dir = hs >> 5;
    const long qrow0  = (long)dir * 8192 + b * 2048 + qt * 128;
    const long kvrow0 = (long)(1 - dir) * 8192 + b * 2048;
    const int hc = h * 64;

    // ---- Q stage: 128 rows x 64 d = 16KB into K-area ----
#pragma unroll
    for (int i = 0; i < 4; i++) {
        int idx = i * 256 + t, row = idx >> 3, p = idx & 7;
        async16(lds + idx * 8, QK + (qrow0 + row) * 512 + hc + ((p ^ (row & 7)) * 8));
    }
    __syncthreads();
    bf16x8 qf[4];
    {
        int qrow = w * 32 + l31;
#pragma unroll
        for (int kd = 0; kd < 4; kd++)
            qf[kd] = *(const bf16x8*)(lds + qrow * 64 + (((kd * 2 + hi) ^ (qrow & 7)) * 8));
    }
    __syncthreads();  // all Q reads done before K/V loads overwrite

    // ---- prologue: K(0) -> K slot0, V(0) -> V slot0 ----
#pragma unroll
    for (int i = 0; i < 2; i++) {
        int idx = i * 256 + t, row = idx >> 3, p = idx & 7;
        async16(Ks + idx * 8, QK + (kvrow0 + row) * 512 + hc + ((p ^ (row & 7)) * 8));
    }
#pragma unroll
    for (int i = 0; i < 2; i++) {
        int idx = i * 256 + t, row = idx >> 3, p = idx & 7;
        async16(Vs + idx * 8, VT + (long)(hc + row) * 16384 + kvrow0 + ((p ^ (row & 7)) * 8));
    }

    f32x16 oacc[2] = {};
    f32x16 racc = {};
    f32x16 sP = {};
    bf16x8 ones;
#pragma unroll
    for (int k2 = 0; k2 < 8; k2++) ones[k2] = (bf16)1.0f;

    // softmax + PV of one 32-key subtile (ksbase: 0 = subtile A, 2 = subtile B)
    auto SM_PV = [&](f32x16 &s, const bf16* Vb, int ksbase) {
#pragma unroll
        for (int r = 0; r < 16; r++) s[r] = exp2f(s[r]);
#pragma unroll
        for (int sh = 0; sh < 2; sh++) {
            unsigned a0 = cvtpk(s[8 * sh + 0], s[8 * sh + 1]);
            unsigned a1 = cvtpk(s[8 * sh + 2], s[8 * sh + 3]);
            unsigned b0 = cvtpk(s[8 * sh + 4], s[8 * sh + 5]);
            unsigned b1 = cvtpk(s[8 * sh + 6], s[8 * sh + 7]);
            pl32(a0, b0); pl32(a1, b1);
            bf16x8 pa = mk8(a0, a1, b0, b1);
            const int ks = ksbase + sh;
            __builtin_amdgcn_s_setprio(1);
#pragma unroll
            for (int db = 0; db < 2; db++) {
                const int vrow = db * 32 + l31;
                bf16x8 vf = *(const bf16x8*)(Vb + vrow * 64 + (((ks * 2 + hi) ^ (vrow & 7)) * 8));
                oacc[db] = mfma32(pa, vf, oacc[db]);
            }
            racc = mfma32(pa, ones, racc);
            __builtin_amdgcn_s_setprio(0);
        }
    };

    for (int kb = 0; kb < 32; kb++) {
        bf16* Kc = Ks + (kb & 1) * 4096;
        bf16* Vc = Vs + (kb % 3) * 4096;
        const bf16* Vp = Vs + ((kb + 2) % 3) * 4096;   // V(kb-1)

        // entry: K(kb), V(kb) (staged during kb-1) resident everywhere
        asm volatile("s_waitcnt vmcnt(0)" ::: "memory");
        __builtin_amdgcn_s_barrier();

        if (kb < 31) {
            const long knext = kvrow0 + (kb + 1) * 64;
            bf16* Kn = Ks + ((kb + 1) & 1) * 4096;
            bf16* Vn = Vs + ((kb + 1) % 3) * 4096;
#pragma unroll
            for (int i = 0; i < 2; i++) {
                int idx = i * 256 + t, row = idx >> 3, p = idx & 7;
                async16(Kn + idx * 8, QK + (knext + row) * 512 + hc + ((p ^ (row & 7)) * 8));
            }
#pragma unroll
            for (int i = 0; i < 2; i++) {
                int idx = i * 256 + t, row = idx >> 3, p = idx & 7;
                async16(Vn + idx * 8, VT + (long)(hc + row) * 16384 + knext + ((p ^ (row & 7)) * 8));
            }
        }

        // ---- QK^T subtile A (keys 0..31 of this block) ----
        f32x16 sA = {};
        {
            const int krow = l31;
            const int ksw = krow & 7;
            bf16x8 kf0 = *(const bf16x8*)(Kc + krow * 64 + (((0 + hi) ^ ksw) * 8));
            bf16x8 kf1 = *(const bf16x8*)(Kc + krow * 64 + (((2 + hi) ^ ksw) * 8));
            bf16x8 kf2 = *(const bf16x8*)(Kc + krow * 64 + (((4 + hi) ^ ksw) * 8));
            bf16x8 kf3 = *(const bf16x8*)(Kc + krow * 64 + (((6 + hi) ^ ksw) * 8));
            __builtin_amdgcn_s_setprio(1);
            sA = mfma32(kf0, qf[0], sA);
            sA = mfma32(kf1, qf[1], sA);
            sA = mfma32(kf2, qf[2], sA);
            sA = mfma32(kf3, qf[3], sA);
            __builtin_amdgcn_s_setprio(0);
        }

        // ---- deferred softmax+PV of prev iter's subtile B (overlaps QK) ----
        if (kb > 0) SM_PV(sP, Vp, 2);

        // ---- QK^T subtile B (keys 32..63) ----
        f32x16 sB = {};
        {
            const int krow = 32 + l31;
            const int ksw = krow & 7;
            bf16x8 kf0 = *(const bf16x8*)(Kc + krow * 64 + (((0 + hi) ^ ksw) * 8));
            bf16x8 kf1 = *(const bf16x8*)(Kc + krow * 64 + (((2 + hi) ^ ksw) * 8));
            bf16x8 kf2 = *(const bf16x8*)(Kc + krow * 64 + (((4 + hi) ^ ksw) * 8));
            bf16x8 kf3 = *(const bf16x8*)(Kc + krow * 64 + (((6 + hi) ^ ksw) * 8));
            __builtin_amdgcn_s_setprio(1);
            sB = mfma32(kf0, qf[0], sB);
            sB = mfma32(kf1, qf[1], sB);
            sB = mfma32(kf2, qf[2], sB);
            sB = mfma32(kf3, qf[3], sB);
            __builtin_amdgcn_s_setprio(0);
        }

        // ---- softmax+PV of subtile A (current V) ----
        SM_PV(sA, Vc, 0);

        sP = sB;
    }
    // tail: kb=31 subtile B, V slot 31%3 = 1
    SM_PV(sP, Vs + 4096, 2);

    // ---- epilogue: O layout col=d=l31(+32db), row=q=(reg&3)+8*(reg>>2)+4*hi ----
#pragma unroll
    for (int reg = 0; reg < 16; reg++) {
        const int q = (reg & 3) + 8 * (reg >> 2) + 4 * hi;
        const float inv = 1.f / racc[reg];
        const long row = qrow0 + w * 32 + q;
#pragma unroll
        for (int db = 0; db < 2; db++)
            o[row * 1024 + hc + db * 32 + l31] = (bf16)(oacc[db][reg] * inv);
    }
}

// ---------------- LayerNorm + GELU (exact erf), in-place on bf16 [16384][1024]
__global__ __launch_bounds__(256) void ln_gelu(bf16* __restrict__ H,
                                               const float* __restrict__ g,
                                               const float* __restrict__ bta)
{
    const int row = blockIdx.x, t = threadIdx.x;
    const int w = t >> 6, lane = t & 63;
    bf16* hp = H + (long)row * 1024 + t * 4;
    bf16x4 hv = *(const bf16x4*)hp;
    float h[4];
#pragma unroll
    for (int j = 0; j < 4; j++) h[j] = (float)hv[j];
    float s1 = h[0] + h[1] + h[2] + h[3];
    float s2 = h[0] * h[0] + h[1] * h[1] + h[2] * h[2] + h[3] * h[3];
#pragma unroll
    for (int d = 1; d < 64; d <<= 1) {
        s1 += __shfl_xor(s1, d);
        s2 += __shfl_xor(s2, d);
    }
    __shared__ float rbuf[8];
    if (lane == 0) { rbuf[w] = s1; rbuf[4 + w] = s2; }
    __syncthreads();
    s1 = rbuf[0] + rbuf[1] + rbuf[2] + rbuf[3];
    s2 = rbuf[4] + rbuf[5] + rbuf[6] + rbuf[7];
    const float mu = s1 * (1.f / 1024.f);
    const float var = s2 * (1.f / 1024.f) - mu * mu;
    const float rstd = rsqrtf(var + 1e-5f);
    bf16x4 out;
#pragma unroll
    for (int j = 0; j < 4; j++) {
        int c = t * 4 + j;
        float x = (h[j] - mu) * rstd * g[c] + bta[c];
        float y = 0.5f * x * (1.f + erff(x * 0.70710678118654752f));
        out[j] = (bf16)y;
    }
    *(bf16x4*)hp = out;
}

extern "C" void kernel_launch(void* const* d_in, const int* in_sizes, int n_in,
                              void* d_out, int out_size, void* d_ws, size_t ws_size,
                              hipStream_t stream)
{
    const float* x0  = (const float*)d_in[0];
    const float* x1  = (const float*)d_in[1];
    const float* Wqk = (const float*)d_in[2];
    const float* bqk = (const float*)d_in[3];
    const float* Wv  = (const float*)d_in[4];
    const float* bv  = (const float*)d_in[5];
    const float* Wo  = (const float*)d_in[6];
    const float* bo  = (const float*)d_in[7];
    const float* Wf1 = (const float*)d_in[8];
    const float* bf1 = (const float*)d_in[9];
    const float* lng = (const float*)d_in[10];
    const float* lnb = (const float*)d_in[11];
    const float* Wf2 = (const float*)d_in[12];
    const float* bf2 = (const float*)d_in[13];

    char* ws = (char*)d_ws;
    bf16* Xbf   = (bf16*)ws; ws += 16384L * 1024 * 2;  // [x | m] both streams
    bf16* QKbf  = (bf16*)ws;                            // qk projection (pre-scaled)
    bf16* Hbuf  = (bf16*)ws;                            // FFN1 out (aliases QKbf+VtG)
    ws += 16384L * 512 * 2;
    bf16* VtG   = (bf16*)ws; ws += 16384L * 512 * 2;   // v proj transposed [512][16384]
    bf16* Wqkv  = (bf16*)ws; ws += 1024L * 512 * 2;    // [Wqk; Wv] bf16
    bf16* Wbig  = (bf16*)ws; ws += 1024L * 1024 * 2;   // [Wf1L | Wcomb]
    bf16* Wf1Rb = (bf16*)ws; ws += 1024L * 512 * 2;
    bf16* Wf2b  = (bf16*)ws; ws += 512L * 1024 * 2;
    bf16* WoT   = (bf16*)ws; ws += 512L * 512 * 2;
    float* bf1p = (float*)ws; ws += 1024 * 4;

    // sqrt((1/8) * log2(e)) — applied to both q and k so scores carry (1/8)*log2(e)
    const float qs = 0.42466090014400953f;

    prep<<<10560, 256, 0, stream>>>(x0, x1, Xbf, Wqk, Wv, Wf1, Wf2,
                                    Wqkv, Wbig, Wf1Rb, Wf2b, Wo, WoT, bo, bf1, bf1p);

    // Wcomb = Wf1R @ Wo -> Wbig right half  [1024,512] = Wf1Rb @ WoT^T
    gemm_bt<4><<<32, 256, 0, stream>>>(Wf1Rb, 512, WoT, 512, nullptr,
                                       Wbig + 512, 1024, nullptr, nullptr,
                                       nullptr, nullptr, 1024, 512, 512, 1.f);

    // fused QKV projection: [16384,1024] = Xbf @ Wqkv^T (pipelined 256x256)
    pipe_gemm<5><<<256, 512, 0, stream>>>(Xbf, 1024, Wqkv, 512, bqk,
                                          QKbf, 512, bv, VtG,
                                          16384, 1024, 512, qs);

    // cross attention -> writes m-heads directly into Xbf right half (ld 1024)
    flash_attn<<<1024, 256, 0, stream>>>(QKbf, VtG, Xbf + 512);

    // FFN1 (Wo folded): [16384,1024] = [x|O] @ [Wf1L|Wcomb]^T + bf1' (pipelined)
    pipe_gemm<0><<<256, 512, 0, stream>>>(Xbf, 1024, Wbig, 1024, bf1p,
                                          Hbuf, 1024, nullptr, nullptr,
                                          16384, 1024, 1024, 1.f);
    ln_gelu<<<16384, 256, 0, stream>>>(Hbuf, lng, lnb);
    // FFN2 + bias + residual -> d_out (fp32), pipelined BM=128 BN=256
    pipe_ffn2<<<256, 512, 0, stream>>>(Hbuf, 1024, Wf2b, 1024, bf2,
                                       (float*)d_out, 512, x0, x1,
                                       16384, 512, 1024);
}

// Round 8
// 358.982 us; speedup vs baseline: 1.0048x; 1.0048x over previous
//
#include <hip/hip_runtime.h>
#include <hip/hip_bf16.h>
#include <math.h>

typedef __bf16 bf16;
typedef __bf16 bf16x8 __attribute__((ext_vector_type(8)));
typedef __bf16 bf16x4 __attribute__((ext_vector_type(4)));
typedef float  f32x4  __attribute__((ext_vector_type(4)));
typedef float  f32x16 __attribute__((ext_vector_type(16)));
typedef unsigned int u32x2 __attribute__((ext_vector_type(2)));

#define DEVI __device__ __forceinline__

DEVI void async16(bf16* lds, const bf16* g) {
    __builtin_amdgcn_global_load_lds(
        (const __attribute__((address_space(1))) unsigned int*)g,
        (__attribute__((address_space(3))) unsigned int*)lds, 16, 0, 0);
}
DEVI f32x4 mfma16(bf16x8 a, bf16x8 b, f32x4 c) {
    return __builtin_amdgcn_mfma_f32_16x16x32_bf16(a, b, c, 0, 0, 0);
}
DEVI f32x16 mfma32(bf16x8 a, bf16x8 b, f32x16 c) {
    return __builtin_amdgcn_mfma_f32_32x32x16_bf16(a, b, c, 0, 0, 0);
}
DEVI unsigned cvtpk(float lo, float hi) {
    unsigned r;
    asm("v_cvt_pk_bf16_f32 %0, %1, %2" : "=v"(r) : "v"(lo), "v"(hi));
    return r;
}
// v_permlane32_swap_b32: a' = [a.lo32, b.lo32], b' = [a.hi32, b.hi32]
DEVI void pl32(unsigned &a, unsigned &b) {
    u32x2 r = __builtin_amdgcn_permlane32_swap(a, b, false, false);
    a = r.x; b = r.y;
}
DEVI bf16x8 mk8(unsigned a0, unsigned a1, unsigned b0, unsigned b1) {
    union { unsigned u[4]; bf16x8 v; } U;
    U.u[0] = a0; U.u[1] = a1; U.u[2] = b0; U.u[3] = b1;
    return U.v;
}

// ---------------- fused prep: cvt_x + cvt_w + wo_t + bias_comb ----------------
__global__ __launch_bounds__(256) void prep(
    const float* __restrict__ x0, const float* __restrict__ x1, bf16* __restrict__ Xbf,
    const float* __restrict__ Wqk, const float* __restrict__ Wv,
    const float* __restrict__ Wf1, const float* __restrict__ Wf2,
    bf16* __restrict__ Wqkv, bf16* __restrict__ Wbig, bf16* __restrict__ Wf1Rb,
    bf16* __restrict__ Wf2b,
    const float* __restrict__ Wo, bf16* __restrict__ WoT,
    const float* __restrict__ bo, const float* __restrict__ bf1,
    float* __restrict__ bf1p)
{
    __shared__ float Ls[64][65];
    const int bid = blockIdx.x, t = threadIdx.x;
    if (bid < 8192) {
        long i = (long)bid * 256 + t;
        long r = i >> 7, c = (i & 127) * 4;
        const float* src = (r < 8192) ? (x0 + r * 512 + c) : (x1 + (r - 8192) * 512 + c);
        float4 v = *(const float4*)src;
        bf16x4 o;
        o[0] = (bf16)v.x; o[1] = (bf16)v.y; o[2] = (bf16)v.z; o[3] = (bf16)v.w;
        *(bf16x4*)(Xbf + r * 1024 + c) = o;
    } else if (bid < 10240) {
        long i = (long)(bid - 8192) * 256 + t;
        const float* s; bf16* d;
        if (i < 131072) {
            s = (i < 65536) ? Wqk + i * 4 : Wv + (i - 65536) * 4;
            d = Wqkv + i * 4;
        } else if (i < 393216) {
            long e = (i - 131072) * 4, r = e >> 10, c = e & 1023;
            s = Wf1 + e;
            d = (c < 512) ? (Wbig + r * 1024 + c) : (Wf1Rb + r * 512 + (c - 512));
        } else {
            s = Wf2 + (i - 393216) * 4;
            d = Wf2b + (i - 393216) * 4;
        }
        float4 v = *(const float4*)s;
        bf16x4 o;
        o[0] = (bf16)v.x; o[1] = (bf16)v.y; o[2] = (bf16)v.z; o[3] = (bf16)v.w;
        *(bf16x4*)d = o;
    } else if (bid < 10304) {
        const int bb = bid - 10240;
        const int bi = bb & 7, bj = bb >> 3;
        const int i0 = bi * 64, j0 = bj * 64;
        const int r0 = t >> 4, c4 = (t & 15) * 4;
#pragma unroll
        for (int it = 0; it < 4; it++) {
            int row = r0 + 16 * it;
            float4 v = *(const float4*)(Wo + (long)(i0 + row) * 512 + j0 + c4);
            Ls[row][c4] = v.x; Ls[row][c4 + 1] = v.y;
            Ls[row][c4 + 2] = v.z; Ls[row][c4 + 3] = v.w;
        }
        __syncthreads();
#pragma unroll
        for (int it = 0; it < 4; it++) {
            int orow = r0 + 16 * it;
            bf16x4 o;
#pragma unroll
            for (int k = 0; k < 4; k++) o[k] = (bf16)Ls[c4 + k][orow];
            *(bf16x4*)(WoT + (long)(j0 + orow) * 512 + i0 + c4) = o;
        }
    } else {
        const int w = t >> 6, lane = t & 63;
        const int row = (bid - 10304) * 4 + w;
        const float* rp = Wf1 + (long)row * 1024 + 512 + lane * 8;
        float4 a = *(const float4*)rp;
        float4 b = *(const float4*)(rp + 4);
        const float* bp = bo + lane * 8;
        float4 c = *(const float4*)bp;
        float4 d = *(const float4*)(bp + 4);
        float s = a.x * c.x + a.y * c.y + a.z * c.z + a.w * c.w +
                  b.x * d.x + b.y * d.y + b.z * d.z + b.w * d.w;
#pragma unroll
        for (int k = 1; k < 64; k <<= 1) s += __shfl_xor(s, k);
        if (lane == 0) bf1p[row] = bf1[row] + s;
    }
}

// ---------------- bf16 GEMM: C = A @ B^T, BK=64 swizzled (Wcomb only) ---------
template <int MODE>
__global__ __launch_bounds__(256) void gemm_bt(
    const bf16* __restrict__ A, long lda,
    const bf16* __restrict__ B, long ldb,
    const float* __restrict__ bias,
    void* __restrict__ Cout, long ldc,
    const float* __restrict__ res0, const float* __restrict__ res1,
    const float* __restrict__ bias2, void* __restrict__ Cout2,
    int M, int N, int K, float scale)
{
    __shared__ bf16 As[128 * 64];
    __shared__ bf16 Bs[128 * 64];
    const int t = threadIdx.x;
    const int w = t >> 6, lane = t & 63, quad = lane >> 4, m15 = lane & 15;
    const int wm = w >> 1, wn = w & 1;
    const int nbx = N >> 7;
    const int xcd = blockIdx.x & 7, local = blockIdx.x >> 3;
    const int mtiles_per_xcd = (int)(gridDim.x >> 3) / nbx;
    const int by = xcd * mtiles_per_xcd + local / nbx;
    const int bx = local % nbx;
    const long m0 = (long)by * 128, n0 = (long)bx * 128;

    f32x4 acc[4][4] = {};

    for (int k0 = 0; k0 < K; k0 += 64) {
#pragma unroll
        for (int i = 0; i < 4; i++) {
            int idx = i * 256 + t, row = idx >> 3, p = idx & 7;
            int gc = k0 + ((p ^ (row & 7)) * 8);
            async16(As + idx * 8, A + (m0 + row) * lda + gc);
            async16(Bs + idx * 8, B + (n0 + row) * ldb + gc);
        }
        __syncthreads();
#pragma unroll
        for (int kk = 0; kk < 2; kk++) {
            bf16x8 af[4], bfr[4];
#pragma unroll
            for (int mt = 0; mt < 4; mt++) {
                int row = wm * 64 + mt * 16 + m15;
                af[mt] = *(const bf16x8*)(As + row * 64 + (((kk * 4 + quad) ^ (row & 7)) * 8));
            }
#pragma unroll
            for (int nt = 0; nt < 4; nt++) {
                int row = wn * 64 + nt * 16 + m15;
                bfr[nt] = *(const bf16x8*)(Bs + row * 64 + (((kk * 4 + quad) ^ (row & 7)) * 8));
            }
#pragma unroll
            for (int mt = 0; mt < 4; mt++)
#pragma unroll
                for (int nt = 0; nt < 4; nt++)
                    acc[mt][nt] = mfma16(af[mt], bfr[nt], acc[mt][nt]);
        }
        __syncthreads();
    }

#pragma unroll
    for (int nt = 0; nt < 4; nt++) {
        long col = n0 + wn * 64 + nt * 16 + m15;
#pragma unroll
        for (int mt = 0; mt < 4; mt++) {
            long row = m0 + wm * 64 + mt * 16 + quad * 4;
            if (MODE == 4) {
                bf16* C = (bf16*)Cout;
#pragma unroll
                for (int r = 0; r < 4; r++)
                    C[(row + r) * ldc + col] = (bf16)acc[mt][nt][r];
            }
        }
    }
}

// ---------------- pipelined 128x128 GEMM: 2 blocks/CU co-resident (T3/T4) -----
// 256 threads = 4 waves (2M x 2N), BM=BN=128, BK=64, LDS 64 KiB (2 slots)
// -> 2 blocks/CU resident: co-resident block hides vmcnt+barrier drains.
// vmcnt(8) at entry (tile t resident, t+1's 8 loads in flight). Grid: any
// multiple of 8 with (grid/8) % nbx == 0. Same swizzle/fragments as gemm_bt.
// MODE 0: C bf16 = acc + bias[col]
// MODE 1: C fp32 = acc + bias[col] + residual (res0 rows<8192, res1 else)
// MODE 5: col<512 -> C bf16 = (acc+bias[col])*scale;
//         col>=512 -> Cout2[(col-512)*16384 + row..row+3] = acc + bias2[col-512]
template <int MODE>
__global__ __launch_bounds__(256, 2) void pipe128(
    const bf16* __restrict__ A, long lda,
    const bf16* __restrict__ B, long ldb,
    const float* __restrict__ bias,
    void* __restrict__ Cout, long ldc,
    const float* __restrict__ res0, const float* __restrict__ res1,
    const float* __restrict__ bias2, void* __restrict__ Cout2,
    int M, int N, int K, float scale)
{
    __shared__ bf16 lds[32768];          // 64 KiB: As[2][8192] | Bs[2][8192]
    bf16* As = lds;
    bf16* Bs = lds + 16384;

    const int t = threadIdx.x;
    const int w = t >> 6, lane = t & 63, quad = lane >> 4, m15 = lane & 15;
    const int wm = w >> 1, wn = w & 1;
    const int nbx = N >> 7;
    const int xcd = blockIdx.x & 7, local = blockIdx.x >> 3;
    const int mtiles_per_xcd = (int)(gridDim.x >> 3) / nbx;
    const int by = xcd * mtiles_per_xcd + local / nbx;
    const int bx = local % nbx;
    const long m0 = (long)by * 128, n0 = (long)bx * 128;
    const int nt = K >> 6;

    f32x4 acc[4][4] = {};

    // stage tile kt into slot kt&1: 8 async16/thread (4 A + 4 B)
    auto stage = [&](int kt) {
        const int slot = kt & 1;
        bf16* Ad = As + slot * 8192;
        bf16* Bd = Bs + slot * 8192;
        const int k0 = kt * 64;
#pragma unroll
        for (int i = 0; i < 4; i++) {
            int idx = i * 256 + t, row = idx >> 3, p = idx & 7;
            int gc = k0 + ((p ^ (row & 7)) * 8);
            async16(Ad + idx * 8, A + (m0 + row) * lda + gc);
            async16(Bd + idx * 8, B + (n0 + row) * ldb + gc);
        }
    };

    stage(0);
    stage(1);

    for (int kt = 0; kt < nt; kt++) {
        if (kt + 1 < nt) {
            asm volatile("s_waitcnt vmcnt(8)" ::: "memory");
        } else {
            asm volatile("s_waitcnt vmcnt(0)" ::: "memory");
        }
        __builtin_amdgcn_s_barrier();
        __builtin_amdgcn_sched_barrier(0);

        const bf16* Asl = As + (kt & 1) * 8192;
        const bf16* Bsl = Bs + (kt & 1) * 8192;
#pragma unroll
        for (int kk = 0; kk < 2; kk++) {
            bf16x8 af[4], bfr[4];
#pragma unroll
            for (int mt = 0; mt < 4; mt++) {
                int row = wm * 64 + mt * 16 + m15;
                af[mt] = *(const bf16x8*)(Asl + row * 64 + (((kk * 4 + quad) ^ (row & 7)) * 8));
            }
#pragma unroll
            for (int nf = 0; nf < 4; nf++) {
                int row = wn * 64 + nf * 16 + m15;
                bfr[nf] = *(const bf16x8*)(Bsl + row * 64 + (((kk * 4 + quad) ^ (row & 7)) * 8));
            }
            __builtin_amdgcn_s_setprio(1);
#pragma unroll
            for (int mt = 0; mt < 4; mt++)
#pragma unroll
                for (int nf = 0; nf < 4; nf++)
                    acc[mt][nf] = mfma16(af[mt], bfr[nf], acc[mt][nf]);
            __builtin_amdgcn_s_setprio(0);
        }

        __builtin_amdgcn_sched_barrier(0);
        __builtin_amdgcn_s_barrier();
        __builtin_amdgcn_sched_barrier(0);
        if (kt + 2 < nt) stage(kt + 2);
    }

#pragma unroll
    for (int nf = 0; nf < 4; nf++) {
        long col = n0 + wn * 64 + nf * 16 + m15;
#pragma unroll
        for (int mt = 0; mt < 4; mt++) {
            long row = m0 + wm * 64 + mt * 16 + quad * 4;
            if (MODE == 0) {
                bf16* C = (bf16*)Cout;
                float bs = bias[col];
#pragma unroll
                for (int r = 0; r < 4; r++)
                    C[(row + r) * ldc + col] = (bf16)(acc[mt][nf][r] + bs);
            } else if (MODE == 5) {
                if (col < 512) {
                    bf16* C = (bf16*)Cout;
                    float bs = bias[col];
#pragma unroll
                    for (int r = 0; r < 4; r++)
                        C[(row + r) * ldc + col] = (bf16)((acc[mt][nf][r] + bs) * scale);
                } else {
                    bf16* V = (bf16*)Cout2;
                    long v = col - 512;
                    float bs = bias2[v];
                    bf16x4 pv;
#pragma unroll
                    for (int r = 0; r < 4; r++) pv[r] = (bf16)(acc[mt][nf][r] + bs);
                    *(bf16x4*)(V + v * 16384 + row) = pv;
                }
            } else {  // MODE 1
                float* C = (float*)Cout;
                float bs = bias[col];
#pragma unroll
                for (int r = 0; r < 4; r++) {
                    long grow = row + r;
                    const float* rs = (grow < 8192) ? (res0 + grow * 512)
                                                    : (res1 + (grow - 8192) * 512);
                    C[grow * ldc + col] = acc[mt][nf][r] + bs + rs[col];
                }
            }
        }
    }
}

// ---------------- flash attention: 32x32 MFMA, in-register P, QBLK=128 --------
// (r3/r5-proven: ~114 us) LDS 32KiB: K dbuf 2x8K | V dbuf 2x8K. One barrier/iter.
__global__ __launch_bounds__(256, 4) void flash_attn(const bf16* __restrict__ QK,
                                                     const bf16* __restrict__ VT,
                                                     bf16* __restrict__ o)
{
    __shared__ bf16 lds[16384];          // 32 KiB: Ks[2][4096] | Vs[2][4096]

    const int t = threadIdx.x, w = t >> 6, lane = t & 63;
    const int l31 = lane & 31, hi = lane >> 5;
    const int j = blockIdx.x;
    const int hs = j & 63;               // head-set id (shares K/V)
    const int qt = j >> 6;               // 0..15 q-tile
    const int h = hs & 7, b = (hs >> 3) & 3, dir = hs >> 5;
    const long qrow0  = (long)dir * 8192 + b * 2048 + qt * 128;
    const long kvrow0 = (long)(1 - dir) * 8192 + b * 2048;
    const int hc = h * 64;

    // ---- Q stage: 128 rows x 64 d = 16KB into first half of LDS ----
#pragma unroll
    for (int i = 0; i < 4; i++) {
        int idx = i * 256 + t, row = idx >> 3, p = idx & 7;
        async16(lds + idx * 8, QK + (qrow0 + row) * 512 + hc + ((p ^ (row & 7)) * 8));
    }
    __syncthreads();
    bf16x8 qf[4];
    {
        int qrow = w * 32 + l31;
#pragma unroll
        for (int kd = 0; kd < 4; kd++)
            qf[kd] = *(const bf16x8*)(lds + qrow * 64 + (((kd * 2 + hi) ^ (qrow & 7)) * 8));
    }
    __syncthreads();  // all Q reads done before K/V loads overwrite

    // ---- prologue: issue K(0), V(0) into buffer 0 ----
#pragma unroll
    for (int i = 0; i < 2; i++) {
        int idx = i * 256 + t, row = idx >> 3, p = idx & 7;
        async16(lds + idx * 8, QK + (kvrow0 + row) * 512 + hc + ((p ^ (row & 7)) * 8));
    }
#pragma unroll
    for (int i = 0; i < 2; i++) {
        int idx = i * 256 + t, row = idx >> 3, p = idx & 7;
        async16(lds + 8192 + idx * 8, VT + (long)(hc + row) * 16384 + kvrow0 + ((p ^ (row & 7)) * 8));
    }

    f32x16 oacc[2] = {};
    f32x16 racc = {};
    bf16x8 ones;
#pragma unroll
    for (int k = 0; k < 8; k++) ones[k] = (bf16)1.0f;

    for (int kb = 0; kb < 32; kb++) {
        bf16* Kc = lds + (kb & 1) * 4096;
        bf16* Vc = lds + 8192 + (kb & 1) * 4096;

        asm volatile("s_waitcnt vmcnt(0)" ::: "memory");
        __builtin_amdgcn_s_barrier();

        if (kb < 31) {
            const long knext = kvrow0 + (kb + 1) * 64;
            bf16* Kn = lds + ((kb + 1) & 1) * 4096;
            bf16* Vn = lds + 8192 + ((kb + 1) & 1) * 4096;
#pragma unroll
            for (int i = 0; i < 2; i++) {
                int idx = i * 256 + t, row = idx >> 3, p = idx & 7;
                async16(Kn + idx * 8, QK + (knext + row) * 512 + hc + ((p ^ (row & 7)) * 8));
            }
#pragma unroll
            for (int i = 0; i < 2; i++) {
                int idx = i * 256 + t, row = idx >> 3, p = idx & 7;
                async16(Vn + idx * 8, VT + (long)(hc + row) * 16384 + knext + ((p ^ (row & 7)) * 8));
            }
        }

#pragma unroll
        for (int kb2 = 0; kb2 < 2; kb2++) {
            const int krow = kb2 * 32 + l31;
            const int ksw = krow & 7;
            bf16x8 kf0 = *(const bf16x8*)(Kc + krow * 64 + (((0 + hi) ^ ksw) * 8));
            bf16x8 kf1 = *(const bf16x8*)(Kc + krow * 64 + (((2 + hi) ^ ksw) * 8));
            bf16x8 kf2 = *(const bf16x8*)(Kc + krow * 64 + (((4 + hi) ^ ksw) * 8));
            bf16x8 kf3 = *(const bf16x8*)(Kc + krow * 64 + (((6 + hi) ^ ksw) * 8));

            f32x16 s0 = {};
            __builtin_amdgcn_s_setprio(1);
            s0 = mfma32(kf0, qf[0], s0);
            s0 = mfma32(kf1, qf[1], s0);
            s0 = mfma32(kf2, qf[2], s0);
            s0 = mfma32(kf3, qf[3], s0);
            __builtin_amdgcn_s_setprio(0);

#pragma unroll
            for (int r = 0; r < 16; r++) s0[r] = exp2f(s0[r]);

#pragma unroll
            for (int sh = 0; sh < 2; sh++) {
                const int ks = kb2 * 2 + sh;
                unsigned a00 = cvtpk(s0[8 * sh + 0], s0[8 * sh + 1]);
                unsigned a01 = cvtpk(s0[8 * sh + 2], s0[8 * sh + 3]);
                unsigned b00 = cvtpk(s0[8 * sh + 4], s0[8 * sh + 5]);
                unsigned b01 = cvtpk(s0[8 * sh + 6], s0[8 * sh + 7]);
                pl32(a00, b00); pl32(a01, b01);
                bf16x8 pa0 = mk8(a00, a01, b00, b01);

                __builtin_amdgcn_s_setprio(1);
#pragma unroll
                for (int db = 0; db < 2; db++) {
                    const int vrow = db * 32 + l31;
                    bf16x8 vf = *(const bf16x8*)(Vc + vrow * 64 + (((ks * 2 + hi) ^ (vrow & 7)) * 8));
                    oacc[db] = mfma32(pa0, vf, oacc[db]);
                }
                racc = mfma32(pa0, ones, racc);
                __builtin_amdgcn_s_setprio(0);
            }
        }
    }

#pragma unroll
    for (int reg = 0; reg < 16; reg++) {
        const int q = (reg & 3) + 8 * (reg >> 2) + 4 * hi;
        const float inv = 1.f / racc[reg];
        const long row = qrow0 + w * 32 + q;
#pragma unroll
        for (int db = 0; db < 2; db++)
            o[row * 1024 + hc + db * 32 + l31] = (bf16)(oacc[db][reg] * inv);
    }
}

// ---------------- LayerNorm + GELU (exact erf), in-place on bf16 [16384][1024]
__global__ __launch_bounds__(256) void ln_gelu(bf16* __restrict__ H,
                                               const float* __restrict__ g,
                                               const float* __restrict__ bta)
{
    const int row = blockIdx.x, t = threadIdx.x;
    const int w = t >> 6, lane = t & 63;
    bf16* hp = H + (long)row * 1024 + t * 4;
    bf16x4 hv = *(const bf16x4*)hp;
    float h[4];
#pragma unroll
    for (int j = 0; j < 4; j++) h[j] = (float)hv[j];
    float s1 = h[0] + h[1] + h[2] + h[3];
    float s2 = h[0] * h[0] + h[1] * h[1] + h[2] * h[2] + h[3] * h[3];
#pragma unroll
    for (int d = 1; d < 64; d <<= 1) {
        s1 += __shfl_xor(s1, d);
        s2 += __shfl_xor(s2, d);
    }
    __shared__ float rbuf[8];
    if (lane == 0) { rbuf[w] = s1; rbuf[4 + w] = s2; }
    __syncthreads();
    s1 = rbuf[0] + rbuf[1] + rbuf[2] + rbuf[3];
    s2 = rbuf[4] + rbuf[5] + rbuf[6] + rbuf[7];
    const float mu = s1 * (1.f / 1024.f);
    const float var = s2 * (1.f / 1024.f) - mu * mu;
    const float rstd = rsqrtf(var + 1e-5f);
    bf16x4 out;
#pragma unroll
    for (int j = 0; j < 4; j++) {
        int c = t * 4 + j;
        float x = (h[j] - mu) * rstd * g[c] + bta[c];
        float y = 0.5f * x * (1.f + erff(x * 0.70710678118654752f));
        out[j] = (bf16)y;
    }
    *(bf16x4*)hp = out;
}

extern "C" void kernel_launch(void* const* d_in, const int* in_sizes, int n_in,
                              void* d_out, int out_size, void* d_ws, size_t ws_size,
                              hipStream_t stream)
{
    const float* x0  = (const float*)d_in[0];
    const float* x1  = (const float*)d_in[1];
    const float* Wqk = (const float*)d_in[2];
    const float* bqk = (const float*)d_in[3];
    const float* Wv  = (const float*)d_in[4];
    const float* bv  = (const float*)d_in[5];
    const float* Wo  = (const float*)d_in[6];
    const float* bo  = (const float*)d_in[7];
    const float* Wf1 = (const float*)d_in[8];
    const float* bf1 = (const float*)d_in[9];
    const float* lng = (const float*)d_in[10];
    const float* lnb = (const float*)d_in[11];
    const float* Wf2 = (const float*)d_in[12];
    const float* bf2 = (const float*)d_in[13];

    char* ws = (char*)d_ws;
    bf16* Xbf   = (bf16*)ws; ws += 16384L * 1024 * 2;  // [x | m] both streams
    bf16* QKbf  = (bf16*)ws;                            // qk projection (pre-scaled)
    bf16* Hbuf  = (bf16*)ws;                            // FFN1 out (aliases QKbf+VtG)
    ws += 16384L * 512 * 2;
    bf16* VtG   = (bf16*)ws; ws += 16384L * 512 * 2;   // v proj transposed [512][16384]
    bf16* Wqkv  = (bf16*)ws; ws += 1024L * 512 * 2;    // [Wqk; Wv] bf16
    bf16* Wbig  = (bf16*)ws; ws += 1024L * 1024 * 2;   // [Wf1L | Wcomb]
    bf16* Wf1Rb = (bf16*)ws; ws += 1024L * 512 * 2;
    bf16* Wf2b  = (bf16*)ws; ws += 512L * 1024 * 2;
    bf16* WoT   = (bf16*)ws; ws += 512L * 512 * 2;
    float* bf1p = (float*)ws; ws += 1024 * 4;

    // sqrt((1/8) * log2(e)) — applied to both q and k so scores carry (1/8)*log2(e)
    const float qs = 0.42466090014400953f;

    prep<<<10560, 256, 0, stream>>>(x0, x1, Xbf, Wqk, Wv, Wf1, Wf2,
                                    Wqkv, Wbig, Wf1Rb, Wf2b, Wo, WoT, bo, bf1, bf1p);

    // Wcomb = Wf1R @ Wo -> Wbig right half  [1024,512] = Wf1Rb @ WoT^T
    gemm_bt<4><<<32, 256, 0, stream>>>(Wf1Rb, 512, WoT, 512, nullptr,
                                       Wbig + 512, 1024, nullptr, nullptr,
                                       nullptr, nullptr, 1024, 512, 512, 1.f);

    // fused QKV projection: [16384,1024] = Xbf @ Wqkv^T (128^2, 2 blk/CU)
    pipe128<5><<<1024, 256, 0, stream>>>(Xbf, 1024, Wqkv, 512, bqk,
                                         QKbf, 512, nullptr, nullptr,
                                         bv, VtG, 16384, 1024, 512, qs);

    // cross attention -> writes m-heads directly into Xbf right half (ld 1024)
    flash_attn<<<1024, 256, 0, stream>>>(QKbf, VtG, Xbf + 512);

    // FFN1 (Wo folded): [16384,1024] = [x|O] @ [Wf1L|Wcomb]^T + bf1'
    pipe128<0><<<1024, 256, 0, stream>>>(Xbf, 1024, Wbig, 1024, bf1p,
                                         Hbuf, 1024, nullptr, nullptr,
                                         nullptr, nullptr, 16384, 1024, 1024, 1.f);
    ln_gelu<<<16384, 256, 0, stream>>>(Hbuf, lng, lnb);
    // FFN2 + bias + residual -> d_out (fp32), 128^2, 2 blk/CU
    pipe128<1><<<512, 256, 0, stream>>>(Hbuf, 1024, Wf2b, 1024, bf2,
                                        d_out, 512, x0, x1,
                                        nullptr, nullptr, 16384, 512, 1024, 1.f);
}

// Round 9
// 345.242 us; speedup vs baseline: 1.0448x; 1.0398x over previous
//
#include <hip/hip_runtime.h>
#include <hip/hip_bf16.h>
#include <math.h>

typedef __bf16 bf16;
typedef __bf16 bf16x8 __attribute__((ext_vector_type(8)));
typedef __bf16 bf16x4 __attribute__((ext_vector_type(4)));
typedef float  f32x4  __attribute__((ext_vector_type(4)));
typedef float  f32x16 __attribute__((ext_vector_type(16)));
typedef unsigned int u32x2 __attribute__((ext_vector_type(2)));

#define DEVI __device__ __forceinline__

DEVI void async16(bf16* lds, const bf16* g) {
    __builtin_amdgcn_global_load_lds(
        (const __attribute__((address_space(1))) unsigned int*)g,
        (__attribute__((address_space(3))) unsigned int*)lds, 16, 0, 0);
}
DEVI f32x4 mfma16(bf16x8 a, bf16x8 b, f32x4 c) {
    return __builtin_amdgcn_mfma_f32_16x16x32_bf16(a, b, c, 0, 0, 0);
}
DEVI f32x16 mfma32(bf16x8 a, bf16x8 b, f32x16 c) {
    return __builtin_amdgcn_mfma_f32_32x32x16_bf16(a, b, c, 0, 0, 0);
}
DEVI unsigned cvtpk(float lo, float hi) {
    unsigned r;
    asm("v_cvt_pk_bf16_f32 %0, %1, %2" : "=v"(r) : "v"(lo), "v"(hi));
    return r;
}
// v_permlane32_swap_b32: a' = [a.lo32, b.lo32], b' = [a.hi32, b.hi32]
DEVI void pl32(unsigned &a, unsigned &b) {
    u32x2 r = __builtin_amdgcn_permlane32_swap(a, b, false, false);
    a = r.x; b = r.y;
}
DEVI bf16x8 mk8(unsigned a0, unsigned a1, unsigned b0, unsigned b1) {
    union { unsigned u[4]; bf16x8 v; } U;
    U.u[0] = a0; U.u[1] = a1; U.u[2] = b0; U.u[3] = b1;
    return U.v;
}
// Abramowitz-Stegun 7.1.26 erf, |err| <= 1.5e-7 (vs libm branchy erff)
DEVI float erf_fast(float x) {
    float ax = fabsf(x);
    float t = 1.f / (1.f + 0.3275911f * ax);
    float y = t * (0.254829592f +
              t * (-0.284496736f +
              t * (1.421413741f +
              t * (-1.453152027f + t * 1.061405429f))));
    float e = __expf(-ax * ax);
    float r = 1.f - y * e;
    return (x < 0.f) ? -r : r;
}

// ---------------- fused prep: cvt_x + cvt_w + wo_t + bias_comb ----------------
__global__ __launch_bounds__(256) void prep(
    const float* __restrict__ x0, const float* __restrict__ x1, bf16* __restrict__ Xbf,
    const float* __restrict__ Wqk, const float* __restrict__ Wv,
    const float* __restrict__ Wf1, const float* __restrict__ Wf2,
    bf16* __restrict__ Wqkv, bf16* __restrict__ Wbig, bf16* __restrict__ Wf1Rb,
    bf16* __restrict__ Wf2b,
    const float* __restrict__ Wo, bf16* __restrict__ WoT,
    const float* __restrict__ bo, const float* __restrict__ bf1,
    float* __restrict__ bf1p)
{
    __shared__ float Ls[64][65];
    const int bid = blockIdx.x, t = threadIdx.x;
    if (bid < 8192) {
        long i = (long)bid * 256 + t;
        long r = i >> 7, c = (i & 127) * 4;
        const float* src = (r < 8192) ? (x0 + r * 512 + c) : (x1 + (r - 8192) * 512 + c);
        float4 v = *(const float4*)src;
        bf16x4 o;
        o[0] = (bf16)v.x; o[1] = (bf16)v.y; o[2] = (bf16)v.z; o[3] = (bf16)v.w;
        *(bf16x4*)(Xbf + r * 1024 + c) = o;
    } else if (bid < 10240) {
        long i = (long)(bid - 8192) * 256 + t;
        const float* s; bf16* d;
        if (i < 131072) {
            s = (i < 65536) ? Wqk + i * 4 : Wv + (i - 65536) * 4;
            d = Wqkv + i * 4;
        } else if (i < 393216) {
            long e = (i - 131072) * 4, r = e >> 10, c = e & 1023;
            s = Wf1 + e;
            d = (c < 512) ? (Wbig + r * 1024 + c) : (Wf1Rb + r * 512 + (c - 512));
        } else {
            s = Wf2 + (i - 393216) * 4;
            d = Wf2b + (i - 393216) * 4;
        }
        float4 v = *(const float4*)s;
        bf16x4 o;
        o[0] = (bf16)v.x; o[1] = (bf16)v.y; o[2] = (bf16)v.z; o[3] = (bf16)v.w;
        *(bf16x4*)d = o;
    } else if (bid < 10304) {
        const int bb = bid - 10240;
        const int bi = bb & 7, bj = bb >> 3;
        const int i0 = bi * 64, j0 = bj * 64;
        const int r0 = t >> 4, c4 = (t & 15) * 4;
#pragma unroll
        for (int it = 0; it < 4; it++) {
            int row = r0 + 16 * it;
            float4 v = *(const float4*)(Wo + (long)(i0 + row) * 512 + j0 + c4);
            Ls[row][c4] = v.x; Ls[row][c4 + 1] = v.y;
            Ls[row][c4 + 2] = v.z; Ls[row][c4 + 3] = v.w;
        }
        __syncthreads();
#pragma unroll
        for (int it = 0; it < 4; it++) {
            int orow = r0 + 16 * it;
            bf16x4 o;
#pragma unroll
            for (int k = 0; k < 4; k++) o[k] = (bf16)Ls[c4 + k][orow];
            *(bf16x4*)(WoT + (long)(j0 + orow) * 512 + i0 + c4) = o;
        }
    } else {
        const int w = t >> 6, lane = t & 63;
        const int row = (bid - 10304) * 4 + w;
        const float* rp = Wf1 + (long)row * 1024 + 512 + lane * 8;
        float4 a = *(const float4*)rp;
        float4 b = *(const float4*)(rp + 4);
        const float* bp = bo + lane * 8;
        float4 c = *(const float4*)bp;
        float4 d = *(const float4*)(bp + 4);
        float s = a.x * c.x + a.y * c.y + a.z * c.z + a.w * c.w +
                  b.x * d.x + b.y * d.y + b.z * d.z + b.w * d.w;
#pragma unroll
        for (int k = 1; k < 64; k <<= 1) s += __shfl_xor(s, k);
        if (lane == 0) bf1p[row] = bf1[row] + s;
    }
}

// ---------------- bf16 GEMM: C = A @ B^T, BK=64 swizzled (Wcomb only) ---------
template <int MODE>
__global__ __launch_bounds__(256) void gemm_bt(
    const bf16* __restrict__ A, long lda,
    const bf16* __restrict__ B, long ldb,
    const float* __restrict__ bias,
    void* __restrict__ Cout, long ldc,
    const float* __restrict__ res0, const float* __restrict__ res1,
    const float* __restrict__ bias2, void* __restrict__ Cout2,
    int M, int N, int K, float scale)
{
    __shared__ bf16 As[128 * 64];
    __shared__ bf16 Bs[128 * 64];
    const int t = threadIdx.x;
    const int w = t >> 6, lane = t & 63, quad = lane >> 4, m15 = lane & 15;
    const int wm = w >> 1, wn = w & 1;
    const int nbx = N >> 7;
    const int xcd = blockIdx.x & 7, local = blockIdx.x >> 3;
    const int mtiles_per_xcd = (int)(gridDim.x >> 3) / nbx;
    const int by = xcd * mtiles_per_xcd + local / nbx;
    const int bx = local % nbx;
    const long m0 = (long)by * 128, n0 = (long)bx * 128;

    f32x4 acc[4][4] = {};

    for (int k0 = 0; k0 < K; k0 += 64) {
#pragma unroll
        for (int i = 0; i < 4; i++) {
            int idx = i * 256 + t, row = idx >> 3, p = idx & 7;
            int gc = k0 + ((p ^ (row & 7)) * 8);
            async16(As + idx * 8, A + (m0 + row) * lda + gc);
            async16(Bs + idx * 8, B + (n0 + row) * ldb + gc);
        }
        __syncthreads();
#pragma unroll
        for (int kk = 0; kk < 2; kk++) {
            bf16x8 af[4], bfr[4];
#pragma unroll
            for (int mt = 0; mt < 4; mt++) {
                int row = wm * 64 + mt * 16 + m15;
                af[mt] = *(const bf16x8*)(As + row * 64 + (((kk * 4 + quad) ^ (row & 7)) * 8));
            }
#pragma unroll
            for (int nt = 0; nt < 4; nt++) {
                int row = wn * 64 + nt * 16 + m15;
                bfr[nt] = *(const bf16x8*)(Bs + row * 64 + (((kk * 4 + quad) ^ (row & 7)) * 8));
            }
#pragma unroll
            for (int mt = 0; mt < 4; mt++)
#pragma unroll
                for (int nt = 0; nt < 4; nt++)
                    acc[mt][nt] = mfma16(af[mt], bfr[nt], acc[mt][nt]);
        }
        __syncthreads();
    }

#pragma unroll
    for (int nt = 0; nt < 4; nt++) {
        long col = n0 + wn * 64 + nt * 16 + m15;
#pragma unroll
        for (int mt = 0; mt < 4; mt++) {
            long row = m0 + wm * 64 + mt * 16 + quad * 4;
            if (MODE == 4) {
                bf16* C = (bf16*)Cout;
#pragma unroll
                for (int r = 0; r < 4; r++)
                    C[(row + r) * ldc + col] = (bf16)acc[mt][nt][r];
            }
        }
    }
}

// ---------------- pipelined 256x256 GEMM: counted vmcnt + EARLY stage issue ---
// 512 threads = 8 waves (2M x 4N), BM=BN=256, BK=64, LDS 128 KiB (2 slots).
// Loop: vmcnt(8) [tile kt resident, kt+1 in flight] -> barrier -> ksub0
// reads+MFMA -> ksub1 reads -> lgkmcnt(0)+barrier [slot free everywhere] ->
// ISSUE stage(kt+2) -> ksub1 MFMA. Stage gains a full MFMA cluster of latency
// cover vs trailing-issue; one barrier/iter removed. Grid 256, N%256==0.
template <int MODE>
__global__ __launch_bounds__(512, 2) void pipe_gemm(
    const bf16* __restrict__ A, long lda,
    const bf16* __restrict__ B, long ldb,
    const float* __restrict__ bias,
    void* __restrict__ Cout, long ldc,
    const float* __restrict__ bias2, void* __restrict__ Cout2,
    int M, int N, int K, float scale)
{
    __shared__ bf16 lds[65536];          // 128 KiB: As[2][16384] | Bs[2][16384]
    bf16* As = lds;
    bf16* Bs = lds + 32768;

    const int t = threadIdx.x;
    const int w = t >> 6, lane = t & 63, quad = lane >> 4, m15 = lane & 15;
    const int wm = w >> 2, wn = w & 3;
    const int nbx = N >> 8;
    const int xcd = blockIdx.x & 7, local = blockIdx.x >> 3;
    const int mtiles_per_xcd = (int)(gridDim.x >> 3) / nbx;
    const int by = xcd * mtiles_per_xcd + local / nbx;
    const int bx = local % nbx;
    const long m0 = (long)by * 256, n0 = (long)bx * 256;
    const int nt = K >> 6;

    f32x4 acc[8][4] = {};

    auto stage = [&](int kt) {
        const int slot = kt & 1;
        bf16* Ad = As + slot * 16384;
        bf16* Bd = Bs + slot * 16384;
        const int k0 = kt * 64;
#pragma unroll
        for (int i = 0; i < 4; i++) {
            int idx = i * 512 + t, row = idx >> 3, p = idx & 7;
            int gc = k0 + ((p ^ (row & 7)) * 8);
            async16(Ad + idx * 8, A + (m0 + row) * lda + gc);
        }
#pragma unroll
        for (int i = 0; i < 4; i++) {
            int idx = i * 512 + t, row = idx >> 3, p = idx & 7;
            int gc = k0 + ((p ^ (row & 7)) * 8);
            async16(Bd + idx * 8, B + (n0 + row) * ldb + gc);
        }
    };

    stage(0);
    stage(1);

    for (int kt = 0; kt < nt; kt++) {
        if (kt + 1 < nt) {
            asm volatile("s_waitcnt vmcnt(8)" ::: "memory");
        } else {
            asm volatile("s_waitcnt vmcnt(0)" ::: "memory");
        }
        __builtin_amdgcn_s_barrier();
        __builtin_amdgcn_sched_barrier(0);

        const bf16* Asl = As + (kt & 1) * 16384;
        const bf16* Bsl = Bs + (kt & 1) * 16384;

        // ---- ksub 0: reads + MFMA ----
        {
            bf16x8 af[8], bfr[4];
#pragma unroll
            for (int mf = 0; mf < 8; mf++) {
                int row = wm * 128 + mf * 16 + m15;
                af[mf] = *(const bf16x8*)(Asl + row * 64 + ((quad ^ (row & 7)) * 8));
            }
#pragma unroll
            for (int nf = 0; nf < 4; nf++) {
                int row = wn * 64 + nf * 16 + m15;
                bfr[nf] = *(const bf16x8*)(Bsl + row * 64 + ((quad ^ (row & 7)) * 8));
            }
            __builtin_amdgcn_s_setprio(1);
#pragma unroll
            for (int mf = 0; mf < 8; mf++)
#pragma unroll
                for (int nf = 0; nf < 4; nf++)
                    acc[mf][nf] = mfma16(af[mf], bfr[nf], acc[mf][nf]);
            __builtin_amdgcn_s_setprio(0);
        }

        // ---- ksub 1: reads, then free the slot, then early stage, then MFMA --
        {
            bf16x8 af[8], bfr[4];
#pragma unroll
            for (int mf = 0; mf < 8; mf++) {
                int row = wm * 128 + mf * 16 + m15;
                af[mf] = *(const bf16x8*)(Asl + row * 64 + (((4 + quad) ^ (row & 7)) * 8));
            }
#pragma unroll
            for (int nf = 0; nf < 4; nf++) {
                int row = wn * 64 + nf * 16 + m15;
                bfr[nf] = *(const bf16x8*)(Bsl + row * 64 + (((4 + quad) ^ (row & 7)) * 8));
            }
            asm volatile("s_waitcnt lgkmcnt(0)" ::: "memory");
            __builtin_amdgcn_sched_barrier(0);
            __builtin_amdgcn_s_barrier();     // all waves done reading this slot
            __builtin_amdgcn_sched_barrier(0);
            if (kt + 2 < nt) stage(kt + 2);   // overwrite slot while MFMA runs
            __builtin_amdgcn_s_setprio(1);
#pragma unroll
            for (int mf = 0; mf < 8; mf++)
#pragma unroll
                for (int nf = 0; nf < 4; nf++)
                    acc[mf][nf] = mfma16(af[mf], bfr[nf], acc[mf][nf]);
            __builtin_amdgcn_s_setprio(0);
        }
    }

#pragma unroll
    for (int nf = 0; nf < 4; nf++) {
        long col = n0 + wn * 64 + nf * 16 + m15;
#pragma unroll
        for (int mf = 0; mf < 8; mf++) {
            long row = m0 + wm * 128 + mf * 16 + quad * 4;
            if (MODE == 0) {
                bf16* C = (bf16*)Cout;
                float bs = bias[col];
#pragma unroll
                for (int r = 0; r < 4; r++)
                    C[(row + r) * ldc + col] = (bf16)(acc[mf][nf][r] + bs);
            } else {  // MODE 5
                if (col < 512) {
                    bf16* C = (bf16*)Cout;
                    float bs = bias[col];
#pragma unroll
                    for (int r = 0; r < 4; r++)
                        C[(row + r) * ldc + col] = (bf16)((acc[mf][nf][r] + bs) * scale);
                } else {
                    bf16* V = (bf16*)Cout2;
                    long v = col - 512;
                    float bs = bias2[v];
                    bf16x4 pv;
#pragma unroll
                    for (int r = 0; r < 4; r++) pv[r] = (bf16)(acc[mf][nf][r] + bs);
                    *(bf16x4*)(V + v * 16384 + row) = pv;
                }
            }
        }
    }
}

// ---------------- pipelined FFN2: BM=128 BN=256, fp32 out + residual ----------
// Same early-stage-issue schedule, vmcnt(6) (stage = 2 A + 4 B per thread).
__global__ __launch_bounds__(512, 2) void pipe_ffn2(
    const bf16* __restrict__ A, long lda,
    const bf16* __restrict__ B, long ldb,
    const float* __restrict__ bias,
    float* __restrict__ C, long ldc,
    const float* __restrict__ res0, const float* __restrict__ res1,
    int M, int N, int K)
{
    __shared__ bf16 lds[49152];          // 96 KiB: As[2][8192] | Bs[2][16384]
    bf16* As = lds;                      // 128 x 64 per slot
    bf16* Bs = lds + 16384;              // 256 x 64 per slot

    const int t = threadIdx.x;
    const int w = t >> 6, lane = t & 63, quad = lane >> 4, m15 = lane & 15;
    const int wm = w >> 2, wn = w & 3;
    const int nbx = N >> 8;              // 2
    const int xcd = blockIdx.x & 7, local = blockIdx.x >> 3;
    const int mtiles_per_xcd = (int)(gridDim.x >> 3) / nbx;
    const int by = xcd * mtiles_per_xcd + local / nbx;
    const int bx = local % nbx;
    const long m0 = (long)by * 128, n0 = (long)bx * 256;
    const int nt = K >> 6;

    f32x4 acc[4][4] = {};

    auto stage = [&](int kt) {
        const int slot = kt & 1;
        bf16* Ad = As + slot * 8192;
        bf16* Bd = Bs + slot * 16384;
        const int k0 = kt * 64;
#pragma unroll
        for (int i = 0; i < 2; i++) {
            int idx = i * 512 + t, row = idx >> 3, p = idx & 7;
            int gc = k0 + ((p ^ (row & 7)) * 8);
            async16(Ad + idx * 8, A + (m0 + row) * lda + gc);
        }
#pragma unroll
        for (int i = 0; i < 4; i++) {
            int idx = i * 512 + t, row = idx >> 3, p = idx & 7;
            int gc = k0 + ((p ^ (row & 7)) * 8);
            async16(Bd + idx * 8, B + (n0 + row) * ldb + gc);
        }
    };

    stage(0);
    stage(1);

    for (int kt = 0; kt < nt; kt++) {
        if (kt + 1 < nt) {
            asm volatile("s_waitcnt vmcnt(6)" ::: "memory");
        } else {
            asm volatile("s_waitcnt vmcnt(0)" ::: "memory");
        }
        __builtin_amdgcn_s_barrier();
        __builtin_amdgcn_sched_barrier(0);

        const bf16* Asl = As + (kt & 1) * 8192;
        const bf16* Bsl = Bs + (kt & 1) * 16384;

        // ---- ksub 0 ----
        {
            bf16x8 af[4], bfr[4];
#pragma unroll
            for (int mf = 0; mf < 4; mf++) {
                int row = wm * 64 + mf * 16 + m15;
                af[mf] = *(const bf16x8*)(Asl + row * 64 + ((quad ^ (row & 7)) * 8));
            }
#pragma unroll
            for (int nf = 0; nf < 4; nf++) {
                int row = wn * 64 + nf * 16 + m15;
                bfr[nf] = *(const bf16x8*)(Bsl + row * 64 + ((quad ^ (row & 7)) * 8));
            }
            __builtin_amdgcn_s_setprio(1);
#pragma unroll
            for (int mf = 0; mf < 4; mf++)
#pragma unroll
                for (int nf = 0; nf < 4; nf++)
                    acc[mf][nf] = mfma16(af[mf], bfr[nf], acc[mf][nf]);
            __builtin_amdgcn_s_setprio(0);
        }

        // ---- ksub 1 with early stage issue ----
        {
            bf16x8 af[4], bfr[4];
#pragma unroll
            for (int mf = 0; mf < 4; mf++) {
                int row = wm * 64 + mf * 16 + m15;
                af[mf] = *(const bf16x8*)(Asl + row * 64 + (((4 + quad) ^ (row & 7)) * 8));
            }
#pragma unroll
            for (int nf = 0; nf < 4; nf++) {
                int row = wn * 64 + nf * 16 + m15;
                bfr[nf] = *(const bf16x8*)(Bsl + row * 64 + (((4 + quad) ^ (row & 7)) * 8));
            }
            asm volatile("s_waitcnt lgkmcnt(0)" ::: "memory");
            __builtin_amdgcn_sched_barrier(0);
            __builtin_amdgcn_s_barrier();
            __builtin_amdgcn_sched_barrier(0);
            if (kt + 2 < nt) stage(kt + 2);
            __builtin_amdgcn_s_setprio(1);
#pragma unroll
            for (int mf = 0; mf < 4; mf++)
#pragma unroll
                for (int nf = 0; nf < 4; nf++)
                    acc[mf][nf] = mfma16(af[mf], bfr[nf], acc[mf][nf]);
            __builtin_amdgcn_s_setprio(0);
        }
    }

#pragma unroll
    for (int nf = 0; nf < 4; nf++) {
        long col = n0 + wn * 64 + nf * 16 + m15;
        float bs = bias[col];
#pragma unroll
        for (int mf = 0; mf < 4; mf++) {
            long row = m0 + wm * 64 + mf * 16 + quad * 4;
#pragma unroll
            for (int r = 0; r < 4; r++) {
                long grow = row + r;
                const float* rs = (grow < 8192) ? (res0 + grow * 512)
                                                : (res1 + (grow - 8192) * 512);
                C[grow * ldc + col] = acc[mf][nf][r] + bs + rs[col];
            }
        }
    }
}

// ---------------- flash attention: 32x32 MFMA, in-register P, QBLK=128 --------
// (r3/r8-proven: ~111 us) LDS 32KiB: K dbuf 2x8K | V dbuf 2x8K. One barrier/iter.
__global__ __launch_bounds__(256, 4) void flash_attn(const bf16* __restrict__ QK,
                                                     const bf16* __restrict__ VT,
                                                     bf16* __restrict__ o)
{
    __shared__ bf16 lds[16384];          // 32 KiB: Ks[2][4096] | Vs[2][4096]

    const int t = threadIdx.x, w = t >> 6, lane = t & 63;
    const int l31 = lane & 31, hi = lane >> 5;
    const int j = blockIdx.x;
    const int hs = j & 63;               // head-set id (shares K/V)
    const int qt = j >> 6;               // 0..15 q-tile
    const int h = hs & 7, b = (hs >> 3) & 3, dir = hs >> 5;
    const long qrow0  = (long)dir * 8192 + b * 2048 + qt * 128;
    const long kvrow0 = (long)(1 - dir) * 8192 + b * 2048;
    const int hc = h * 64;

    // ---- Q stage: 128 rows x 64 d = 16KB into first half of LDS ----
#pragma unroll
    for (int i = 0; i < 4; i++) {
        int idx = i * 256 + t, row = idx >> 3, p = idx & 7;
        async16(lds + idx * 8, QK + (qrow0 + row) * 512 + hc + ((p ^ (row & 7)) * 8));
    }
    __syncthreads();
    bf16x8 qf[4];
    {
        int qrow = w * 32 + l31;
#pragma unroll
        for (int kd = 0; kd < 4; kd++)
            qf[kd] = *(const bf16x8*)(lds + qrow * 64 + (((kd * 2 + hi) ^ (qrow & 7)) * 8));
    }
    __syncthreads();  // all Q reads done before K/V loads overwrite

    // ---- prologue: issue K(0), V(0) into buffer 0 ----
#pragma unroll
    for (int i = 0; i < 2; i++) {
        int idx = i * 256 + t, row = idx >> 3, p = idx & 7;
        async16(lds + idx * 8, QK + (kvrow0 + row) * 512 + hc + ((p ^ (row & 7)) * 8));
    }
#pragma unroll
    for (int i = 0; i < 2; i++) {
        int idx = i * 256 + t, row = idx >> 3, p = idx & 7;
        async16(lds + 8192 + idx * 8, VT + (long)(hc + row) * 16384 + kvrow0 + ((p ^ (row & 7)) * 8));
    }

    f32x16 oacc[2] = {};
    f32x16 racc = {};
    bf16x8 ones;
#pragma unroll
    for (int k = 0; k < 8; k++) ones[k] = (bf16)1.0f;

    for (int kb = 0; kb < 32; kb++) {
        bf16* Kc = lds + (kb & 1) * 4096;
        bf16* Vc = lds + 8192 + (kb & 1) * 4096;

        asm volatile("s_waitcnt vmcnt(0)" ::: "memory");
        __builtin_amdgcn_s_barrier();

        if (kb < 31) {
            const long knext = kvrow0 + (kb + 1) * 64;
            bf16* Kn = lds + ((kb + 1) & 1) * 4096;
            bf16* Vn = lds + 8192 + ((kb + 1) & 1) * 4096;
#pragma unroll
            for (int i = 0; i < 2; i++) {
                int idx = i * 256 + t, row = idx >> 3, p = idx & 7;
                async16(Kn + idx * 8, QK + (knext + row) * 512 + hc + ((p ^ (row & 7)) * 8));
            }
#pragma unroll
            for (int i = 0; i < 2; i++) {
                int idx = i * 256 + t, row = idx >> 3, p = idx & 7;
                async16(Vn + idx * 8, VT + (long)(hc + row) * 16384 + knext + ((p ^ (row & 7)) * 8));
            }
        }

#pragma unroll
        for (int kb2 = 0; kb2 < 2; kb2++) {
            const int krow = kb2 * 32 + l31;
            const int ksw = krow & 7;
            bf16x8 kf0 = *(const bf16x8*)(Kc + krow * 64 + (((0 + hi) ^ ksw) * 8));
            bf16x8 kf1 = *(const bf16x8*)(Kc + krow * 64 + (((2 + hi) ^ ksw) * 8));
            bf16x8 kf2 = *(const bf16x8*)(Kc + krow * 64 + (((4 + hi) ^ ksw) * 8));
            bf16x8 kf3 = *(const bf16x8*)(Kc + krow * 64 + (((6 + hi) ^ ksw) * 8));

            f32x16 s0 = {};
            __builtin_amdgcn_s_setprio(1);
            s0 = mfma32(kf0, qf[0], s0);
            s0 = mfma32(kf1, qf[1], s0);
            s0 = mfma32(kf2, qf[2], s0);
            s0 = mfma32(kf3, qf[3], s0);
            __builtin_amdgcn_s_setprio(0);

#pragma unroll
            for (int r = 0; r < 16; r++) s0[r] = exp2f(s0[r]);

#pragma unroll
            for (int sh = 0; sh < 2; sh++) {
                const int ks = kb2 * 2 + sh;
                unsigned a00 = cvtpk(s0[8 * sh + 0], s0[8 * sh + 1]);
                unsigned a01 = cvtpk(s0[8 * sh + 2], s0[8 * sh + 3]);
                unsigned b00 = cvtpk(s0[8 * sh + 4], s0[8 * sh + 5]);
                unsigned b01 = cvtpk(s0[8 * sh + 6], s0[8 * sh + 7]);
                pl32(a00, b00); pl32(a01, b01);
                bf16x8 pa0 = mk8(a00, a01, b00, b01);

                __builtin_amdgcn_s_setprio(1);
#pragma unroll
                for (int db = 0; db < 2; db++) {
                    const int vrow = db * 32 + l31;
                    bf16x8 vf = *(const bf16x8*)(Vc + vrow * 64 + (((ks * 2 + hi) ^ (vrow & 7)) * 8));
                    oacc[db] = mfma32(pa0, vf, oacc[db]);
                }
                racc = mfma32(pa0, ones, racc);
                __builtin_amdgcn_s_setprio(0);
            }
        }
    }

#pragma unroll
    for (int reg = 0; reg < 16; reg++) {
        const int q = (reg & 3) + 8 * (reg >> 2) + 4 * hi;
        const float inv = 1.f / racc[reg];
        const long row = qrow0 + w * 32 + q;
#pragma unroll
        for (int db = 0; db < 2; db++)
            o[row * 1024 + hc + db * 32 + l31] = (bf16)(oacc[db][reg] * inv);
    }
}

// ---------------- LayerNorm + GELU (fast erf), in-place on bf16 [16384][1024]
__global__ __launch_bounds__(256) void ln_gelu(bf16* __restrict__ H,
                                               const float* __restrict__ g,
                                               const float* __restrict__ bta)
{
    const int row = blockIdx.x, t = threadIdx.x;
    const int w = t >> 6, lane = t & 63;
    bf16* hp = H + (long)row * 1024 + t * 4;
    bf16x4 hv = *(const bf16x4*)hp;
    float h[4];
#pragma unroll
    for (int j = 0; j < 4; j++) h[j] = (float)hv[j];
    float s1 = h[0] + h[1] + h[2] + h[3];
    float s2 = h[0] * h[0] + h[1] * h[1] + h[2] * h[2] + h[3] * h[3];
#pragma unroll
    for (int d = 1; d < 64; d <<= 1) {
        s1 += __shfl_xor(s1, d);
        s2 += __shfl_xor(s2, d);
    }
    __shared__ float rbuf[8];
    if (lane == 0) { rbuf[w] = s1; rbuf[4 + w] = s2; }
    __syncthreads();
    s1 = rbuf[0] + rbuf[1] + rbuf[2] + rbuf[3];
    s2 = rbuf[4] + rbuf[5] + rbuf[6] + rbuf[7];
    const float mu = s1 * (1.f / 1024.f);
    const float var = s2 * (1.f / 1024.f) - mu * mu;
    const float rstd = rsqrtf(var + 1e-5f);
    bf16x4 out;
#pragma unroll
    for (int j = 0; j < 4; j++) {
        int c = t * 4 + j;
        float x = (h[j] - mu) * rstd * g[c] + bta[c];
        float y = 0.5f * x * (1.f + erf_fast(x * 0.70710678118654752f));
        out[j] = (bf16)y;
    }
    *(bf16x4*)hp = out;
}

extern "C" void kernel_launch(void* const* d_in, const int* in_sizes, int n_in,
                              void* d_out, int out_size, void* d_ws, size_t ws_size,
                              hipStream_t stream)
{
    const float* x0  = (const float*)d_in[0];
    const float* x1  = (const float*)d_in[1];
    const float* Wqk = (const float*)d_in[2];
    const float* bqk = (const float*)d_in[3];
    const float* Wv  = (const float*)d_in[4];
    const float* bv  = (const float*)d_in[5];
    const float* Wo  = (const float*)d_in[6];
    const float* bo  = (const float*)d_in[7];
    const float* Wf1 = (const float*)d_in[8];
    const float* bf1 = (const float*)d_in[9];
    const float* lng = (const float*)d_in[10];
    const float* lnb = (const float*)d_in[11];
    const float* Wf2 = (const float*)d_in[12];
    const float* bf2 = (const float*)d_in[13];

    char* ws = (char*)d_ws;
    bf16* Xbf   = (bf16*)ws; ws += 16384L * 1024 * 2;  // [x | m] both streams
    bf16* QKbf  = (bf16*)ws;                            // qk projection (pre-scaled)
    bf16* Hbuf  = (bf16*)ws;                            // FFN1 out (aliases QKbf+VtG)
    ws += 16384L * 512 * 2;
    bf16* VtG   = (bf16*)ws; ws += 16384L * 512 * 2;   // v proj transposed [512][16384]
    bf16* Wqkv  = (bf16*)ws; ws += 1024L * 512 * 2;    // [Wqk; Wv] bf16
    bf16* Wbig  = (bf16*)ws; ws += 1024L * 1024 * 2;   // [Wf1L | Wcomb]
    bf16* Wf1Rb = (bf16*)ws; ws += 1024L * 512 * 2;
    bf16* Wf2b  = (bf16*)ws; ws += 512L * 1024 * 2;
    bf16* WoT   = (bf16*)ws; ws += 512L * 512 * 2;
    float* bf1p = (float*)ws; ws += 1024 * 4;

    // sqrt((1/8) * log2(e)) — applied to both q and k so scores carry (1/8)*log2(e)
    const float qs = 0.42466090014400953f;

    prep<<<10560, 256, 0, stream>>>(x0, x1, Xbf, Wqk, Wv, Wf1, Wf2,
                                    Wqkv, Wbig, Wf1Rb, Wf2b, Wo, WoT, bo, bf1, bf1p);

    // Wcomb = Wf1R @ Wo -> Wbig right half  [1024,512] = Wf1Rb @ WoT^T
    gemm_bt<4><<<32, 256, 0, stream>>>(Wf1Rb, 512, WoT, 512, nullptr,
                                       Wbig + 512, 1024, nullptr, nullptr,
                                       nullptr, nullptr, 1024, 512, 512, 1.f);

    // fused QKV projection: [16384,1024] = Xbf @ Wqkv^T (pipelined 256x256)
    pipe_gemm<5><<<256, 512, 0, stream>>>(Xbf, 1024, Wqkv, 512, bqk,
                                          QKbf, 512, bv, VtG,
                                          16384, 1024, 512, qs);

    // cross attention -> writes m-heads directly into Xbf right half (ld 1024)
    flash_attn<<<1024, 256, 0, stream>>>(QKbf, VtG, Xbf + 512);

    // FFN1 (Wo folded): [16384,1024] = [x|O] @ [Wf1L|Wcomb]^T + bf1' (pipelined)
    pipe_gemm<0><<<256, 512, 0, stream>>>(Xbf, 1024, Wbig, 1024, bf1p,
                                          Hbuf, 1024, nullptr, nullptr,
                                          16384, 1024, 1024, 1.f);
    ln_gelu<<<16384, 256, 0, stream>>>(Hbuf, lng, lnb);
    // FFN2 + bias + residual -> d_out (fp32), pipelined BM=128 BN=256
    pipe_ffn2<<<256, 512, 0, stream>>>(Hbuf, 1024, Wf2b, 1024, bf2,
                                       (float*)d_out, 512, x0, x1,
                                       16384, 512, 1024);
}

// Round 10
// 329.829 us; speedup vs baseline: 1.0936x; 1.0467x over previous
//
#include <hip/hip_runtime.h>
#include <hip/hip_bf16.h>
#include <math.h>

typedef __bf16 bf16;
typedef __bf16 bf16x8 __attribute__((ext_vector_type(8)));
typedef __bf16 bf16x4 __attribute__((ext_vector_type(4)));
typedef float  f32x4  __attribute__((ext_vector_type(4)));
typedef float  f32x16 __attribute__((ext_vector_type(16)));
typedef unsigned int u32x2 __attribute__((ext_vector_type(2)));

#define DEVI __device__ __forceinline__

DEVI void async16(bf16* lds, const bf16* g) {
    __builtin_amdgcn_global_load_lds(
        (const __attribute__((address_space(1))) unsigned int*)g,
        (__attribute__((address_space(3))) unsigned int*)lds, 16, 0, 0);
}
DEVI f32x4 mfma16(bf16x8 a, bf16x8 b, f32x4 c) {
    return __builtin_amdgcn_mfma_f32_16x16x32_bf16(a, b, c, 0, 0, 0);
}
DEVI f32x16 mfma32(bf16x8 a, bf16x8 b, f32x16 c) {
    return __builtin_amdgcn_mfma_f32_32x32x16_bf16(a, b, c, 0, 0, 0);
}
DEVI unsigned cvtpk(float lo, float hi) {
    unsigned r;
    asm("v_cvt_pk_bf16_f32 %0, %1, %2" : "=v"(r) : "v"(lo), "v"(hi));
    return r;
}
// v_permlane32_swap_b32: a' = [a.lo32, b.lo32], b' = [a.hi32, b.hi32]
DEVI void pl32(unsigned &a, unsigned &b) {
    u32x2 r = __builtin_amdgcn_permlane32_swap(a, b, false, false);
    a = r.x; b = r.y;
}
DEVI bf16x8 mk8(unsigned a0, unsigned a1, unsigned b0, unsigned b1) {
    union { unsigned u[4]; bf16x8 v; } U;
    U.u[0] = a0; U.u[1] = a1; U.u[2] = b0; U.u[3] = b1;
    return U.v;
}
// Abramowitz-Stegun 7.1.26 erf, |err| <= 1.5e-7 (vs libm branchy erff)
DEVI float erf_fast(float x) {
    float ax = fabsf(x);
    float t = 1.f / (1.f + 0.3275911f * ax);
    float y = t * (0.254829592f +
              t * (-0.284496736f +
              t * (1.421413741f +
              t * (-1.453152027f + t * 1.061405429f))));
    float e = __expf(-ax * ax);
    float r = 1.f - y * e;
    return (x < 0.f) ? -r : r;
}

// ---------------- fused prep: cvt_x + cvt_w + wo_t + bias_comb ----------------
__global__ __launch_bounds__(256) void prep(
    const float* __restrict__ x0, const float* __restrict__ x1, bf16* __restrict__ Xbf,
    const float* __restrict__ Wqk, const float* __restrict__ Wv,
    const float* __restrict__ Wf1, const float* __restrict__ Wf2,
    bf16* __restrict__ Wqkv, bf16* __restrict__ Wbig, bf16* __restrict__ Wf1Rb,
    bf16* __restrict__ Wf2b,
    const float* __restrict__ Wo, bf16* __restrict__ WoT,
    const float* __restrict__ bo, const float* __restrict__ bf1,
    float* __restrict__ bf1p)
{
    __shared__ float Ls[64][65];
    const int bid = blockIdx.x, t = threadIdx.x;
    if (bid < 8192) {
        long i = (long)bid * 256 + t;
        long r = i >> 7, c = (i & 127) * 4;
        const float* src = (r < 8192) ? (x0 + r * 512 + c) : (x1 + (r - 8192) * 512 + c);
        float4 v = *(const float4*)src;
        bf16x4 o;
        o[0] = (bf16)v.x; o[1] = (bf16)v.y; o[2] = (bf16)v.z; o[3] = (bf16)v.w;
        *(bf16x4*)(Xbf + r * 1024 + c) = o;
    } else if (bid < 10240) {
        long i = (long)(bid - 8192) * 256 + t;
        const float* s; bf16* d;
        if (i < 131072) {
            s = (i < 65536) ? Wqk + i * 4 : Wv + (i - 65536) * 4;
            d = Wqkv + i * 4;
        } else if (i < 393216) {
            long e = (i - 131072) * 4, r = e >> 10, c = e & 1023;
            s = Wf1 + e;
            d = (c < 512) ? (Wbig + r * 1024 + c) : (Wf1Rb + r * 512 + (c - 512));
        } else {
            s = Wf2 + (i - 393216) * 4;
            d = Wf2b + (i - 393216) * 4;
        }
        float4 v = *(const float4*)s;
        bf16x4 o;
        o[0] = (bf16)v.x; o[1] = (bf16)v.y; o[2] = (bf16)v.z; o[3] = (bf16)v.w;
        *(bf16x4*)d = o;
    } else if (bid < 10304) {
        const int bb = bid - 10240;
        const int bi = bb & 7, bj = bb >> 3;
        const int i0 = bi * 64, j0 = bj * 64;
        const int r0 = t >> 4, c4 = (t & 15) * 4;
#pragma unroll
        for (int it = 0; it < 4; it++) {
            int row = r0 + 16 * it;
            float4 v = *(const float4*)(Wo + (long)(i0 + row) * 512 + j0 + c4);
            Ls[row][c4] = v.x; Ls[row][c4 + 1] = v.y;
            Ls[row][c4 + 2] = v.z; Ls[row][c4 + 3] = v.w;
        }
        __syncthreads();
#pragma unroll
        for (int it = 0; it < 4; it++) {
            int orow = r0 + 16 * it;
            bf16x4 o;
#pragma unroll
            for (int k = 0; k < 4; k++) o[k] = (bf16)Ls[c4 + k][orow];
            *(bf16x4*)(WoT + (long)(j0 + orow) * 512 + i0 + c4) = o;
        }
    } else {
        const int w = t >> 6, lane = t & 63;
        const int row = (bid - 10304) * 4 + w;
        const float* rp = Wf1 + (long)row * 1024 + 512 + lane * 8;
        float4 a = *(const float4*)rp;
        float4 b = *(const float4*)(rp + 4);
        const float* bp = bo + lane * 8;
        float4 c = *(const float4*)bp;
        float4 d = *(const float4*)(bp + 4);
        float s = a.x * c.x + a.y * c.y + a.z * c.z + a.w * c.w +
                  b.x * d.x + b.y * d.y + b.z * d.z + b.w * d.w;
#pragma unroll
        for (int k = 1; k < 64; k <<= 1) s += __shfl_xor(s, k);
        if (lane == 0) bf1p[row] = bf1[row] + s;
    }
}

// ---------------- bf16 GEMM: C = A @ B^T, BK=64 swizzled (Wcomb only) ---------
template <int MODE>
__global__ __launch_bounds__(256) void gemm_bt(
    const bf16* __restrict__ A, long lda,
    const bf16* __restrict__ B, long ldb,
    const float* __restrict__ bias,
    void* __restrict__ Cout, long ldc,
    const float* __restrict__ res0, const float* __restrict__ res1,
    const float* __restrict__ bias2, void* __restrict__ Cout2,
    int M, int N, int K, float scale)
{
    __shared__ bf16 As[128 * 64];
    __shared__ bf16 Bs[128 * 64];
    const int t = threadIdx.x;
    const int w = t >> 6, lane = t & 63, quad = lane >> 4, m15 = lane & 15;
    const int wm = w >> 1, wn = w & 1;
    const int nbx = N >> 7;
    const int xcd = blockIdx.x & 7, local = blockIdx.x >> 3;
    const int mtiles_per_xcd = (int)(gridDim.x >> 3) / nbx;
    const int by = xcd * mtiles_per_xcd + local / nbx;
    const int bx = local % nbx;
    const long m0 = (long)by * 128, n0 = (long)bx * 128;

    f32x4 acc[4][4] = {};

    for (int k0 = 0; k0 < K; k0 += 64) {
#pragma unroll
        for (int i = 0; i < 4; i++) {
            int idx = i * 256 + t, row = idx >> 3, p = idx & 7;
            int gc = k0 + ((p ^ (row & 7)) * 8);
            async16(As + idx * 8, A + (m0 + row) * lda + gc);
            async16(Bs + idx * 8, B + (n0 + row) * ldb + gc);
        }
        __syncthreads();
#pragma unroll
        for (int kk = 0; kk < 2; kk++) {
            bf16x8 af[4], bfr[4];
#pragma unroll
            for (int mt = 0; mt < 4; mt++) {
                int row = wm * 64 + mt * 16 + m15;
                af[mt] = *(const bf16x8*)(As + row * 64 + (((kk * 4 + quad) ^ (row & 7)) * 8));
            }
#pragma unroll
            for (int nt = 0; nt < 4; nt++) {
                int row = wn * 64 + nt * 16 + m15;
                bfr[nt] = *(const bf16x8*)(Bs + row * 64 + (((kk * 4 + quad) ^ (row & 7)) * 8));
            }
#pragma unroll
            for (int mt = 0; mt < 4; mt++)
#pragma unroll
                for (int nt = 0; nt < 4; nt++)
                    acc[mt][nt] = mfma16(af[mt], bfr[nt], acc[mt][nt]);
        }
        __syncthreads();
    }

#pragma unroll
    for (int nt = 0; nt < 4; nt++) {
        long col = n0 + wn * 64 + nt * 16 + m15;
#pragma unroll
        for (int mt = 0; mt < 4; mt++) {
            long row = m0 + wm * 64 + mt * 16 + quad * 4;
            if (MODE == 4) {
                bf16* C = (bf16*)Cout;
#pragma unroll
                for (int r = 0; r < 4; r++)
                    C[(row + r) * ldc + col] = (bf16)acc[mt][nt][r];
            }
        }
    }
}

// ---------------- pipelined 256x256 GEMM: 16 waves, early stage issue ---------
// 1024 threads = 16 waves (4M x 4N), BM=BN=256, BK=64, LDS 128 KiB (2 slots).
// 1 block/CU but 16 waves = 4 waves/SIMD (r9 had 8 waves = 2/SIMD): barrier
// and vmcnt drains hide behind the other 3 SIMD-resident waves.
// Schedule/iter: vmcnt(4) [tile kt resident, kt+1's 4 loads in flight] ->
// barrier -> ksub0 reads+MFMA -> ksub1 reads -> lgkmcnt(0)+barrier -> issue
// stage(kt+2) -> ksub1 MFMA. Grid 256, N%256==0.
template <int MODE>
__global__ __launch_bounds__(1024, 4) void pipe_gemm(
    const bf16* __restrict__ A, long lda,
    const bf16* __restrict__ B, long ldb,
    const float* __restrict__ bias,
    void* __restrict__ Cout, long ldc,
    const float* __restrict__ bias2, void* __restrict__ Cout2,
    int M, int N, int K, float scale)
{
    __shared__ bf16 lds[65536];          // 128 KiB: As[2][16384] | Bs[2][16384]
    bf16* As = lds;
    bf16* Bs = lds + 32768;

    const int t = threadIdx.x;
    const int w = t >> 6, lane = t & 63, quad = lane >> 4, m15 = lane & 15;
    const int wm = w >> 2, wn = w & 3;           // 4 x 4 wave grid
    const int nbx = N >> 8;
    const int xcd = blockIdx.x & 7, local = blockIdx.x >> 3;
    const int mtiles_per_xcd = (int)(gridDim.x >> 3) / nbx;
    const int by = xcd * mtiles_per_xcd + local / nbx;
    const int bx = local % nbx;
    const long m0 = (long)by * 256, n0 = (long)bx * 256;
    const int nt = K >> 6;

    f32x4 acc[4][4] = {};

    // stage tile kt into slot kt&1: 4 async16/thread (2 A + 2 B)
    auto stage = [&](int kt) {
        const int slot = kt & 1;
        bf16* Ad = As + slot * 16384;
        bf16* Bd = Bs + slot * 16384;
        const int k0 = kt * 64;
#pragma unroll
        for (int i = 0; i < 2; i++) {
            int idx = i * 1024 + t, row = idx >> 3, p = idx & 7;
            int gc = k0 + ((p ^ (row & 7)) * 8);
            async16(Ad + idx * 8, A + (m0 + row) * lda + gc);
        }
#pragma unroll
        for (int i = 0; i < 2; i++) {
            int idx = i * 1024 + t, row = idx >> 3, p = idx & 7;
            int gc = k0 + ((p ^ (row & 7)) * 8);
            async16(Bd + idx * 8, B + (n0 + row) * ldb + gc);
        }
    };

    stage(0);
    stage(1);

    for (int kt = 0; kt < nt; kt++) {
        if (kt + 1 < nt) {
            asm volatile("s_waitcnt vmcnt(4)" ::: "memory");
        } else {
            asm volatile("s_waitcnt vmcnt(0)" ::: "memory");
        }
        __builtin_amdgcn_s_barrier();
        __builtin_amdgcn_sched_barrier(0);

        const bf16* Asl = As + (kt & 1) * 16384;
        const bf16* Bsl = Bs + (kt & 1) * 16384;

        // ---- ksub 0: reads + MFMA ----
        {
            bf16x8 af[4], bfr[4];
#pragma unroll
            for (int mf = 0; mf < 4; mf++) {
                int row = wm * 64 + mf * 16 + m15;
                af[mf] = *(const bf16x8*)(Asl + row * 64 + ((quad ^ (row & 7)) * 8));
            }
#pragma unroll
            for (int nf = 0; nf < 4; nf++) {
                int row = wn * 64 + nf * 16 + m15;
                bfr[nf] = *(const bf16x8*)(Bsl + row * 64 + ((quad ^ (row & 7)) * 8));
            }
            __builtin_amdgcn_s_setprio(1);
#pragma unroll
            for (int mf = 0; mf < 4; mf++)
#pragma unroll
                for (int nf = 0; nf < 4; nf++)
                    acc[mf][nf] = mfma16(af[mf], bfr[nf], acc[mf][nf]);
            __builtin_amdgcn_s_setprio(0);
        }

        // ---- ksub 1: reads, free the slot, early stage, MFMA ----
        {
            bf16x8 af[4], bfr[4];
#pragma unroll
            for (int mf = 0; mf < 4; mf++) {
                int row = wm * 64 + mf * 16 + m15;
                af[mf] = *(const bf16x8*)(Asl + row * 64 + (((4 + quad) ^ (row & 7)) * 8));
            }
#pragma unroll
            for (int nf = 0; nf < 4; nf++) {
                int row = wn * 64 + nf * 16 + m15;
                bfr[nf] = *(const bf16x8*)(Bsl + row * 64 + (((4 + quad) ^ (row & 7)) * 8));
            }
            asm volatile("s_waitcnt lgkmcnt(0)" ::: "memory");
            __builtin_amdgcn_sched_barrier(0);
            __builtin_amdgcn_s_barrier();     // all waves done reading this slot
            __builtin_amdgcn_sched_barrier(0);
            if (kt + 2 < nt) stage(kt + 2);   // overwrite slot while MFMA runs
            __builtin_amdgcn_s_setprio(1);
#pragma unroll
            for (int mf = 0; mf < 4; mf++)
#pragma unroll
                for (int nf = 0; nf < 4; nf++)
                    acc[mf][nf] = mfma16(af[mf], bfr[nf], acc[mf][nf]);
            __builtin_amdgcn_s_setprio(0);
        }
    }

#pragma unroll
    for (int nf = 0; nf < 4; nf++) {
        long col = n0 + wn * 64 + nf * 16 + m15;
#pragma unroll
        for (int mf = 0; mf < 4; mf++) {
            long row = m0 + wm * 64 + mf * 16 + quad * 4;
            if (MODE == 0) {
                bf16* C = (bf16*)Cout;
                float bs = bias[col];
#pragma unroll
                for (int r = 0; r < 4; r++)
                    C[(row + r) * ldc + col] = (bf16)(acc[mf][nf][r] + bs);
            } else {  // MODE 5
                if (col < 512) {
                    bf16* C = (bf16*)Cout;
                    float bs = bias[col];
#pragma unroll
                    for (int r = 0; r < 4; r++)
                        C[(row + r) * ldc + col] = (bf16)((acc[mf][nf][r] + bs) * scale);
                } else {
                    bf16* V = (bf16*)Cout2;
                    long v = col - 512;
                    float bs = bias2[v];
                    bf16x4 pv;
#pragma unroll
                    for (int r = 0; r < 4; r++) pv[r] = (bf16)(acc[mf][nf][r] + bs);
                    *(bf16x4*)(V + v * 16384 + row) = pv;
                }
            }
        }
    }
}

// ---------------- pipelined FFN2: BM=128 BN=256, 16 waves, fp32 out ----------
// 1024 threads = 16 waves (4M x 4N), per-wave 32x64 output. vmcnt(3)
// (stage = 1 A + 2 B per thread). Same early-stage-issue schedule.
__global__ __launch_bounds__(1024, 4) void pipe_ffn2(
    const bf16* __restrict__ A, long lda,
    const bf16* __restrict__ B, long ldb,
    const float* __restrict__ bias,
    float* __restrict__ C, long ldc,
    const float* __restrict__ res0, const float* __restrict__ res1,
    int M, int N, int K)
{
    __shared__ bf16 lds[49152];          // 96 KiB: As[2][8192] | Bs[2][16384]
    bf16* As = lds;                      // 128 x 64 per slot
    bf16* Bs = lds + 16384;              // 256 x 64 per slot

    const int t = threadIdx.x;
    const int w = t >> 6, lane = t & 63, quad = lane >> 4, m15 = lane & 15;
    const int wm = w >> 2, wn = w & 3;   // 4 x 4 wave grid
    const int nbx = N >> 8;              // 2
    const int xcd = blockIdx.x & 7, local = blockIdx.x >> 3;
    const int mtiles_per_xcd = (int)(gridDim.x >> 3) / nbx;
    const int by = xcd * mtiles_per_xcd + local / nbx;
    const int bx = local % nbx;
    const long m0 = (long)by * 128, n0 = (long)bx * 256;
    const int nt = K >> 6;

    f32x4 acc[2][4] = {};

    auto stage = [&](int kt) {
        const int slot = kt & 1;
        bf16* Ad = As + slot * 8192;
        bf16* Bd = Bs + slot * 16384;
        const int k0 = kt * 64;
        {
            int idx = t, row = idx >> 3, p = idx & 7;
            int gc = k0 + ((p ^ (row & 7)) * 8);
            async16(Ad + idx * 8, A + (m0 + row) * lda + gc);
        }
#pragma unroll
        for (int i = 0; i < 2; i++) {
            int idx = i * 1024 + t, row = idx >> 3, p = idx & 7;
            int gc = k0 + ((p ^ (row & 7)) * 8);
            async16(Bd + idx * 8, B + (n0 + row) * ldb + gc);
        }
    };

    stage(0);
    stage(1);

    for (int kt = 0; kt < nt; kt++) {
        if (kt + 1 < nt) {
            asm volatile("s_waitcnt vmcnt(3)" ::: "memory");
        } else {
            asm volatile("s_waitcnt vmcnt(0)" ::: "memory");
        }
        __builtin_amdgcn_s_barrier();
        __builtin_amdgcn_sched_barrier(0);

        const bf16* Asl = As + (kt & 1) * 8192;
        const bf16* Bsl = Bs + (kt & 1) * 16384;

        // ---- ksub 0 ----
        {
            bf16x8 af[2], bfr[4];
#pragma unroll
            for (int mf = 0; mf < 2; mf++) {
                int row = wm * 32 + mf * 16 + m15;
                af[mf] = *(const bf16x8*)(Asl + row * 64 + ((quad ^ (row & 7)) * 8));
            }
#pragma unroll
            for (int nf = 0; nf < 4; nf++) {
                int row = wn * 64 + nf * 16 + m15;
                bfr[nf] = *(const bf16x8*)(Bsl + row * 64 + ((quad ^ (row & 7)) * 8));
            }
            __builtin_amdgcn_s_setprio(1);
#pragma unroll
            for (int mf = 0; mf < 2; mf++)
#pragma unroll
                for (int nf = 0; nf < 4; nf++)
                    acc[mf][nf] = mfma16(af[mf], bfr[nf], acc[mf][nf]);
            __builtin_amdgcn_s_setprio(0);
        }

        // ---- ksub 1 with early stage issue ----
        {
            bf16x8 af[2], bfr[4];
#pragma unroll
            for (int mf = 0; mf < 2; mf++) {
                int row = wm * 32 + mf * 16 + m15;
                af[mf] = *(const bf16x8*)(Asl + row * 64 + (((4 + quad) ^ (row & 7)) * 8));
            }
#pragma unroll
            for (int nf = 0; nf < 4; nf++) {
                int row = wn * 64 + nf * 16 + m15;
                bfr[nf] = *(const bf16x8*)(Bsl + row * 64 + (((4 + quad) ^ (row & 7)) * 8));
            }
            asm volatile("s_waitcnt lgkmcnt(0)" ::: "memory");
            __builtin_amdgcn_sched_barrier(0);
            __builtin_amdgcn_s_barrier();
            __builtin_amdgcn_sched_barrier(0);
            if (kt + 2 < nt) stage(kt + 2);
            __builtin_amdgcn_s_setprio(1);
#pragma unroll
            for (int mf = 0; mf < 2; mf++)
#pragma unroll
                for (int nf = 0; nf < 4; nf++)
                    acc[mf][nf] = mfma16(af[mf], bfr[nf], acc[mf][nf]);
            __builtin_amdgcn_s_setprio(0);
        }
    }

#pragma unroll
    for (int nf = 0; nf < 4; nf++) {
        long col = n0 + wn * 64 + nf * 16 + m15;
        float bs = bias[col];
#pragma unroll
        for (int mf = 0; mf < 2; mf++) {
            long row = m0 + wm * 32 + mf * 16 + quad * 4;
#pragma unroll
            for (int r = 0; r < 4; r++) {
                long grow = row + r;
                const float* rs = (grow < 8192) ? (res0 + grow * 512)
                                                : (res1 + (grow - 8192) * 512);
                C[grow * ldc + col] = acc[mf][nf][r] + bs + rs[col];
            }
        }
    }
}

// ---------------- flash attention: 32x32 MFMA, in-register P, QBLK=128 --------
// (r3/r8-proven: ~111 us) LDS 32KiB: K dbuf 2x8K | V dbuf 2x8K. One barrier/iter.
__global__ __launch_bounds__(256, 4) void flash_attn(const bf16* __restrict__ QK,
                                                     const bf16* __restrict__ VT,
                                                     bf16* __restrict__ o)
{
    __shared__ bf16 lds[16384];          // 32 KiB: Ks[2][4096] | Vs[2][4096]

    const int t = threadIdx.x, w = t >> 6, lane = t & 63;
    const int l31 = lane & 31, hi = lane >> 5;
    const int j = blockIdx.x;
    const int hs = j & 63;               // head-set id (shares K/V)
    const int qt = j >> 6;               // 0..15 q-tile
    const int h = hs & 7, b = (hs >> 3) & 3, dir = hs >> 5;
    const long qrow0  = (long)dir * 8192 + b * 2048 + qt * 128;
    const long kvrow0 = (long)(1 - dir) * 8192 + b * 2048;
    const int hc = h * 64;

    // ---- Q stage: 128 rows x 64 d = 16KB into first half of LDS ----
#pragma unroll
    for (int i = 0; i < 4; i++) {
        int idx = i * 256 + t, row = idx >> 3, p = idx & 7;
        async16(lds + idx * 8, QK + (qrow0 + row) * 512 + hc + ((p ^ (row & 7)) * 8));
    }
    __syncthreads();
    bf16x8 qf[4];
    {
        int qrow = w * 32 + l31;
#pragma unroll
        for (int kd = 0; kd < 4; kd++)
            qf[kd] = *(const bf16x8*)(lds + qrow * 64 + (((kd * 2 + hi) ^ (qrow & 7)) * 8));
    }
    __syncthreads();  // all Q reads done before K/V loads overwrite

    // ---- prologue: issue K(0), V(0) into buffer 0 ----
#pragma unroll
    for (int i = 0; i < 2; i++) {
        int idx = i * 256 + t, row = idx >> 3, p = idx & 7;
        async16(lds + idx * 8, QK + (kvrow0 + row) * 512 + hc + ((p ^ (row & 7)) * 8));
    }
#pragma unroll
    for (int i = 0; i < 2; i++) {
        int idx = i * 256 + t, row = idx >> 3, p = idx & 7;
        async16(lds + 8192 + idx * 8, VT + (long)(hc + row) * 16384 + kvrow0 + ((p ^ (row & 7)) * 8));
    }

    f32x16 oacc[2] = {};
    f32x16 racc = {};
    bf16x8 ones;
#pragma unroll
    for (int k = 0; k < 8; k++) ones[k] = (bf16)1.0f;

    for (int kb = 0; kb < 32; kb++) {
        bf16* Kc = lds + (kb & 1) * 4096;
        bf16* Vc = lds + 8192 + (kb & 1) * 4096;

        asm volatile("s_waitcnt vmcnt(0)" ::: "memory");
        __builtin_amdgcn_s_barrier();

        if (kb < 31) {
            const long knext = kvrow0 + (kb + 1) * 64;
            bf16* Kn = lds + ((kb + 1) & 1) * 4096;
            bf16* Vn = lds + 8192 + ((kb + 1) & 1) * 4096;
#pragma unroll
            for (int i = 0; i < 2; i++) {
                int idx = i * 256 + t, row = idx >> 3, p = idx & 7;
                async16(Kn + idx * 8, QK + (knext + row) * 512 + hc + ((p ^ (row & 7)) * 8));
            }
#pragma unroll
            for (int i = 0; i < 2; i++) {
                int idx = i * 256 + t, row = idx >> 3, p = idx & 7;
                async16(Vn + idx * 8, VT + (long)(hc + row) * 16384 + knext + ((p ^ (row & 7)) * 8));
            }
        }

#pragma unroll
        for (int kb2 = 0; kb2 < 2; kb2++) {
            const int krow = kb2 * 32 + l31;
            const int ksw = krow & 7;
            bf16x8 kf0 = *(const bf16x8*)(Kc + krow * 64 + (((0 + hi) ^ ksw) * 8));
            bf16x8 kf1 = *(const bf16x8*)(Kc + krow * 64 + (((2 + hi) ^ ksw) * 8));
            bf16x8 kf2 = *(const bf16x8*)(Kc + krow * 64 + (((4 + hi) ^ ksw) * 8));
            bf16x8 kf3 = *(const bf16x8*)(Kc + krow * 64 + (((6 + hi) ^ ksw) * 8));

            f32x16 s0 = {};
            __builtin_amdgcn_s_setprio(1);
            s0 = mfma32(kf0, qf[0], s0);
            s0 = mfma32(kf1, qf[1], s0);
            s0 = mfma32(kf2, qf[2], s0);
            s0 = mfma32(kf3, qf[3], s0);
            __builtin_amdgcn_s_setprio(0);

#pragma unroll
            for (int r = 0; r < 16; r++) s0[r] = exp2f(s0[r]);

#pragma unroll
            for (int sh = 0; sh < 2; sh++) {
                const int ks = kb2 * 2 + sh;
                unsigned a00 = cvtpk(s0[8 * sh + 0], s0[8 * sh + 1]);
                unsigned a01 = cvtpk(s0[8 * sh + 2], s0[8 * sh + 3]);
                unsigned b00 = cvtpk(s0[8 * sh + 4], s0[8 * sh + 5]);
                unsigned b01 = cvtpk(s0[8 * sh + 6], s0[8 * sh + 7]);
                pl32(a00, b00); pl32(a01, b01);
                bf16x8 pa0 = mk8(a00, a01, b00, b01);

                __builtin_amdgcn_s_setprio(1);
#pragma unroll
                for (int db = 0; db < 2; db++) {
                    const int vrow = db * 32 + l31;
                    bf16x8 vf = *(const bf16x8*)(Vc + vrow * 64 + (((ks * 2 + hi) ^ (vrow & 7)) * 8));
                    oacc[db] = mfma32(pa0, vf, oacc[db]);
                }
                racc = mfma32(pa0, ones, racc);
                __builtin_amdgcn_s_setprio(0);
            }
        }
    }

#pragma unroll
    for (int reg = 0; reg < 16; reg++) {
        const int q = (reg & 3) + 8 * (reg >> 2) + 4 * hi;
        const float inv = 1.f / racc[reg];
        const long row = qrow0 + w * 32 + q;
#pragma unroll
        for (int db = 0; db < 2; db++)
            o[row * 1024 + hc + db * 32 + l31] = (bf16)(oacc[db][reg] * inv);
    }
}

// ---------------- LayerNorm + GELU (fast erf), in-place on bf16 [16384][1024]
__global__ __launch_bounds__(256) void ln_gelu(bf16* __restrict__ H,
                                               const float* __restrict__ g,
                                               const float* __restrict__ bta)
{
    const int row = blockIdx.x, t = threadIdx.x;
    const int w = t >> 6, lane = t & 63;
    bf16* hp = H + (long)row * 1024 + t * 4;
    bf16x4 hv = *(const bf16x4*)hp;
    float h[4];
#pragma unroll
    for (int j = 0; j < 4; j++) h[j] = (float)hv[j];
    float s1 = h[0] + h[1] + h[2] + h[3];
    float s2 = h[0] * h[0] + h[1] * h[1] + h[2] * h[2] + h[3] * h[3];
#pragma unroll
    for (int d = 1; d < 64; d <<= 1) {
        s1 += __shfl_xor(s1, d);
        s2 += __shfl_xor(s2, d);
    }
    __shared__ float rbuf[8];
    if (lane == 0) { rbuf[w] = s1; rbuf[4 + w] = s2; }
    __syncthreads();
    s1 = rbuf[0] + rbuf[1] + rbuf[2] + rbuf[3];
    s2 = rbuf[4] + rbuf[5] + rbuf[6] + rbuf[7];
    const float mu = s1 * (1.f / 1024.f);
    const float var = s2 * (1.f / 1024.f) - mu * mu;
    const float rstd = rsqrtf(var + 1e-5f);
    bf16x4 out;
#pragma unroll
    for (int j = 0; j < 4; j++) {
        int c = t * 4 + j;
        float x = (h[j] - mu) * rstd * g[c] + bta[c];
        float y = 0.5f * x * (1.f + erf_fast(x * 0.70710678118654752f));
        out[j] = (bf16)y;
    }
    *(bf16x4*)hp = out;
}

extern "C" void kernel_launch(void* const* d_in, const int* in_sizes, int n_in,
                              void* d_out, int out_size, void* d_ws, size_t ws_size,
                              hipStream_t stream)
{
    const float* x0  = (const float*)d_in[0];
    const float* x1  = (const float*)d_in[1];
    const float* Wqk = (const float*)d_in[2];
    const float* bqk = (const float*)d_in[3];
    const float* Wv  = (const float*)d_in[4];
    const float* bv  = (const float*)d_in[5];
    const float* Wo  = (const float*)d_in[6];
    const float* bo  = (const float*)d_in[7];
    const float* Wf1 = (const float*)d_in[8];
    const float* bf1 = (const float*)d_in[9];
    const float* lng = (const float*)d_in[10];
    const float* lnb = (const float*)d_in[11];
    const float* Wf2 = (const float*)d_in[12];
    const float* bf2 = (const float*)d_in[13];

    char* ws = (char*)d_ws;
    bf16* Xbf   = (bf16*)ws; ws += 16384L * 1024 * 2;  // [x | m] both streams
    bf16* QKbf  = (bf16*)ws;                            // qk projection (pre-scaled)
    bf16* Hbuf  = (bf16*)ws;                            // FFN1 out (aliases QKbf+VtG)
    ws += 16384L * 512 * 2;
    bf16* VtG   = (bf16*)ws; ws += 16384L * 512 * 2;   // v proj transposed [512][16384]
    bf16* Wqkv  = (bf16*)ws; ws += 1024L * 512 * 2;    // [Wqk; Wv] bf16
    bf16* Wbig  = (bf16*)ws; ws += 1024L * 1024 * 2;   // [Wf1L | Wcomb]
    bf16* Wf1Rb = (bf16*)ws; ws += 1024L * 512 * 2;
    bf16* Wf2b  = (bf16*)ws; ws += 512L * 1024 * 2;
    bf16* WoT   = (bf16*)ws; ws += 512L * 512 * 2;
    float* bf1p = (float*)ws; ws += 1024 * 4;

    // sqrt((1/8) * log2(e)) — applied to both q and k so scores carry (1/8)*log2(e)
    const float qs = 0.42466090014400953f;

    prep<<<10560, 256, 0, stream>>>(x0, x1, Xbf, Wqk, Wv, Wf1, Wf2,
                                    Wqkv, Wbig, Wf1Rb, Wf2b, Wo, WoT, bo, bf1, bf1p);

    // Wcomb = Wf1R @ Wo -> Wbig right half  [1024,512] = Wf1Rb @ WoT^T
    gemm_bt<4><<<32, 256, 0, stream>>>(Wf1Rb, 512, WoT, 512, nullptr,
                                       Wbig + 512, 1024, nullptr, nullptr,
                                       nullptr, nullptr, 1024, 512, 512, 1.f);

    // fused QKV projection: [16384,1024] = Xbf @ Wqkv^T (256x256, 16 waves)
    pipe_gemm<5><<<256, 1024, 0, stream>>>(Xbf, 1024, Wqkv, 512, bqk,
                                           QKbf, 512, bv, VtG,
                                           16384, 1024, 512, qs);

    // cross attention -> writes m-heads directly into Xbf right half (ld 1024)
    flash_attn<<<1024, 256, 0, stream>>>(QKbf, VtG, Xbf + 512);

    // FFN1 (Wo folded): [16384,1024] = [x|O] @ [Wf1L|Wcomb]^T + bf1'
    pipe_gemm<0><<<256, 1024, 0, stream>>>(Xbf, 1024, Wbig, 1024, bf1p,
                                           Hbuf, 1024, nullptr, nullptr,
                                           16384, 1024, 1024, 1.f);
    ln_gelu<<<16384, 256, 0, stream>>>(Hbuf, lng, lnb);
    // FFN2 + bias + residual -> d_out (fp32), BM=128 BN=256, 16 waves
    pipe_ffn2<<<256, 1024, 0, stream>>>(Hbuf, 1024, Wf2b, 1024, bf2,
                                        (float*)d_out, 512, x0, x1,
                                        16384, 512, 1024);
}

// Round 11
// 319.050 us; speedup vs baseline: 1.1305x; 1.0338x over previous
//
#include <hip/hip_runtime.h>
#include <hip/hip_bf16.h>
#include <math.h>

typedef __bf16 bf16;
typedef __bf16 bf16x8 __attribute__((ext_vector_type(8)));
typedef __bf16 bf16x4 __attribute__((ext_vector_type(4)));
typedef float  f32x4  __attribute__((ext_vector_type(4)));
typedef float  f32x16 __attribute__((ext_vector_type(16)));
typedef unsigned int u32x2 __attribute__((ext_vector_type(2)));

#define DEVI __device__ __forceinline__

DEVI void async16(bf16* lds, const bf16* g) {
    __builtin_amdgcn_global_load_lds(
        (const __attribute__((address_space(1))) unsigned int*)g,
        (__attribute__((address_space(3))) unsigned int*)lds, 16, 0, 0);
}
DEVI f32x4 mfma16(bf16x8 a, bf16x8 b, f32x4 c) {
    return __builtin_amdgcn_mfma_f32_16x16x32_bf16(a, b, c, 0, 0, 0);
}
DEVI f32x16 mfma32(bf16x8 a, bf16x8 b, f32x16 c) {
    return __builtin_amdgcn_mfma_f32_32x32x16_bf16(a, b, c, 0, 0, 0);
}
DEVI unsigned cvtpk(float lo, float hi) {
    unsigned r;
    asm("v_cvt_pk_bf16_f32 %0, %1, %2" : "=v"(r) : "v"(lo), "v"(hi));
    return r;
}
// v_permlane32_swap_b32: a' = [a.lo32, b.lo32], b' = [a.hi32, b.hi32]
DEVI void pl32(unsigned &a, unsigned &b) {
    u32x2 r = __builtin_amdgcn_permlane32_swap(a, b, false, false);
    a = r.x; b = r.y;
}
DEVI bf16x8 mk8(unsigned a0, unsigned a1, unsigned b0, unsigned b1) {
    union { unsigned u[4]; bf16x8 v; } U;
    U.u[0] = a0; U.u[1] = a1; U.u[2] = b0; U.u[3] = b1;
    return U.v;
}
// Abramowitz-Stegun 7.1.26 erf, |err| <= 1.5e-7 (vs libm branchy erff)
DEVI float erf_fast(float x) {
    float ax = fabsf(x);
    float t = 1.f / (1.f + 0.3275911f * ax);
    float y = t * (0.254829592f +
              t * (-0.284496736f +
              t * (1.421413741f +
              t * (-1.453152027f + t * 1.061405429f))));
    float e = __expf(-ax * ax);
    float r = 1.f - y * e;
    return (x < 0.f) ? -r : r;
}

// ---------------- fused prep: cvt_x + cvt_w + wo_t + bias_comb ----------------
__global__ __launch_bounds__(256) void prep(
    const float* __restrict__ x0, const float* __restrict__ x1, bf16* __restrict__ Xbf,
    const float* __restrict__ Wqk, const float* __restrict__ Wv,
    const float* __restrict__ Wf1, const float* __restrict__ Wf2,
    bf16* __restrict__ Wqkv, bf16* __restrict__ Wbig, bf16* __restrict__ Wf1Rb,
    bf16* __restrict__ Wf2b,
    const float* __restrict__ Wo, bf16* __restrict__ WoT,
    const float* __restrict__ bo, const float* __restrict__ bf1,
    float* __restrict__ bf1p)
{
    __shared__ float Ls[64][65];
    const int bid = blockIdx.x, t = threadIdx.x;
    if (bid < 8192) {
        long i = (long)bid * 256 + t;
        long r = i >> 7, c = (i & 127) * 4;
        const float* src = (r < 8192) ? (x0 + r * 512 + c) : (x1 + (r - 8192) * 512 + c);
        float4 v = *(const float4*)src;
        bf16x4 o;
        o[0] = (bf16)v.x; o[1] = (bf16)v.y; o[2] = (bf16)v.z; o[3] = (bf16)v.w;
        *(bf16x4*)(Xbf + r * 1024 + c) = o;
    } else if (bid < 10240) {
        long i = (long)(bid - 8192) * 256 + t;
        const float* s; bf16* d;
        if (i < 131072) {
            s = (i < 65536) ? Wqk + i * 4 : Wv + (i - 65536) * 4;
            d = Wqkv + i * 4;
        } else if (i < 393216) {
            long e = (i - 131072) * 4, r = e >> 10, c = e & 1023;
            s = Wf1 + e;
            d = (c < 512) ? (Wbig + r * 1024 + c) : (Wf1Rb + r * 512 + (c - 512));
        } else {
            s = Wf2 + (i - 393216) * 4;
            d = Wf2b + (i - 393216) * 4;
        }
        float4 v = *(const float4*)s;
        bf16x4 o;
        o[0] = (bf16)v.x; o[1] = (bf16)v.y; o[2] = (bf16)v.z; o[3] = (bf16)v.w;
        *(bf16x4*)d = o;
    } else if (bid < 10304) {
        const int bb = bid - 10240;
        const int bi = bb & 7, bj = bb >> 3;
        const int i0 = bi * 64, j0 = bj * 64;
        const int r0 = t >> 4, c4 = (t & 15) * 4;
#pragma unroll
        for (int it = 0; it < 4; it++) {
            int row = r0 + 16 * it;
            float4 v = *(const float4*)(Wo + (long)(i0 + row) * 512 + j0 + c4);
            Ls[row][c4] = v.x; Ls[row][c4 + 1] = v.y;
            Ls[row][c4 + 2] = v.z; Ls[row][c4 + 3] = v.w;
        }
        __syncthreads();
#pragma unroll
        for (int it = 0; it < 4; it++) {
            int orow = r0 + 16 * it;
            bf16x4 o;
#pragma unroll
            for (int k = 0; k < 4; k++) o[k] = (bf16)Ls[c4 + k][orow];
            *(bf16x4*)(WoT + (long)(j0 + orow) * 512 + i0 + c4) = o;
        }
    } else {
        const int w = t >> 6, lane = t & 63;
        const int row = (bid - 10304) * 4 + w;
        const float* rp = Wf1 + (long)row * 1024 + 512 + lane * 8;
        float4 a = *(const float4*)rp;
        float4 b = *(const float4*)(rp + 4);
        const float* bp = bo + lane * 8;
        float4 c = *(const float4*)bp;
        float4 d = *(const float4*)(bp + 4);
        float s = a.x * c.x + a.y * c.y + a.z * c.z + a.w * c.w +
                  b.x * d.x + b.y * d.y + b.z * d.z + b.w * d.w;
#pragma unroll
        for (int k = 1; k < 64; k <<= 1) s += __shfl_xor(s, k);
        if (lane == 0) bf1p[row] = bf1[row] + s;
    }
}

// ---------------- bf16 GEMM: C = A @ B^T, BK=64 swizzled (Wcomb only) ---------
template <int MODE>
__global__ __launch_bounds__(256) void gemm_bt(
    const bf16* __restrict__ A, long lda,
    const bf16* __restrict__ B, long ldb,
    const float* __restrict__ bias,
    void* __restrict__ Cout, long ldc,
    const float* __restrict__ res0, const float* __restrict__ res1,
    const float* __restrict__ bias2, void* __restrict__ Cout2,
    int M, int N, int K, float scale)
{
    __shared__ bf16 As[128 * 64];
    __shared__ bf16 Bs[128 * 64];
    const int t = threadIdx.x;
    const int w = t >> 6, lane = t & 63, quad = lane >> 4, m15 = lane & 15;
    const int wm = w >> 1, wn = w & 1;
    const int nbx = N >> 7;
    const int xcd = blockIdx.x & 7, local = blockIdx.x >> 3;
    const int mtiles_per_xcd = (int)(gridDim.x >> 3) / nbx;
    const int by = xcd * mtiles_per_xcd + local / nbx;
    const int bx = local % nbx;
    const long m0 = (long)by * 128, n0 = (long)bx * 128;

    f32x4 acc[4][4] = {};

    for (int k0 = 0; k0 < K; k0 += 64) {
#pragma unroll
        for (int i = 0; i < 4; i++) {
            int idx = i * 256 + t, row = idx >> 3, p = idx & 7;
            int gc = k0 + ((p ^ (row & 7)) * 8);
            async16(As + idx * 8, A + (m0 + row) * lda + gc);
            async16(Bs + idx * 8, B + (n0 + row) * ldb + gc);
        }
        __syncthreads();
#pragma unroll
        for (int kk = 0; kk < 2; kk++) {
            bf16x8 af[4], bfr[4];
#pragma unroll
            for (int mt = 0; mt < 4; mt++) {
                int row = wm * 64 + mt * 16 + m15;
                af[mt] = *(const bf16x8*)(As + row * 64 + (((kk * 4 + quad) ^ (row & 7)) * 8));
            }
#pragma unroll
            for (int nt = 0; nt < 4; nt++) {
                int row = wn * 64 + nt * 16 + m15;
                bfr[nt] = *(const bf16x8*)(Bs + row * 64 + (((kk * 4 + quad) ^ (row & 7)) * 8));
            }
#pragma unroll
            for (int mt = 0; mt < 4; mt++)
#pragma unroll
                for (int nt = 0; nt < 4; nt++)
                    acc[mt][nt] = mfma16(af[mt], bfr[nt], acc[mt][nt]);
        }
        __syncthreads();
    }

#pragma unroll
    for (int nt = 0; nt < 4; nt++) {
        long col = n0 + wn * 64 + nt * 16 + m15;
#pragma unroll
        for (int mt = 0; mt < 4; mt++) {
            long row = m0 + wm * 64 + mt * 16 + quad * 4;
            if (MODE == 4) {
                bf16* C = (bf16*)Cout;
#pragma unroll
                for (int r = 0; r < 4; r++)
                    C[(row + r) * ldc + col] = (bf16)acc[mt][nt][r];
            }
        }
    }
}

// ---------------- pipelined 256x256 GEMM: 16 waves, 32x32 MFMA ----------------
// 1024 threads = 16 waves (4M x 4N), per-wave 64x64 via 2x2 mfma32 blocks.
// Same schedule as r10 (counted vmcnt(4), early stage issue): only the MFMA
// shape changed -> half the MFMA instructions, ~17% fewer matrix-pipe cycles
// (m119: 32x32x16 = 8.07cyc/32kFLOP vs 16x16x32 = 4.85cyc/16kFLOP).
// Fragment addressing + C/D layout identical to flash's verified kf/oacc.
// Grid 256, N%256==0.
template <int MODE>
__global__ __launch_bounds__(1024, 4) void pipe_gemm(
    const bf16* __restrict__ A, long lda,
    const bf16* __restrict__ B, long ldb,
    const float* __restrict__ bias,
    void* __restrict__ Cout, long ldc,
    const float* __restrict__ bias2, void* __restrict__ Cout2,
    int M, int N, int K, float scale)
{
    __shared__ bf16 lds[65536];          // 128 KiB: As[2][16384] | Bs[2][16384]
    bf16* As = lds;
    bf16* Bs = lds + 32768;

    const int t = threadIdx.x;
    const int w = t >> 6, lane = t & 63;
    const int l31 = lane & 31, hi = lane >> 5;
    const int wm = w >> 2, wn = w & 3;           // 4 x 4 wave grid
    const int nbx = N >> 8;
    const int xcd = blockIdx.x & 7, local = blockIdx.x >> 3;
    const int mtiles_per_xcd = (int)(gridDim.x >> 3) / nbx;
    const int by = xcd * mtiles_per_xcd + local / nbx;
    const int bx = local % nbx;
    const long m0 = (long)by * 256, n0 = (long)bx * 256;
    const int nt = K >> 6;

    f32x16 acc[2][2] = {};               // [mb][nb], each 32x32

    // stage tile kt into slot kt&1: 4 async16/thread (2 A + 2 B)
    auto stage = [&](int kt) {
        const int slot = kt & 1;
        bf16* Ad = As + slot * 16384;
        bf16* Bd = Bs + slot * 16384;
        const int k0 = kt * 64;
#pragma unroll
        for (int i = 0; i < 2; i++) {
            int idx = i * 1024 + t, row = idx >> 3, p = idx & 7;
            int gc = k0 + ((p ^ (row & 7)) * 8);
            async16(Ad + idx * 8, A + (m0 + row) * lda + gc);
        }
#pragma unroll
        for (int i = 0; i < 2; i++) {
            int idx = i * 1024 + t, row = idx >> 3, p = idx & 7;
            int gc = k0 + ((p ^ (row & 7)) * 8);
            async16(Bd + idx * 8, B + (n0 + row) * ldb + gc);
        }
    };

    stage(0);
    stage(1);

    for (int kt = 0; kt < nt; kt++) {
        if (kt + 1 < nt) {
            asm volatile("s_waitcnt vmcnt(4)" ::: "memory");
        } else {
            asm volatile("s_waitcnt vmcnt(0)" ::: "memory");
        }
        __builtin_amdgcn_s_barrier();
        __builtin_amdgcn_sched_barrier(0);

        const bf16* Asl = As + (kt & 1) * 16384;
        const bf16* Bsl = Bs + (kt & 1) * 16384;

        // ---- phase A: ksteps 0,1 ----
        {
            bf16x8 af[2][2], bfr[2][2];  // [mb|nb][ks]
#pragma unroll
            for (int mb = 0; mb < 2; mb++) {
                int row = wm * 64 + mb * 32 + l31;
#pragma unroll
                for (int ks = 0; ks < 2; ks++)
                    af[mb][ks] = *(const bf16x8*)(Asl + row * 64 + (((ks * 2 + hi) ^ (row & 7)) * 8));
            }
#pragma unroll
            for (int nb = 0; nb < 2; nb++) {
                int row = wn * 64 + nb * 32 + l31;
#pragma unroll
                for (int ks = 0; ks < 2; ks++)
                    bfr[nb][ks] = *(const bf16x8*)(Bsl + row * 64 + (((ks * 2 + hi) ^ (row & 7)) * 8));
            }
            __builtin_amdgcn_s_setprio(1);
#pragma unroll
            for (int ks = 0; ks < 2; ks++)
#pragma unroll
                for (int mb = 0; mb < 2; mb++)
#pragma unroll
                    for (int nb = 0; nb < 2; nb++)
                        acc[mb][nb] = mfma32(af[mb][ks], bfr[nb][ks], acc[mb][nb]);
            __builtin_amdgcn_s_setprio(0);
        }

        // ---- phase B: ksteps 2,3 + slot-free barrier + early stage ----
        {
            bf16x8 af[2][2], bfr[2][2];
#pragma unroll
            for (int mb = 0; mb < 2; mb++) {
                int row = wm * 64 + mb * 32 + l31;
#pragma unroll
                for (int ks = 0; ks < 2; ks++)
                    af[mb][ks] = *(const bf16x8*)(Asl + row * 64 + ((((2 + ks) * 2 + hi) ^ (row & 7)) * 8));
            }
#pragma unroll
            for (int nb = 0; nb < 2; nb++) {
                int row = wn * 64 + nb * 32 + l31;
#pragma unroll
                for (int ks = 0; ks < 2; ks++)
                    bfr[nb][ks] = *(const bf16x8*)(Bsl + row * 64 + ((((2 + ks) * 2 + hi) ^ (row & 7)) * 8));
            }
            asm volatile("s_waitcnt lgkmcnt(0)" ::: "memory");
            __builtin_amdgcn_sched_barrier(0);
            __builtin_amdgcn_s_barrier();     // all waves done reading this slot
            __builtin_amdgcn_sched_barrier(0);
            if (kt + 2 < nt) stage(kt + 2);   // overwrite slot while MFMA runs
            __builtin_amdgcn_s_setprio(1);
#pragma unroll
            for (int ks = 0; ks < 2; ks++)
#pragma unroll
                for (int mb = 0; mb < 2; mb++)
#pragma unroll
                    for (int nb = 0; nb < 2; nb++)
                        acc[mb][nb] = mfma32(af[mb][ks], bfr[nb][ks], acc[mb][nb]);
            __builtin_amdgcn_s_setprio(0);
        }
    }

    // ---- epilogue: D layout col=l31, row=(reg&3)+8*(reg>>2)+4*hi ----
#pragma unroll
    for (int nb = 0; nb < 2; nb++) {
        long col = n0 + wn * 64 + nb * 32 + l31;
#pragma unroll
        for (int mb = 0; mb < 2; mb++) {
            long rbase = m0 + wm * 64 + mb * 32;
            if (MODE == 0) {
                bf16* C = (bf16*)Cout;
                float bs = bias[col];
#pragma unroll
                for (int reg = 0; reg < 16; reg++) {
                    long row = rbase + (reg & 3) + 8 * (reg >> 2) + 4 * hi;
                    C[row * ldc + col] = (bf16)(acc[mb][nb][reg] + bs);
                }
            } else {  // MODE 5
                if (col < 512) {
                    bf16* C = (bf16*)Cout;
                    float bs = bias[col];
#pragma unroll
                    for (int reg = 0; reg < 16; reg++) {
                        long row = rbase + (reg & 3) + 8 * (reg >> 2) + 4 * hi;
                        C[row * ldc + col] = (bf16)((acc[mb][nb][reg] + bs) * scale);
                    }
                } else {
                    bf16* V = (bf16*)Cout2;
                    long v = col - 512;
                    float bs = bias2[v];
#pragma unroll
                    for (int rq = 0; rq < 4; rq++) {
                        long vrow = rbase + rq * 8 + 4 * hi;  // 4 consecutive rows
                        bf16x4 pv;
#pragma unroll
                        for (int r = 0; r < 4; r++) pv[r] = (bf16)(acc[mb][nb][rq * 4 + r] + bs);
                        *(bf16x4*)(V + v * 16384 + vrow) = pv;
                    }
                }
            }
        }
    }
}

// ---------------- pipelined FFN2: BM=128 BN=256, 16 waves, 32x32 MFMA ---------
// Per-wave 32x64 (1x2 mfma32 blocks). vmcnt(3). fp32 out + residual.
__global__ __launch_bounds__(1024, 4) void pipe_ffn2(
    const bf16* __restrict__ A, long lda,
    const bf16* __restrict__ B, long ldb,
    const float* __restrict__ bias,
    float* __restrict__ C, long ldc,
    const float* __restrict__ res0, const float* __restrict__ res1,
    int M, int N, int K)
{
    __shared__ bf16 lds[49152];          // 96 KiB: As[2][8192] | Bs[2][16384]
    bf16* As = lds;                      // 128 x 64 per slot
    bf16* Bs = lds + 16384;              // 256 x 64 per slot

    const int t = threadIdx.x;
    const int w = t >> 6, lane = t & 63;
    const int l31 = lane & 31, hi = lane >> 5;
    const int wm = w >> 2, wn = w & 3;   // 4 x 4 wave grid
    const int nbx = N >> 8;              // 2
    const int xcd = blockIdx.x & 7, local = blockIdx.x >> 3;
    const int mtiles_per_xcd = (int)(gridDim.x >> 3) / nbx;
    const int by = xcd * mtiles_per_xcd + local / nbx;
    const int bx = local % nbx;
    const long m0 = (long)by * 128, n0 = (long)bx * 256;
    const int nt = K >> 6;

    f32x16 acc[2] = {};                  // [nb], 32x32 each

    auto stage = [&](int kt) {
        const int slot = kt & 1;
        bf16* Ad = As + slot * 8192;
        bf16* Bd = Bs + slot * 16384;
        const int k0 = kt * 64;
        {
            int idx = t, row = idx >> 3, p = idx & 7;
            int gc = k0 + ((p ^ (row & 7)) * 8);
            async16(Ad + idx * 8, A + (m0 + row) * lda + gc);
        }
#pragma unroll
        for (int i = 0; i < 2; i++) {
            int idx = i * 1024 + t, row = idx >> 3, p = idx & 7;
            int gc = k0 + ((p ^ (row & 7)) * 8);
            async16(Bd + idx * 8, B + (n0 + row) * ldb + gc);
        }
    };

    stage(0);
    stage(1);

    for (int kt = 0; kt < nt; kt++) {
        if (kt + 1 < nt) {
            asm volatile("s_waitcnt vmcnt(3)" ::: "memory");
        } else {
            asm volatile("s_waitcnt vmcnt(0)" ::: "memory");
        }
        __builtin_amdgcn_s_barrier();
        __builtin_amdgcn_sched_barrier(0);

        const bf16* Asl = As + (kt & 1) * 8192;
        const bf16* Bsl = Bs + (kt & 1) * 16384;
        const int arow = wm * 32 + l31;

        // ---- phase A: ksteps 0,1 ----
        {
            bf16x8 af[2], bfr[2][2];
#pragma unroll
            for (int ks = 0; ks < 2; ks++)
                af[ks] = *(const bf16x8*)(Asl + arow * 64 + (((ks * 2 + hi) ^ (arow & 7)) * 8));
#pragma unroll
            for (int nb = 0; nb < 2; nb++) {
                int row = wn * 64 + nb * 32 + l31;
#pragma unroll
                for (int ks = 0; ks < 2; ks++)
                    bfr[nb][ks] = *(const bf16x8*)(Bsl + row * 64 + (((ks * 2 + hi) ^ (row & 7)) * 8));
            }
            __builtin_amdgcn_s_setprio(1);
#pragma unroll
            for (int ks = 0; ks < 2; ks++)
#pragma unroll
                for (int nb = 0; nb < 2; nb++)
                    acc[nb] = mfma32(af[ks], bfr[nb][ks], acc[nb]);
            __builtin_amdgcn_s_setprio(0);
        }

        // ---- phase B: ksteps 2,3 + early stage ----
        {
            bf16x8 af[2], bfr[2][2];
#pragma unroll
            for (int ks = 0; ks < 2; ks++)
                af[ks] = *(const bf16x8*)(Asl + arow * 64 + ((((2 + ks) * 2 + hi) ^ (arow & 7)) * 8));
#pragma unroll
            for (int nb = 0; nb < 2; nb++) {
                int row = wn * 64 + nb * 32 + l31;
#pragma unroll
                for (int ks = 0; ks < 2; ks++)
                    bfr[nb][ks] = *(const bf16x8*)(Bsl + row * 64 + ((((2 + ks) * 2 + hi) ^ (row & 7)) * 8));
            }
            asm volatile("s_waitcnt lgkmcnt(0)" ::: "memory");
            __builtin_amdgcn_sched_barrier(0);
            __builtin_amdgcn_s_barrier();
            __builtin_amdgcn_sched_barrier(0);
            if (kt + 2 < nt) stage(kt + 2);
            __builtin_amdgcn_s_setprio(1);
#pragma unroll
            for (int ks = 0; ks < 2; ks++)
#pragma unroll
                for (int nb = 0; nb < 2; nb++)
                    acc[nb] = mfma32(af[ks], bfr[nb][ks], acc[nb]);
            __builtin_amdgcn_s_setprio(0);
        }
    }

#pragma unroll
    for (int nb = 0; nb < 2; nb++) {
        long col = n0 + wn * 64 + nb * 32 + l31;
        float bs = bias[col];
        long rbase = m0 + wm * 32;
#pragma unroll
        for (int reg = 0; reg < 16; reg++) {
            long grow = rbase + (reg & 3) + 8 * (reg >> 2) + 4 * hi;
            const float* rs = (grow < 8192) ? (res0 + grow * 512)
                                            : (res1 + (grow - 8192) * 512);
            C[grow * ldc + col] = acc[nb][reg] + bs + rs[col];
        }
    }
}

// ---------------- flash attention: 32x32 MFMA, in-register P, QBLK=128 --------
// (r3/r8-proven: ~111 us) LDS 32KiB: K dbuf 2x8K | V dbuf 2x8K. One barrier/iter.
__global__ __launch_bounds__(256, 4) void flash_attn(const bf16* __restrict__ QK,
                                                     const bf16* __restrict__ VT,
                                                     bf16* __restrict__ o)
{
    __shared__ bf16 lds[16384];          // 32 KiB: Ks[2][4096] | Vs[2][4096]

    const int t = threadIdx.x, w = t >> 6, lane = t & 63;
    const int l31 = lane & 31, hi = lane >> 5;
    const int j = blockIdx.x;
    const int hs = j & 63;               // head-set id (shares K/V)
    const int qt = j >> 6;               // 0..15 q-tile
    const int h = hs & 7, b = (hs >> 3) & 3, dir = hs >> 5;
    const long qrow0  = (long)dir * 8192 + b * 2048 + qt * 128;
    const long kvrow0 = (long)(1 - dir) * 8192 + b * 2048;
    const int hc = h * 64;

    // ---- Q stage: 128 rows x 64 d = 16KB into first half of LDS ----
#pragma unroll
    for (int i = 0; i < 4; i++) {
        int idx = i * 256 + t, row = idx >> 3, p = idx & 7;
        async16(lds + idx * 8, QK + (qrow0 + row) * 512 + hc + ((p ^ (row & 7)) * 8));
    }
    __syncthreads();
    bf16x8 qf[4];
    {
        int qrow = w * 32 + l31;
#pragma unroll
        for (int kd = 0; kd < 4; kd++)
            qf[kd] = *(const bf16x8*)(lds + qrow * 64 + (((kd * 2 + hi) ^ (qrow & 7)) * 8));
    }
    __syncthreads();  // all Q reads done before K/V loads overwrite

    // ---- prologue: issue K(0), V(0) into buffer 0 ----
#pragma unroll
    for (int i = 0; i < 2; i++) {
        int idx = i * 256 + t, row = idx >> 3, p = idx & 7;
        async16(lds + idx * 8, QK + (kvrow0 + row) * 512 + hc + ((p ^ (row & 7)) * 8));
    }
#pragma unroll
    for (int i = 0; i < 2; i++) {
        int idx = i * 256 + t, row = idx >> 3, p = idx & 7;
        async16(lds + 8192 + idx * 8, VT + (long)(hc + row) * 16384 + kvrow0 + ((p ^ (row & 7)) * 8));
    }

    f32x16 oacc[2] = {};
    f32x16 racc = {};
    bf16x8 ones;
#pragma unroll
    for (int k = 0; k < 8; k++) ones[k] = (bf16)1.0f;

    for (int kb = 0; kb < 32; kb++) {
        bf16* Kc = lds + (kb & 1) * 4096;
        bf16* Vc = lds + 8192 + (kb & 1) * 4096;

        asm volatile("s_waitcnt vmcnt(0)" ::: "memory");
        __builtin_amdgcn_s_barrier();

        if (kb < 31) {
            const long knext = kvrow0 + (kb + 1) * 64;
            bf16* Kn = lds + ((kb + 1) & 1) * 4096;
            bf16* Vn = lds + 8192 + ((kb + 1) & 1) * 4096;
#pragma unroll
            for (int i = 0; i < 2; i++) {
                int idx = i * 256 + t, row = idx >> 3, p = idx & 7;
                async16(Kn + idx * 8, QK + (knext + row) * 512 + hc + ((p ^ (row & 7)) * 8));
            }
#pragma unroll
            for (int i = 0; i < 2; i++) {
                int idx = i * 256 + t, row = idx >> 3, p = idx & 7;
                async16(Vn + idx * 8, VT + (long)(hc + row) * 16384 + knext + ((p ^ (row & 7)) * 8));
            }
        }

#pragma unroll
        for (int kb2 = 0; kb2 < 2; kb2++) {
            const int krow = kb2 * 32 + l31;
            const int ksw = krow & 7;
            bf16x8 kf0 = *(const bf16x8*)(Kc + krow * 64 + (((0 + hi) ^ ksw) * 8));
            bf16x8 kf1 = *(const bf16x8*)(Kc + krow * 64 + (((2 + hi) ^ ksw) * 8));
            bf16x8 kf2 = *(const bf16x8*)(Kc + krow * 64 + (((4 + hi) ^ ksw) * 8));
            bf16x8 kf3 = *(const bf16x8*)(Kc + krow * 64 + (((6 + hi) ^ ksw) * 8));

            f32x16 s0 = {};
            __builtin_amdgcn_s_setprio(1);
            s0 = mfma32(kf0, qf[0], s0);
            s0 = mfma32(kf1, qf[1], s0);
            s0 = mfma32(kf2, qf[2], s0);
            s0 = mfma32(kf3, qf[3], s0);
            __builtin_amdgcn_s_setprio(0);

#pragma unroll
            for (int r = 0; r < 16; r++) s0[r] = __builtin_amdgcn_exp2f(s0[r]);

#pragma unroll
            for (int sh = 0; sh < 2; sh++) {
                const int ks = kb2 * 2 + sh;
                unsigned a00 = cvtpk(s0[8 * sh + 0], s0[8 * sh + 1]);
                unsigned a01 = cvtpk(s0[8 * sh + 2], s0[8 * sh + 3]);
                unsigned b00 = cvtpk(s0[8 * sh + 4], s0[8 * sh + 5]);
                unsigned b01 = cvtpk(s0[8 * sh + 6], s0[8 * sh + 7]);
                pl32(a00, b00); pl32(a01, b01);
                bf16x8 pa0 = mk8(a00, a01, b00, b01);

                __builtin_amdgcn_s_setprio(1);
#pragma unroll
                for (int db = 0; db < 2; db++) {
                    const int vrow = db * 32 + l31;
                    bf16x8 vf = *(const bf16x8*)(Vc + vrow * 64 + (((ks * 2 + hi) ^ (vrow & 7)) * 8));
                    oacc[db] = mfma32(pa0, vf, oacc[db]);
                }
                racc = mfma32(pa0, ones, racc);
                __builtin_amdgcn_s_setprio(0);
            }
        }
    }

#pragma unroll
    for (int reg = 0; reg < 16; reg++) {
        const int q = (reg & 3) + 8 * (reg >> 2) + 4 * hi;
        const float inv = __builtin_amdgcn_rcpf(racc[reg]);
        const long row = qrow0 + w * 32 + q;
#pragma unroll
        for (int db = 0; db < 2; db++)
            o[row * 1024 + hc + db * 32 + l31] = (bf16)(oacc[db][reg] * inv);
    }
}

// ---------------- LayerNorm + GELU (fast erf), in-place on bf16 [16384][1024]
__global__ __launch_bounds__(256) void ln_gelu(bf16* __restrict__ H,
                                               const float* __restrict__ g,
                                               const float* __restrict__ bta)
{
    const int row = blockIdx.x, t = threadIdx.x;
    const int w = t >> 6, lane = t & 63;
    bf16* hp = H + (long)row * 1024 + t * 4;
    bf16x4 hv = *(const bf16x4*)hp;
    float h[4];
#pragma unroll
    for (int j = 0; j < 4; j++) h[j] = (float)hv[j];
    float s1 = h[0] + h[1] + h[2] + h[3];
    float s2 = h[0] * h[0] + h[1] * h[1] + h[2] * h[2] + h[3] * h[3];
#pragma unroll
    for (int d = 1; d < 64; d <<= 1) {
        s1 += __shfl_xor(s1, d);
        s2 += __shfl_xor(s2, d);
    }
    __shared__ float rbuf[8];
    if (lane == 0) { rbuf[w] = s1; rbuf[4 + w] = s2; }
    __syncthreads();
    s1 = rbuf[0] + rbuf[1] + rbuf[2] + rbuf[3];
    s2 = rbuf[4] + rbuf[5] + rbuf[6] + rbuf[7];
    const float mu = s1 * (1.f / 1024.f);
    const float var = s2 * (1.f / 1024.f) - mu * mu;
    const float rstd = rsqrtf(var + 1e-5f);
    bf16x4 out;
#pragma unroll
    for (int j = 0; j < 4; j++) {
        int c = t * 4 + j;
        float x = (h[j] - mu) * rstd * g[c] + bta[c];
        float y = 0.5f * x * (1.f + erf_fast(x * 0.70710678118654752f));
        out[j] = (bf16)y;
    }
    *(bf16x4*)hp = out;
}

extern "C" void kernel_launch(void* const* d_in, const int* in_sizes, int n_in,
                              void* d_out, int out_size, void* d_ws, size_t ws_size,
                              hipStream_t stream)
{
    const float* x0  = (const float*)d_in[0];
    const float* x1  = (const float*)d_in[1];
    const float* Wqk = (const float*)d_in[2];
    const float* bqk = (const float*)d_in[3];
    const float* Wv  = (const float*)d_in[4];
    const float* bv  = (const float*)d_in[5];
    const float* Wo  = (const float*)d_in[6];
    const float* bo  = (const float*)d_in[7];
    const float* Wf1 = (const float*)d_in[8];
    const float* bf1 = (const float*)d_in[9];
    const float* lng = (const float*)d_in[10];
    const float* lnb = (const float*)d_in[11];
    const float* Wf2 = (const float*)d_in[12];
    const float* bf2 = (const float*)d_in[13];

    char* ws = (char*)d_ws;
    bf16* Xbf   = (bf16*)ws; ws += 16384L * 1024 * 2;  // [x | m] both streams
    bf16* QKbf  = (bf16*)ws;                            // qk projection (pre-scaled)
    bf16* Hbuf  = (bf16*)ws;                            // FFN1 out (aliases QKbf+VtG)
    ws += 16384L * 512 * 2;
    bf16* VtG   = (bf16*)ws; ws += 16384L * 512 * 2;   // v proj transposed [512][16384]
    bf16* Wqkv  = (bf16*)ws; ws += 1024L * 512 * 2;    // [Wqk; Wv] bf16
    bf16* Wbig  = (bf16*)ws; ws += 1024L * 1024 * 2;   // [Wf1L | Wcomb]
    bf16* Wf1Rb = (bf16*)ws; ws += 1024L * 512 * 2;
    bf16* Wf2b  = (bf16*)ws; ws += 512L * 1024 * 2;
    bf16* WoT   = (bf16*)ws; ws += 512L * 512 * 2;
    float* bf1p = (float*)ws; ws += 1024 * 4;

    // sqrt((1/8) * log2(e)) — applied to both q and k so scores carry (1/8)*log2(e)
    const float qs = 0.42466090014400953f;

    prep<<<10560, 256, 0, stream>>>(x0, x1, Xbf, Wqk, Wv, Wf1, Wf2,
                                    Wqkv, Wbig, Wf1Rb, Wf2b, Wo, WoT, bo, bf1, bf1p);

    // Wcomb = Wf1R @ Wo -> Wbig right half  [1024,512] = Wf1Rb @ WoT^T
    gemm_bt<4><<<32, 256, 0, stream>>>(Wf1Rb, 512, WoT, 512, nullptr,
                                       Wbig + 512, 1024, nullptr, nullptr,
                                       nullptr, nullptr, 1024, 512, 512, 1.f);

    // fused QKV projection: [16384,1024] = Xbf @ Wqkv^T (256x256, 16 waves)
    pipe_gemm<5><<<256, 1024, 0, stream>>>(Xbf, 1024, Wqkv, 512, bqk,
                                           QKbf, 512, bv, VtG,
                                           16384, 1024, 512, qs);

    // cross attention -> writes m-heads directly into Xbf right half (ld 1024)
    flash_attn<<<1024, 256, 0, stream>>>(QKbf, VtG, Xbf + 512);

    // FFN1 (Wo folded): [16384,1024] = [x|O] @ [Wf1L|Wcomb]^T + bf1'
    pipe_gemm<0><<<256, 1024, 0, stream>>>(Xbf, 1024, Wbig, 1024, bf1p,
                                           Hbuf, 1024, nullptr, nullptr,
                                           16384, 1024, 1024, 1.f);
    ln_gelu<<<16384, 256, 0, stream>>>(Hbuf, lng, lnb);
    // FFN2 + bias + residual -> d_out (fp32), BM=128 BN=256, 16 waves
    pipe_ffn2<<<256, 1024, 0, stream>>>(Hbuf, 1024, Wf2b, 1024, bf2,
                                        (float*)d_out, 512, x0, x1,
                                        16384, 512, 1024);
}

// Round 13
// 311.142 us; speedup vs baseline: 1.1593x; 1.0254x over previous
//
#include <hip/hip_runtime.h>
#include <hip/hip_bf16.h>
#include <math.h>

typedef __bf16 bf16;
typedef __bf16 bf16x8 __attribute__((ext_vector_type(8)));
typedef __bf16 bf16x4 __attribute__((ext_vector_type(4)));
typedef float  f32x4  __attribute__((ext_vector_type(4)));
typedef float  f32x16 __attribute__((ext_vector_type(16)));
typedef unsigned int u32x2 __attribute__((ext_vector_type(2)));

#define DEVI __device__ __forceinline__

DEVI void async16(bf16* lds, const bf16* g) {
    __builtin_amdgcn_global_load_lds(
        (const __attribute__((address_space(1))) unsigned int*)g,
        (__attribute__((address_space(3))) unsigned int*)lds, 16, 0, 0);
}
DEVI f32x4 mfma16(bf16x8 a, bf16x8 b, f32x4 c) {
    return __builtin_amdgcn_mfma_f32_16x16x32_bf16(a, b, c, 0, 0, 0);
}
DEVI f32x16 mfma32(bf16x8 a, bf16x8 b, f32x16 c) {
    return __builtin_amdgcn_mfma_f32_32x32x16_bf16(a, b, c, 0, 0, 0);
}
DEVI unsigned cvtpk(float lo, float hi) {
    unsigned r;
    asm("v_cvt_pk_bf16_f32 %0, %1, %2" : "=v"(r) : "v"(lo), "v"(hi));
    return r;
}
// v_permlane32_swap_b32: a' = [a.lo32, b.lo32], b' = [a.hi32, b.hi32]
DEVI void pl32(unsigned &a, unsigned &b) {
    u32x2 r = __builtin_amdgcn_permlane32_swap(a, b, false, false);
    a = r.x; b = r.y;
}
DEVI bf16x8 mk8(unsigned a0, unsigned a1, unsigned b0, unsigned b1) {
    union { unsigned u[4]; bf16x8 v; } U;
    U.u[0] = a0; U.u[1] = a1; U.u[2] = b0; U.u[3] = b1;
    return U.v;
}
// Abramowitz-Stegun 7.1.26 erf, |err| <= 1.5e-7 (vs libm branchy erff)
DEVI float erf_fast(float x) {
    float ax = fabsf(x);
    float t = 1.f / (1.f + 0.3275911f * ax);
    float y = t * (0.254829592f +
              t * (-0.284496736f +
              t * (1.421413741f +
              t * (-1.453152027f + t * 1.061405429f))));
    float e = __expf(-ax * ax);
    float r = 1.f - y * e;
    return (x < 0.f) ? -r : r;
}

// ---------------- fused prep: cvt_x + cvt_w + wo_t + bias_comb ----------------
__global__ __launch_bounds__(256) void prep(
    const float* __restrict__ x0, const float* __restrict__ x1, bf16* __restrict__ Xbf,
    const float* __restrict__ Wqk, const float* __restrict__ Wv,
    const float* __restrict__ Wf1, const float* __restrict__ Wf2,
    bf16* __restrict__ Wqkv, bf16* __restrict__ Wbig, bf16* __restrict__ Wf1Rb,
    bf16* __restrict__ Wf2b,
    const float* __restrict__ Wo, bf16* __restrict__ WoT,
    const float* __restrict__ bo, const float* __restrict__ bf1,
    float* __restrict__ bf1p)
{
    __shared__ float Ls[64][65];
    const int bid = blockIdx.x, t = threadIdx.x;
    if (bid < 8192) {
        long i = (long)bid * 256 + t;
        long r = i >> 7, c = (i & 127) * 4;
        const float* src = (r < 8192) ? (x0 + r * 512 + c) : (x1 + (r - 8192) * 512 + c);
        float4 v = *(const float4*)src;
        bf16x4 o;
        o[0] = (bf16)v.x; o[1] = (bf16)v.y; o[2] = (bf16)v.z; o[3] = (bf16)v.w;
        *(bf16x4*)(Xbf + r * 1024 + c) = o;
    } else if (bid < 10240) {
        long i = (long)(bid - 8192) * 256 + t;
        const float* s; bf16* d;
        if (i < 131072) {
            s = (i < 65536) ? Wqk + i * 4 : Wv + (i - 65536) * 4;
            d = Wqkv + i * 4;
        } else if (i < 393216) {
            long e = (i - 131072) * 4, r = e >> 10, c = e & 1023;
            s = Wf1 + e;
            d = (c < 512) ? (Wbig + r * 1024 + c) : (Wf1Rb + r * 512 + (c - 512));
        } else {
            s = Wf2 + (i - 393216) * 4;
            d = Wf2b + (i - 393216) * 4;
        }
        float4 v = *(const float4*)s;
        bf16x4 o;
        o[0] = (bf16)v.x; o[1] = (bf16)v.y; o[2] = (bf16)v.z; o[3] = (bf16)v.w;
        *(bf16x4*)d = o;
    } else if (bid < 10304) {
        const int bb = bid - 10240;
        const int bi = bb & 7, bj = bb >> 3;
        const int i0 = bi * 64, j0 = bj * 64;
        const int r0 = t >> 4, c4 = (t & 15) * 4;
#pragma unroll
        for (int it = 0; it < 4; it++) {
            int row = r0 + 16 * it;
            float4 v = *(const float4*)(Wo + (long)(i0 + row) * 512 + j0 + c4);
            Ls[row][c4] = v.x; Ls[row][c4 + 1] = v.y;
            Ls[row][c4 + 2] = v.z; Ls[row][c4 + 3] = v.w;
        }
        __syncthreads();
#pragma unroll
        for (int it = 0; it < 4; it++) {
            int orow = r0 + 16 * it;
            bf16x4 o;
#pragma unroll
            for (int k = 0; k < 4; k++) o[k] = (bf16)Ls[c4 + k][orow];
            *(bf16x4*)(WoT + (long)(j0 + orow) * 512 + i0 + c4) = o;
        }
    } else {
        const int w = t >> 6, lane = t & 63;
        const int row = (bid - 10304) * 4 + w;
        const float* rp = Wf1 + (long)row * 1024 + 512 + lane * 8;
        float4 a = *(const float4*)rp;
        float4 b = *(const float4*)(rp + 4);
        const float* bp = bo + lane * 8;
        float4 c = *(const float4*)bp;
        float4 d = *(const float4*)(bp + 4);
        float s = a.x * c.x + a.y * c.y + a.z * c.z + a.w * c.w +
                  b.x * d.x + b.y * d.y + b.z * d.z + b.w * d.w;
#pragma unroll
        for (int k = 1; k < 64; k <<= 1) s += __shfl_xor(s, k);
        if (lane == 0) bf1p[row] = bf1[row] + s;
    }
}

// ---------------- bf16 GEMM: C = A @ B^T, BK=64 swizzled (Wcomb only) ---------
template <int MODE>
__global__ __launch_bounds__(256) void gemm_bt(
    const bf16* __restrict__ A, long lda,
    const bf16* __restrict__ B, long ldb,
    const float* __restrict__ bias,
    void* __restrict__ Cout, long ldc,
    const float* __restrict__ res0, const float* __restrict__ res1,
    const float* __restrict__ bias2, void* __restrict__ Cout2,
    int M, int N, int K, float scale)
{
    __shared__ bf16 As[128 * 64];
    __shared__ bf16 Bs[128 * 64];
    const int t = threadIdx.x;
    const int w = t >> 6, lane = t & 63, quad = lane >> 4, m15 = lane & 15;
    const int wm = w >> 1, wn = w & 1;
    const int nbx = N >> 7;
    const int xcd = blockIdx.x & 7, local = blockIdx.x >> 3;
    const int mtiles_per_xcd = (int)(gridDim.x >> 3) / nbx;
    const int by = xcd * mtiles_per_xcd + local / nbx;
    const int bx = local % nbx;
    const long m0 = (long)by * 128, n0 = (long)bx * 128;

    f32x4 acc[4][4] = {};

    for (int k0 = 0; k0 < K; k0 += 64) {
#pragma unroll
        for (int i = 0; i < 4; i++) {
            int idx = i * 256 + t, row = idx >> 3, p = idx & 7;
            int gc = k0 + ((p ^ (row & 7)) * 8);
            async16(As + idx * 8, A + (m0 + row) * lda + gc);
            async16(Bs + idx * 8, B + (n0 + row) * ldb + gc);
        }
        __syncthreads();
#pragma unroll
        for (int kk = 0; kk < 2; kk++) {
            bf16x8 af[4], bfr[4];
#pragma unroll
            for (int mt = 0; mt < 4; mt++) {
                int row = wm * 64 + mt * 16 + m15;
                af[mt] = *(const bf16x8*)(As + row * 64 + (((kk * 4 + quad) ^ (row & 7)) * 8));
            }
#pragma unroll
            for (int nt = 0; nt < 4; nt++) {
                int row = wn * 64 + nt * 16 + m15;
                bfr[nt] = *(const bf16x8*)(Bs + row * 64 + (((kk * 4 + quad) ^ (row & 7)) * 8));
            }
#pragma unroll
            for (int mt = 0; mt < 4; mt++)
#pragma unroll
                for (int nt = 0; nt < 4; nt++)
                    acc[mt][nt] = mfma16(af[mt], bfr[nt], acc[mt][nt]);
        }
        __syncthreads();
    }

#pragma unroll
    for (int nt = 0; nt < 4; nt++) {
        long col = n0 + wn * 64 + nt * 16 + m15;
#pragma unroll
        for (int mt = 0; mt < 4; mt++) {
            long row = m0 + wm * 64 + mt * 16 + quad * 4;
            if (MODE == 4) {
                bf16* C = (bf16*)Cout;
#pragma unroll
                for (int r = 0; r < 4; r++)
                    C[(row + r) * ldc + col] = (bf16)acc[mt][nt][r];
            }
        }
    }
}

// ---------------- pipelined 256x256 GEMM: 16 waves, early stage issue ---------
// (r10-proven best GEMM config) 1024 threads = 16 waves (4M x 4N), BM=BN=256,
// BK=64, LDS 128 KiB (2 slots). 4 waves/SIMD hide vmcnt+barrier drains.
// Schedule/iter: vmcnt(4) -> barrier -> ksub0 reads+MFMA -> ksub1 reads ->
// lgkmcnt(0)+barrier -> issue stage(kt+2) -> ksub1 MFMA. Grid 256, N%256==0.
// 16x16 mfma (r11's 32x32 port regressed: 4-deep acc chains < 16 independent).
template <int MODE>
__global__ __launch_bounds__(1024, 4) void pipe_gemm(
    const bf16* __restrict__ A, long lda,
    const bf16* __restrict__ B, long ldb,
    const float* __restrict__ bias,
    void* __restrict__ Cout, long ldc,
    const float* __restrict__ bias2, void* __restrict__ Cout2,
    int M, int N, int K, float scale)
{
    __shared__ bf16 lds[65536];          // 128 KiB: As[2][16384] | Bs[2][16384]
    bf16* As = lds;
    bf16* Bs = lds + 32768;

    const int t = threadIdx.x;
    const int w = t >> 6, lane = t & 63, quad = lane >> 4, m15 = lane & 15;
    const int wm = w >> 2, wn = w & 3;           // 4 x 4 wave grid
    const int nbx = N >> 8;
    const int xcd = blockIdx.x & 7, local = blockIdx.x >> 3;
    const int mtiles_per_xcd = (int)(gridDim.x >> 3) / nbx;
    const int by = xcd * mtiles_per_xcd + local / nbx;
    const int bx = local % nbx;
    const long m0 = (long)by * 256, n0 = (long)bx * 256;
    const int nt = K >> 6;

    f32x4 acc[4][4] = {};

    // stage tile kt into slot kt&1: 4 async16/thread (2 A + 2 B)
    auto stage = [&](int kt) {
        const int slot = kt & 1;
        bf16* Ad = As + slot * 16384;
        bf16* Bd = Bs + slot * 16384;
        const int k0 = kt * 64;
#pragma unroll
        for (int i = 0; i < 2; i++) {
            int idx = i * 1024 + t, row = idx >> 3, p = idx & 7;
            int gc = k0 + ((p ^ (row & 7)) * 8);
            async16(Ad + idx * 8, A + (m0 + row) * lda + gc);
        }
#pragma unroll
        for (int i = 0; i < 2; i++) {
            int idx = i * 1024 + t, row = idx >> 3, p = idx & 7;
            int gc = k0 + ((p ^ (row & 7)) * 8);
            async16(Bd + idx * 8, B + (n0 + row) * ldb + gc);
        }
    };

    stage(0);
    stage(1);

    for (int kt = 0; kt < nt; kt++) {
        if (kt + 1 < nt) {
            asm volatile("s_waitcnt vmcnt(4)" ::: "memory");
        } else {
            asm volatile("s_waitcnt vmcnt(0)" ::: "memory");
        }
        __builtin_amdgcn_s_barrier();
        __builtin_amdgcn_sched_barrier(0);

        const bf16* Asl = As + (kt & 1) * 16384;
        const bf16* Bsl = Bs + (kt & 1) * 16384;

        // ---- ksub 0: reads + MFMA ----
        {
            bf16x8 af[4], bfr[4];
#pragma unroll
            for (int mf = 0; mf < 4; mf++) {
                int row = wm * 64 + mf * 16 + m15;
                af[mf] = *(const bf16x8*)(Asl + row * 64 + ((quad ^ (row & 7)) * 8));
            }
#pragma unroll
            for (int nf = 0; nf < 4; nf++) {
                int row = wn * 64 + nf * 16 + m15;
                bfr[nf] = *(const bf16x8*)(Bsl + row * 64 + ((quad ^ (row & 7)) * 8));
            }
            __builtin_amdgcn_s_setprio(1);
#pragma unroll
            for (int mf = 0; mf < 4; mf++)
#pragma unroll
                for (int nf = 0; nf < 4; nf++)
                    acc[mf][nf] = mfma16(af[mf], bfr[nf], acc[mf][nf]);
            __builtin_amdgcn_s_setprio(0);
        }

        // ---- ksub 1: reads, free the slot, early stage, MFMA ----
        {
            bf16x8 af[4], bfr[4];
#pragma unroll
            for (int mf = 0; mf < 4; mf++) {
                int row = wm * 64 + mf * 16 + m15;
                af[mf] = *(const bf16x8*)(Asl + row * 64 + (((4 + quad) ^ (row & 7)) * 8));
            }
#pragma unroll
            for (int nf = 0; nf < 4; nf++) {
                int row = wn * 64 + nf * 16 + m15;
                bfr[nf] = *(const bf16x8*)(Bsl + row * 64 + (((4 + quad) ^ (row & 7)) * 8));
            }
            asm volatile("s_waitcnt lgkmcnt(0)" ::: "memory");
            __builtin_amdgcn_sched_barrier(0);
            __builtin_amdgcn_s_barrier();     // all waves done reading this slot
            __builtin_amdgcn_sched_barrier(0);
            if (kt + 2 < nt) stage(kt + 2);   // overwrite slot while MFMA runs
            __builtin_amdgcn_s_setprio(1);
#pragma unroll
            for (int mf = 0; mf < 4; mf++)
#pragma unroll
                for (int nf = 0; nf < 4; nf++)
                    acc[mf][nf] = mfma16(af[mf], bfr[nf], acc[mf][nf]);
            __builtin_amdgcn_s_setprio(0);
        }
    }

#pragma unroll
    for (int nf = 0; nf < 4; nf++) {
        long col = n0 + wn * 64 + nf * 16 + m15;
#pragma unroll
        for (int mf = 0; mf < 4; mf++) {
            long row = m0 + wm * 64 + mf * 16 + quad * 4;
            if (MODE == 0) {
                bf16* C = (bf16*)Cout;
                float bs = bias[col];
#pragma unroll
                for (int r = 0; r < 4; r++)
                    C[(row + r) * ldc + col] = (bf16)(acc[mf][nf][r] + bs);
            } else {  // MODE 5
                if (col < 512) {
                    bf16* C = (bf16*)Cout;
                    float bs = bias[col];
#pragma unroll
                    for (int r = 0; r < 4; r++)
                        C[(row + r) * ldc + col] = (bf16)((acc[mf][nf][r] + bs) * scale);
                } else {
                    bf16* V = (bf16*)Cout2;
                    long v = col - 512;
                    float bs = bias2[v];
                    bf16x4 pv;
#pragma unroll
                    for (int r = 0; r < 4; r++) pv[r] = (bf16)(acc[mf][nf][r] + bs);
                    *(bf16x4*)(V + v * 16384 + row) = pv;
                }
            }
        }
    }
}

// ---------------- pipelined FFN2: BM=128 BN=256, 16 waves, fp32 out ----------
// (r10-proven) 1024 threads = 16 waves (4M x 4N), per-wave 32x64 output.
// vmcnt(3) (stage = 1 A + 2 B per thread). Early-stage-issue schedule.
__global__ __launch_bounds__(1024, 4) void pipe_ffn2(
    const bf16* __restrict__ A, long lda,
    const bf16* __restrict__ B, long ldb,
    const float* __restrict__ bias,
    float* __restrict__ C, long ldc,
    const float* __restrict__ res0, const float* __restrict__ res1,
    int M, int N, int K)
{
    __shared__ bf16 lds[49152];          // 96 KiB: As[2][8192] | Bs[2][16384]
    bf16* As = lds;                      // 128 x 64 per slot
    bf16* Bs = lds + 16384;              // 256 x 64 per slot

    const int t = threadIdx.x;
    const int w = t >> 6, lane = t & 63, quad = lane >> 4, m15 = lane & 15;
    const int wm = w >> 2, wn = w & 3;   // 4 x 4 wave grid
    const int nbx = N >> 8;              // 2
    const int xcd = blockIdx.x & 7, local = blockIdx.x >> 3;
    const int mtiles_per_xcd = (int)(gridDim.x >> 3) / nbx;
    const int by = xcd * mtiles_per_xcd + local / nbx;
    const int bx = local % nbx;
    const long m0 = (long)by * 128, n0 = (long)bx * 256;
    const int nt = K >> 6;

    f32x4 acc[2][4] = {};

    auto stage = [&](int kt) {
        const int slot = kt & 1;
        bf16* Ad = As + slot * 8192;
        bf16* Bd = Bs + slot * 16384;
        const int k0 = kt * 64;
        {
            int idx = t, row = idx >> 3, p = idx & 7;
            int gc = k0 + ((p ^ (row & 7)) * 8);
            async16(Ad + idx * 8, A + (m0 + row) * lda + gc);
        }
#pragma unroll
        for (int i = 0; i < 2; i++) {
            int idx = i * 1024 + t, row = idx >> 3, p = idx & 7;
            int gc = k0 + ((p ^ (row & 7)) * 8);
            async16(Bd + idx * 8, B + (n0 + row) * ldb + gc);
        }
    };

    stage(0);
    stage(1);

    for (int kt = 0; kt < nt; kt++) {
        if (kt + 1 < nt) {
            asm volatile("s_waitcnt vmcnt(3)" ::: "memory");
        } else {
            asm volatile("s_waitcnt vmcnt(0)" ::: "memory");
        }
        __builtin_amdgcn_s_barrier();
        __builtin_amdgcn_sched_barrier(0);

        const bf16* Asl = As + (kt & 1) * 8192;
        const bf16* Bsl = Bs + (kt & 1) * 16384;

        // ---- ksub 0 ----
        {
            bf16x8 af[2], bfr[4];
#pragma unroll
            for (int mf = 0; mf < 2; mf++) {
                int row = wm * 32 + mf * 16 + m15;
                af[mf] = *(const bf16x8*)(Asl + row * 64 + ((quad ^ (row & 7)) * 8));
            }
#pragma unroll
            for (int nf = 0; nf < 4; nf++) {
                int row = wn * 64 + nf * 16 + m15;
                bfr[nf] = *(const bf16x8*)(Bsl + row * 64 + ((quad ^ (row & 7)) * 8));
            }
            __builtin_amdgcn_s_setprio(1);
#pragma unroll
            for (int mf = 0; mf < 2; mf++)
#pragma unroll
                for (int nf = 0; nf < 4; nf++)
                    acc[mf][nf] = mfma16(af[mf], bfr[nf], acc[mf][nf]);
            __builtin_amdgcn_s_setprio(0);
        }

        // ---- ksub 1 with early stage issue ----
        {
            bf16x8 af[2], bfr[4];
#pragma unroll
            for (int mf = 0; mf < 2; mf++) {
                int row = wm * 32 + mf * 16 + m15;
                af[mf] = *(const bf16x8*)(Asl + row * 64 + (((4 + quad) ^ (row & 7)) * 8));
            }
#pragma unroll
            for (int nf = 0; nf < 4; nf++) {
                int row = wn * 64 + nf * 16 + m15;
                bfr[nf] = *(const bf16x8*)(Bsl + row * 64 + (((4 + quad) ^ (row & 7)) * 8));
            }
            asm volatile("s_waitcnt lgkmcnt(0)" ::: "memory");
            __builtin_amdgcn_sched_barrier(0);
            __builtin_amdgcn_s_barrier();
            __builtin_amdgcn_sched_barrier(0);
            if (kt + 2 < nt) stage(kt + 2);
            __builtin_amdgcn_s_setprio(1);
#pragma unroll
            for (int mf = 0; mf < 2; mf++)
#pragma unroll
                for (int nf = 0; nf < 4; nf++)
                    acc[mf][nf] = mfma16(af[mf], bfr[nf], acc[mf][nf]);
            __builtin_amdgcn_s_setprio(0);
        }
    }

#pragma unroll
    for (int nf = 0; nf < 4; nf++) {
        long col = n0 + wn * 64 + nf * 16 + m15;
        float bs = bias[col];
#pragma unroll
        for (int mf = 0; mf < 2; mf++) {
            long row = m0 + wm * 32 + mf * 16 + quad * 4;
#pragma unroll
            for (int r = 0; r < 4; r++) {
                long grow = row + r;
                const float* rs = (grow < 8192) ? (res0 + grow * 512)
                                                : (res1 + (grow - 8192) * 512);
                C[grow * ldc + col] = acc[mf][nf][r] + bs + rs[col];
            }
        }
    }
}

// ---------------- flash attention: 32x32 MFMA, in-register P, QBLK=128 --------
// (r11-proven: ~85 us — builtin exp2/rcp removed the libm softmax guards)
// LDS 32KiB: K dbuf 2x8K | V dbuf 2x8K. One barrier/iter.
__global__ __launch_bounds__(256, 4) void flash_attn(const bf16* __restrict__ QK,
                                                     const bf16* __restrict__ VT,
                                                     bf16* __restrict__ o)
{
    __shared__ bf16 lds[16384];          // 32 KiB: Ks[2][4096] | Vs[2][4096]

    const int t = threadIdx.x, w = t >> 6, lane = t & 63;
    const int l31 = lane & 31, hi = lane >> 5;
    const int j = blockIdx.x;
    const int hs = j & 63;               // head-set id (shares K/V)
    const int qt = j >> 6;               // 0..15 q-tile
    const int h = hs & 7, b = (hs >> 3) & 3, dir = hs >> 5;
    const long qrow0  = (long)dir * 8192 + b * 2048 + qt * 128;
    const long kvrow0 = (long)(1 - dir) * 8192 + b * 2048;
    const int hc = h * 64;

    // ---- Q stage: 128 rows x 64 d = 16KB into first half of LDS ----
#pragma unroll
    for (int i = 0; i < 4; i++) {
        int idx = i * 256 + t, row = idx >> 3, p = idx & 7;
        async16(lds + idx * 8, QK + (qrow0 + row) * 512 + hc + ((p ^ (row & 7)) * 8));
    }
    __syncthreads();
    bf16x8 qf[4];
    {
        int qrow = w * 32 + l31;
#pragma unroll
        for (int kd = 0; kd < 4; kd++)
            qf[kd] = *(const bf16x8*)(lds + qrow * 64 + (((kd * 2 + hi) ^ (qrow & 7)) * 8));
    }
    __syncthreads();  // all Q reads done before K/V loads overwrite

    // ---- prologue: issue K(0), V(0) into buffer 0 ----
#pragma unroll
    for (int i = 0; i < 2; i++) {
        int idx = i * 256 + t, row = idx >> 3, p = idx & 7;
        async16(lds + idx * 8, QK + (kvrow0 + row) * 512 + hc + ((p ^ (row & 7)) * 8));
    }
#pragma unroll
    for (int i = 0; i < 2; i++) {
        int idx = i * 256 + t, row = idx >> 3, p = idx & 7;
        async16(lds + 8192 + idx * 8, VT + (long)(hc + row) * 16384 + kvrow0 + ((p ^ (row & 7)) * 8));
    }

    f32x16 oacc[2] = {};
    f32x16 racc = {};
    bf16x8 ones;
#pragma unroll
    for (int k = 0; k < 8; k++) ones[k] = (bf16)1.0f;

    for (int kb = 0; kb < 32; kb++) {
        bf16* Kc = lds + (kb & 1) * 4096;
        bf16* Vc = lds + 8192 + (kb & 1) * 4096;

        asm volatile("s_waitcnt vmcnt(0)" ::: "memory");
        __builtin_amdgcn_s_barrier();

        if (kb < 31) {
            const long knext = kvrow0 + (kb + 1) * 64;
            bf16* Kn = lds + ((kb + 1) & 1) * 4096;
            bf16* Vn = lds + 8192 + ((kb + 1) & 1) * 4096;
#pragma unroll
            for (int i = 0; i < 2; i++) {
                int idx = i * 256 + t, row = idx >> 3, p = idx & 7;
                async16(Kn + idx * 8, QK + (knext + row) * 512 + hc + ((p ^ (row & 7)) * 8));
            }
#pragma unroll
            for (int i = 0; i < 2; i++) {
                int idx = i * 256 + t, row = idx >> 3, p = idx & 7;
                async16(Vn + idx * 8, VT + (long)(hc + row) * 16384 + knext + ((p ^ (row & 7)) * 8));
            }
        }

#pragma unroll
        for (int kb2 = 0; kb2 < 2; kb2++) {
            const int krow = kb2 * 32 + l31;
            const int ksw = krow & 7;
            bf16x8 kf0 = *(const bf16x8*)(Kc + krow * 64 + (((0 + hi) ^ ksw) * 8));
            bf16x8 kf1 = *(const bf16x8*)(Kc + krow * 64 + (((2 + hi) ^ ksw) * 8));
            bf16x8 kf2 = *(const bf16x8*)(Kc + krow * 64 + (((4 + hi) ^ ksw) * 8));
            bf16x8 kf3 = *(const bf16x8*)(Kc + krow * 64 + (((6 + hi) ^ ksw) * 8));

            f32x16 s0 = {};
            __builtin_amdgcn_s_setprio(1);
            s0 = mfma32(kf0, qf[0], s0);
            s0 = mfma32(kf1, qf[1], s0);
            s0 = mfma32(kf2, qf[2], s0);
            s0 = mfma32(kf3, qf[3], s0);
            __builtin_amdgcn_s_setprio(0);

#pragma unroll
            for (int r = 0; r < 16; r++) s0[r] = __builtin_amdgcn_exp2f(s0[r]);

#pragma unroll
            for (int sh = 0; sh < 2; sh++) {
                const int ks = kb2 * 2 + sh;
                unsigned a00 = cvtpk(s0[8 * sh + 0], s0[8 * sh + 1]);
                unsigned a01 = cvtpk(s0[8 * sh + 2], s0[8 * sh + 3]);
                unsigned b00 = cvtpk(s0[8 * sh + 4], s0[8 * sh + 5]);
                unsigned b01 = cvtpk(s0[8 * sh + 6], s0[8 * sh + 7]);
                pl32(a00, b00); pl32(a01, b01);
                bf16x8 pa0 = mk8(a00, a01, b00, b01);

                __builtin_amdgcn_s_setprio(1);
#pragma unroll
                for (int db = 0; db < 2; db++) {
                    const int vrow = db * 32 + l31;
                    bf16x8 vf = *(const bf16x8*)(Vc + vrow * 64 + (((ks * 2 + hi) ^ (vrow & 7)) * 8));
                    oacc[db] = mfma32(pa0, vf, oacc[db]);
                }
                racc = mfma32(pa0, ones, racc);
                __builtin_amdgcn_s_setprio(0);
            }
        }
    }

#pragma unroll
    for (int reg = 0; reg < 16; reg++) {
        const int q = (reg & 3) + 8 * (reg >> 2) + 4 * hi;
        const float inv = __builtin_amdgcn_rcpf(racc[reg]);
        const long row = qrow0 + w * 32 + q;
#pragma unroll
        for (int db = 0; db < 2; db++)
            o[row * 1024 + hc + db * 32 + l31] = (bf16)(oacc[db][reg] * inv);
    }
}

// ---------------- LayerNorm + GELU (fast erf), in-place on bf16 [16384][1024]
__global__ __launch_bounds__(256) void ln_gelu(bf16* __restrict__ H,
                                               const float* __restrict__ g,
                                               const float* __restrict__ bta)
{
    const int row = blockIdx.x, t = threadIdx.x;
    const int w = t >> 6, lane = t & 63;
    bf16* hp = H + (long)row * 1024 + t * 4;
    bf16x4 hv = *(const bf16x4*)hp;
    float h[4];
#pragma unroll
    for (int j = 0; j < 4; j++) h[j] = (float)hv[j];
    float s1 = h[0] + h[1] + h[2] + h[3];
    float s2 = h[0] * h[0] + h[1] * h[1] + h[2] * h[2] + h[3] * h[3];
#pragma unroll
    for (int d = 1; d < 64; d <<= 1) {
        s1 += __shfl_xor(s1, d);
        s2 += __shfl_xor(s2, d);
    }
    __shared__ float rbuf[8];
    if (lane == 0) { rbuf[w] = s1; rbuf[4 + w] = s2; }
    __syncthreads();
    s1 = rbuf[0] + rbuf[1] + rbuf[2] + rbuf[3];
    s2 = rbuf[4] + rbuf[5] + rbuf[6] + rbuf[7];
    const float mu = s1 * (1.f / 1024.f);
    const float var = s2 * (1.f / 1024.f) - mu * mu;
    const float rstd = rsqrtf(var + 1e-5f);
    bf16x4 out;
#pragma unroll
    for (int j = 0; j < 4; j++) {
        int c = t * 4 + j;
        float x = (h[j] - mu) * rstd * g[c] + bta[c];
        float y = 0.5f * x * (1.f + erf_fast(x * 0.70710678118654752f));
        out[j] = (bf16)y;
    }
    *(bf16x4*)hp = out;
}

extern "C" void kernel_launch(void* const* d_in, const int* in_sizes, int n_in,
                              void* d_out, int out_size, void* d_ws, size_t ws_size,
                              hipStream_t stream)
{
    const float* x0  = (const float*)d_in[0];
    const float* x1  = (const float*)d_in[1];
    const float* Wqk = (const float*)d_in[2];
    const float* bqk = (const float*)d_in[3];
    const float* Wv  = (const float*)d_in[4];
    const float* bv  = (const float*)d_in[5];
    const float* Wo  = (const float*)d_in[6];
    const float* bo  = (const float*)d_in[7];
    const float* Wf1 = (const float*)d_in[8];
    const float* bf1 = (const float*)d_in[9];
    const float* lng = (const float*)d_in[10];
    const float* lnb = (const float*)d_in[11];
    const float* Wf2 = (const float*)d_in[12];
    const float* bf2 = (const float*)d_in[13];

    char* ws = (char*)d_ws;
    bf16* Xbf   = (bf16*)ws; ws += 16384L * 1024 * 2;  // [x | m] both streams
    bf16* QKbf  = (bf16*)ws;                            // qk projection (pre-scaled)
    bf16* Hbuf  = (bf16*)ws;                            // FFN1 out (aliases QKbf+VtG)
    ws += 16384L * 512 * 2;
    bf16* VtG   = (bf16*)ws; ws += 16384L * 512 * 2;   // v proj transposed [512][16384]
    bf16* Wqkv  = (bf16*)ws; ws += 1024L * 512 * 2;    // [Wqk; Wv] bf16
    bf16* Wbig  = (bf16*)ws; ws += 1024L * 1024 * 2;   // [Wf1L | Wcomb]
    bf16* Wf1Rb = (bf16*)ws; ws += 1024L * 512 * 2;
    bf16* Wf2b  = (bf16*)ws; ws += 512L * 1024 * 2;
    bf16* WoT   = (bf16*)ws; ws += 512L * 512 * 2;
    float* bf1p = (float*)ws; ws += 1024 * 4;

    // sqrt((1/8) * log2(e)) — applied to both q and k so scores carry (1/8)*log2(e)
    const float qs = 0.42466090014400953f;

    prep<<<10560, 256, 0, stream>>>(x0, x1, Xbf, Wqk, Wv, Wf1, Wf2,
                                    Wqkv, Wbig, Wf1Rb, Wf2b, Wo, WoT, bo, bf1, bf1p);

    // Wcomb = Wf1R @ Wo -> Wbig right half  [1024,512] = Wf1Rb @ WoT^T
    gemm_bt<4><<<32, 256, 0, stream>>>(Wf1Rb, 512, WoT, 512, nullptr,
                                       Wbig + 512, 1024, nullptr, nullptr,
                                       nullptr, nullptr, 1024, 512, 512, 1.f);

    // fused QKV projection: [16384,1024] = Xbf @ Wqkv^T (256x256, 16 waves)
    pipe_gemm<5><<<256, 1024, 0, stream>>>(Xbf, 1024, Wqkv, 512, bqk,
                                           QKbf, 512, bv, VtG,
                                           16384, 1024, 512, qs);

    // cross attention -> writes m-heads directly into Xbf right half (ld 1024)
    flash_attn<<<1024, 256, 0, stream>>>(QKbf, VtG, Xbf + 512);

    // FFN1 (Wo folded): [16384,1024] = [x|O] @ [Wf1L|Wcomb]^T + bf1'
    pipe_gemm<0><<<256, 1024, 0, stream>>>(Xbf, 1024, Wbig, 1024, bf1p,
                                           Hbuf, 1024, nullptr, nullptr,
                                           16384, 1024, 1024, 1.f);
    ln_gelu<<<16384, 256, 0, stream>>>(Hbuf, lng, lnb);
    // FFN2 + bias + residual -> d_out (fp32), BM=128 BN=256, 16 waves
    pipe_ffn2<<<256, 1024, 0, stream>>>(Hbuf, 1024, Wf2b, 1024, bf2,
                                        (float*)d_out, 512, x0, x1,
                                        16384, 512, 1024);
}

// Round 14
// 297.596 us; speedup vs baseline: 1.2121x; 1.0455x over previous
//
#include <hip/hip_runtime.h>
#include <hip/hip_bf16.h>
#include <math.h>

typedef __bf16 bf16;
typedef __bf16 bf16x8 __attribute__((ext_vector_type(8)));
typedef __bf16 bf16x4 __attribute__((ext_vector_type(4)));
typedef float  f32x4  __attribute__((ext_vector_type(4)));
typedef float  f32x16 __attribute__((ext_vector_type(16)));
typedef unsigned int u32x2 __attribute__((ext_vector_type(2)));

#define DEVI __device__ __forceinline__

DEVI void async16(bf16* lds, const bf16* g) {
    __builtin_amdgcn_global_load_lds(
        (const __attribute__((address_space(1))) unsigned int*)g,
        (__attribute__((address_space(3))) unsigned int*)lds, 16, 0, 0);
}
DEVI f32x4 mfma16(bf16x8 a, bf16x8 b, f32x4 c) {
    return __builtin_amdgcn_mfma_f32_16x16x32_bf16(a, b, c, 0, 0, 0);
}
DEVI f32x16 mfma32(bf16x8 a, bf16x8 b, f32x16 c) {
    return __builtin_amdgcn_mfma_f32_32x32x16_bf16(a, b, c, 0, 0, 0);
}
DEVI unsigned cvtpk(float lo, float hi) {
    unsigned r;
    asm("v_cvt_pk_bf16_f32 %0, %1, %2" : "=v"(r) : "v"(lo), "v"(hi));
    return r;
}
// v_permlane32_swap_b32: a' = [a.lo32, b.lo32], b' = [a.hi32, b.hi32]
DEVI void pl32(unsigned &a, unsigned &b) {
    u32x2 r = __builtin_amdgcn_permlane32_swap(a, b, false, false);
    a = r.x; b = r.y;
}
DEVI bf16x8 mk8(unsigned a0, unsigned a1, unsigned b0, unsigned b1) {
    union { unsigned u[4]; bf16x8 v; } U;
    U.u[0] = a0; U.u[1] = a1; U.u[2] = b0; U.u[3] = b1;
    return U.v;
}
// Abramowitz-Stegun 7.1.26 erf, |err| <= 1.5e-7 (vs libm branchy erff)
DEVI float erf_fast(float x) {
    float ax = fabsf(x);
    float t = 1.f / (1.f + 0.3275911f * ax);
    float y = t * (0.254829592f +
              t * (-0.284496736f +
              t * (1.421413741f +
              t * (-1.453152027f + t * 1.061405429f))));
    float e = __expf(-ax * ax);
    float r = 1.f - y * e;
    return (x < 0.f) ? -r : r;
}

// ---------------- fused prep: cvt_x + cvt_w + wo_t + bias_comb ----------------
__global__ __launch_bounds__(256) void prep(
    const float* __restrict__ x0, const float* __restrict__ x1, bf16* __restrict__ Xbf,
    const float* __restrict__ Wqk, const float* __restrict__ Wv,
    const float* __restrict__ Wf1, const float* __restrict__ Wf2,
    bf16* __restrict__ Wqkv, bf16* __restrict__ Wbig, bf16* __restrict__ Wf1Rb,
    bf16* __restrict__ Wf2b,
    const float* __restrict__ Wo, bf16* __restrict__ WoT,
    const float* __restrict__ bo, const float* __restrict__ bf1,
    float* __restrict__ bf1p)
{
    __shared__ float Ls[64][65];
    const int bid = blockIdx.x, t = threadIdx.x;
    if (bid < 8192) {
        long i = (long)bid * 256 + t;
        long r = i >> 7, c = (i & 127) * 4;
        const float* src = (r < 8192) ? (x0 + r * 512 + c) : (x1 + (r - 8192) * 512 + c);
        float4 v = *(const float4*)src;
        bf16x4 o;
        o[0] = (bf16)v.x; o[1] = (bf16)v.y; o[2] = (bf16)v.z; o[3] = (bf16)v.w;
        *(bf16x4*)(Xbf + r * 1024 + c) = o;
    } else if (bid < 10240) {
        long i = (long)(bid - 8192) * 256 + t;
        const float* s; bf16* d;
        if (i < 131072) {
            s = (i < 65536) ? Wqk + i * 4 : Wv + (i - 65536) * 4;
            d = Wqkv + i * 4;
        } else if (i < 393216) {
            long e = (i - 131072) * 4, r = e >> 10, c = e & 1023;
            s = Wf1 + e;
            d = (c < 512) ? (Wbig + r * 1024 + c) : (Wf1Rb + r * 512 + (c - 512));
        } else {
            s = Wf2 + (i - 393216) * 4;
            d = Wf2b + (i - 393216) * 4;
        }
        float4 v = *(const float4*)s;
        bf16x4 o;
        o[0] = (bf16)v.x; o[1] = (bf16)v.y; o[2] = (bf16)v.z; o[3] = (bf16)v.w;
        *(bf16x4*)d = o;
    } else if (bid < 10304) {
        const int bb = bid - 10240;
        const int bi = bb & 7, bj = bb >> 3;
        const int i0 = bi * 64, j0 = bj * 64;
        const int r0 = t >> 4, c4 = (t & 15) * 4;
#pragma unroll
        for (int it = 0; it < 4; it++) {
            int row = r0 + 16 * it;
            float4 v = *(const float4*)(Wo + (long)(i0 + row) * 512 + j0 + c4);
            Ls[row][c4] = v.x; Ls[row][c4 + 1] = v.y;
            Ls[row][c4 + 2] = v.z; Ls[row][c4 + 3] = v.w;
        }
        __syncthreads();
#pragma unroll
        for (int it = 0; it < 4; it++) {
            int orow = r0 + 16 * it;
            bf16x4 o;
#pragma unroll
            for (int k = 0; k < 4; k++) o[k] = (bf16)Ls[c4 + k][orow];
            *(bf16x4*)(WoT + (long)(j0 + orow) * 512 + i0 + c4) = o;
        }
    } else {
        const int w = t >> 6, lane = t & 63;
        const int row = (bid - 10304) * 4 + w;
        const float* rp = Wf1 + (long)row * 1024 + 512 + lane * 8;
        float4 a = *(const float4*)rp;
        float4 b = *(const float4*)(rp + 4);
        const float* bp = bo + lane * 8;
        float4 c = *(const float4*)bp;
        float4 d = *(const float4*)(bp + 4);
        float s = a.x * c.x + a.y * c.y + a.z * c.z + a.w * c.w +
                  b.x * d.x + b.y * d.y + b.z * d.z + b.w * d.w;
#pragma unroll
        for (int k = 1; k < 64; k <<= 1) s += __shfl_xor(s, k);
        if (lane == 0) bf1p[row] = bf1[row] + s;
    }
}

// ---------------- bf16 GEMM: C = A @ B^T, BK=64 swizzled (Wcomb only) ---------
template <int MODE>
__global__ __launch_bounds__(256) void gemm_bt(
    const bf16* __restrict__ A, long lda,
    const bf16* __restrict__ B, long ldb,
    const float* __restrict__ bias,
    void* __restrict__ Cout, long ldc,
    const float* __restrict__ res0, const float* __restrict__ res1,
    const float* __restrict__ bias2, void* __restrict__ Cout2,
    int M, int N, int K, float scale)
{
    __shared__ bf16 As[128 * 64];
    __shared__ bf16 Bs[128 * 64];
    const int t = threadIdx.x;
    const int w = t >> 6, lane = t & 63, quad = lane >> 4, m15 = lane & 15;
    const int wm = w >> 1, wn = w & 1;
    const int nbx = N >> 7;
    const int xcd = blockIdx.x & 7, local = blockIdx.x >> 3;
    const int mtiles_per_xcd = (int)(gridDim.x >> 3) / nbx;
    const int by = xcd * mtiles_per_xcd + local / nbx;
    const int bx = local % nbx;
    const long m0 = (long)by * 128, n0 = (long)bx * 128;

    f32x4 acc[4][4] = {};

    for (int k0 = 0; k0 < K; k0 += 64) {
#pragma unroll
        for (int i = 0; i < 4; i++) {
            int idx = i * 256 + t, row = idx >> 3, p = idx & 7;
            int gc = k0 + ((p ^ (row & 7)) * 8);
            async16(As + idx * 8, A + (m0 + row) * lda + gc);
            async16(Bs + idx * 8, B + (n0 + row) * ldb + gc);
        }
        __syncthreads();
#pragma unroll
        for (int kk = 0; kk < 2; kk++) {
            bf16x8 af[4], bfr[4];
#pragma unroll
            for (int mt = 0; mt < 4; mt++) {
                int row = wm * 64 + mt * 16 + m15;
                af[mt] = *(const bf16x8*)(As + row * 64 + (((kk * 4 + quad) ^ (row & 7)) * 8));
            }
#pragma unroll
            for (int nt = 0; nt < 4; nt++) {
                int row = wn * 64 + nt * 16 + m15;
                bfr[nt] = *(const bf16x8*)(Bs + row * 64 + (((kk * 4 + quad) ^ (row & 7)) * 8));
            }
#pragma unroll
            for (int mt = 0; mt < 4; mt++)
#pragma unroll
                for (int nt = 0; nt < 4; nt++)
                    acc[mt][nt] = mfma16(af[mt], bfr[nt], acc[mt][nt]);
        }
        __syncthreads();
    }

#pragma unroll
    for (int nt = 0; nt < 4; nt++) {
        long col = n0 + wn * 64 + nt * 16 + m15;
#pragma unroll
        for (int mt = 0; mt < 4; mt++) {
            long row = m0 + wm * 64 + mt * 16 + quad * 4;
            if (MODE == 4) {
                bf16* C = (bf16*)Cout;
#pragma unroll
                for (int r = 0; r < 4; r++)
                    C[(row + r) * ldc + col] = (bf16)acc[mt][nt][r];
            }
        }
    }
}

// ---------------- pipelined 256x256 GEMM: 16 waves, early stage issue ---------
// (r10-proven best GEMM config) 1024 threads = 16 waves (4M x 4N), BM=BN=256,
// BK=64, LDS 128 KiB (2 slots). 4 waves/SIMD hide vmcnt+barrier drains.
template <int MODE>
__global__ __launch_bounds__(1024, 4) void pipe_gemm(
    const bf16* __restrict__ A, long lda,
    const bf16* __restrict__ B, long ldb,
    const float* __restrict__ bias,
    void* __restrict__ Cout, long ldc,
    const float* __restrict__ bias2, void* __restrict__ Cout2,
    int M, int N, int K, float scale)
{
    __shared__ bf16 lds[65536];          // 128 KiB: As[2][16384] | Bs[2][16384]
    bf16* As = lds;
    bf16* Bs = lds + 32768;

    const int t = threadIdx.x;
    const int w = t >> 6, lane = t & 63, quad = lane >> 4, m15 = lane & 15;
    const int wm = w >> 2, wn = w & 3;           // 4 x 4 wave grid
    const int nbx = N >> 8;
    const int xcd = blockIdx.x & 7, local = blockIdx.x >> 3;
    const int mtiles_per_xcd = (int)(gridDim.x >> 3) / nbx;
    const int by = xcd * mtiles_per_xcd + local / nbx;
    const int bx = local % nbx;
    const long m0 = (long)by * 256, n0 = (long)bx * 256;
    const int nt = K >> 6;

    f32x4 acc[4][4] = {};

    // stage tile kt into slot kt&1: 4 async16/thread (2 A + 2 B)
    auto stage = [&](int kt) {
        const int slot = kt & 1;
        bf16* Ad = As + slot * 16384;
        bf16* Bd = Bs + slot * 16384;
        const int k0 = kt * 64;
#pragma unroll
        for (int i = 0; i < 2; i++) {
            int idx = i * 1024 + t, row = idx >> 3, p = idx & 7;
            int gc = k0 + ((p ^ (row & 7)) * 8);
            async16(Ad + idx * 8, A + (m0 + row) * lda + gc);
        }
#pragma unroll
        for (int i = 0; i < 2; i++) {
            int idx = i * 1024 + t, row = idx >> 3, p = idx & 7;
            int gc = k0 + ((p ^ (row & 7)) * 8);
            async16(Bd + idx * 8, B + (n0 + row) * ldb + gc);
        }
    };

    stage(0);
    stage(1);

    for (int kt = 0; kt < nt; kt++) {
        if (kt + 1 < nt) {
            asm volatile("s_waitcnt vmcnt(4)" ::: "memory");
        } else {
            asm volatile("s_waitcnt vmcnt(0)" ::: "memory");
        }
        __builtin_amdgcn_s_barrier();
        __builtin_amdgcn_sched_barrier(0);

        const bf16* Asl = As + (kt & 1) * 16384;
        const bf16* Bsl = Bs + (kt & 1) * 16384;

        // ---- ksub 0: reads + MFMA ----
        {
            bf16x8 af[4], bfr[4];
#pragma unroll
            for (int mf = 0; mf < 4; mf++) {
                int row = wm * 64 + mf * 16 + m15;
                af[mf] = *(const bf16x8*)(Asl + row * 64 + ((quad ^ (row & 7)) * 8));
            }
#pragma unroll
            for (int nf = 0; nf < 4; nf++) {
                int row = wn * 64 + nf * 16 + m15;
                bfr[nf] = *(const bf16x8*)(Bsl + row * 64 + ((quad ^ (row & 7)) * 8));
            }
            __builtin_amdgcn_s_setprio(1);
#pragma unroll
            for (int mf = 0; mf < 4; mf++)
#pragma unroll
                for (int nf = 0; nf < 4; nf++)
                    acc[mf][nf] = mfma16(af[mf], bfr[nf], acc[mf][nf]);
            __builtin_amdgcn_s_setprio(0);
        }

        // ---- ksub 1: reads, free the slot, early stage, MFMA ----
        {
            bf16x8 af[4], bfr[4];
#pragma unroll
            for (int mf = 0; mf < 4; mf++) {
                int row = wm * 64 + mf * 16 + m15;
                af[mf] = *(const bf16x8*)(Asl + row * 64 + (((4 + quad) ^ (row & 7)) * 8));
            }
#pragma unroll
            for (int nf = 0; nf < 4; nf++) {
                int row = wn * 64 + nf * 16 + m15;
                bfr[nf] = *(const bf16x8*)(Bsl + row * 64 + (((4 + quad) ^ (row & 7)) * 8));
            }
            asm volatile("s_waitcnt lgkmcnt(0)" ::: "memory");
            __builtin_amdgcn_sched_barrier(0);
            __builtin_amdgcn_s_barrier();     // all waves done reading this slot
            __builtin_amdgcn_sched_barrier(0);
            if (kt + 2 < nt) stage(kt + 2);   // overwrite slot while MFMA runs
            __builtin_amdgcn_s_setprio(1);
#pragma unroll
            for (int mf = 0; mf < 4; mf++)
#pragma unroll
                for (int nf = 0; nf < 4; nf++)
                    acc[mf][nf] = mfma16(af[mf], bfr[nf], acc[mf][nf]);
            __builtin_amdgcn_s_setprio(0);
        }
    }

#pragma unroll
    for (int nf = 0; nf < 4; nf++) {
        long col = n0 + wn * 64 + nf * 16 + m15;
#pragma unroll
        for (int mf = 0; mf < 4; mf++) {
            long row = m0 + wm * 64 + mf * 16 + quad * 4;
            if (MODE == 0) {
                bf16* C = (bf16*)Cout;
                float bs = bias[col];
#pragma unroll
                for (int r = 0; r < 4; r++)
                    C[(row + r) * ldc + col] = (bf16)(acc[mf][nf][r] + bs);
            } else {  // MODE 5
                if (col < 512) {
                    bf16* C = (bf16*)Cout;
                    float bs = bias[col];
#pragma unroll
                    for (int r = 0; r < 4; r++)
                        C[(row + r) * ldc + col] = (bf16)((acc[mf][nf][r] + bs) * scale);
                } else {
                    bf16* V = (bf16*)Cout2;
                    long v = col - 512;
                    float bs = bias2[v];
                    bf16x4 pv;
#pragma unroll
                    for (int r = 0; r < 4; r++) pv[r] = (bf16)(acc[mf][nf][r] + bs);
                    *(bf16x4*)(V + v * 16384 + row) = pv;
                }
            }
        }
    }
}

// ---------------- pipelined FFN2: BM=128 BN=256, 16 waves, fp32 out ----------
// (r10-proven) vmcnt(3) (stage = 1 A + 2 B per thread). Early-stage-issue.
__global__ __launch_bounds__(1024, 4) void pipe_ffn2(
    const bf16* __restrict__ A, long lda,
    const bf16* __restrict__ B, long ldb,
    const float* __restrict__ bias,
    float* __restrict__ C, long ldc,
    const float* __restrict__ res0, const float* __restrict__ res1,
    int M, int N, int K)
{
    __shared__ bf16 lds[49152];          // 96 KiB: As[2][8192] | Bs[2][16384]
    bf16* As = lds;                      // 128 x 64 per slot
    bf16* Bs = lds + 16384;              // 256 x 64 per slot

    const int t = threadIdx.x;
    const int w = t >> 6, lane = t & 63, quad = lane >> 4, m15 = lane & 15;
    const int wm = w >> 2, wn = w & 3;   // 4 x 4 wave grid
    const int nbx = N >> 8;              // 2
    const int xcd = blockIdx.x & 7, local = blockIdx.x >> 3;
    const int mtiles_per_xcd = (int)(gridDim.x >> 3) / nbx;
    const int by = xcd * mtiles_per_xcd + local / nbx;
    const int bx = local % nbx;
    const long m0 = (long)by * 128, n0 = (long)bx * 256;
    const int nt = K >> 6;

    f32x4 acc[2][4] = {};

    auto stage = [&](int kt) {
        const int slot = kt & 1;
        bf16* Ad = As + slot * 8192;
        bf16* Bd = Bs + slot * 16384;
        const int k0 = kt * 64;
        {
            int idx = t, row = idx >> 3, p = idx & 7;
            int gc = k0 + ((p ^ (row & 7)) * 8);
            async16(Ad + idx * 8, A + (m0 + row) * lda + gc);
        }
#pragma unroll
        for (int i = 0; i < 2; i++) {
            int idx = i * 1024 + t, row = idx >> 3, p = idx & 7;
            int gc = k0 + ((p ^ (row & 7)) * 8);
            async16(Bd + idx * 8, B + (n0 + row) * ldb + gc);
        }
    };

    stage(0);
    stage(1);

    for (int kt = 0; kt < nt; kt++) {
        if (kt + 1 < nt) {
            asm volatile("s_waitcnt vmcnt(3)" ::: "memory");
        } else {
            asm volatile("s_waitcnt vmcnt(0)" ::: "memory");
        }
        __builtin_amdgcn_s_barrier();
        __builtin_amdgcn_sched_barrier(0);

        const bf16* Asl = As + (kt & 1) * 8192;
        const bf16* Bsl = Bs + (kt & 1) * 16384;

        // ---- ksub 0 ----
        {
            bf16x8 af[2], bfr[4];
#pragma unroll
            for (int mf = 0; mf < 2; mf++) {
                int row = wm * 32 + mf * 16 + m15;
                af[mf] = *(const bf16x8*)(Asl + row * 64 + ((quad ^ (row & 7)) * 8));
            }
#pragma unroll
            for (int nf = 0; nf < 4; nf++) {
                int row = wn * 64 + nf * 16 + m15;
                bfr[nf] = *(const bf16x8*)(Bsl + row * 64 + ((quad ^ (row & 7)) * 8));
            }
            __builtin_amdgcn_s_setprio(1);
#pragma unroll
            for (int mf = 0; mf < 2; mf++)
#pragma unroll
                for (int nf = 0; nf < 4; nf++)
                    acc[mf][nf] = mfma16(af[mf], bfr[nf], acc[mf][nf]);
            __builtin_amdgcn_s_setprio(0);
        }

        // ---- ksub 1 with early stage issue ----
        {
            bf16x8 af[2], bfr[4];
#pragma unroll
            for (int mf = 0; mf < 2; mf++) {
                int row = wm * 32 + mf * 16 + m15;
                af[mf] = *(const bf16x8*)(Asl + row * 64 + (((4 + quad) ^ (row & 7)) * 8));
            }
#pragma unroll
            for (int nf = 0; nf < 4; nf++) {
                int row = wn * 64 + nf * 16 + m15;
                bfr[nf] = *(const bf16x8*)(Bsl + row * 64 + (((4 + quad) ^ (row & 7)) * 8));
            }
            asm volatile("s_waitcnt lgkmcnt(0)" ::: "memory");
            __builtin_amdgcn_sched_barrier(0);
            __builtin_amdgcn_s_barrier();
            __builtin_amdgcn_sched_barrier(0);
            if (kt + 2 < nt) stage(kt + 2);
            __builtin_amdgcn_s_setprio(1);
#pragma unroll
            for (int mf = 0; mf < 2; mf++)
#pragma unroll
                for (int nf = 0; nf < 4; nf++)
                    acc[mf][nf] = mfma16(af[mf], bfr[nf], acc[mf][nf]);
            __builtin_amdgcn_s_setprio(0);
        }
    }

#pragma unroll
    for (int nf = 0; nf < 4; nf++) {
        long col = n0 + wn * 64 + nf * 16 + m15;
        float bs = bias[col];
#pragma unroll
        for (int mf = 0; mf < 2; mf++) {
            long row = m0 + wm * 32 + mf * 16 + quad * 4;
#pragma unroll
            for (int r = 0; r < 4; r++) {
                long grow = row + r;
                const float* rs = (grow < 8192) ? (res0 + grow * 512)
                                                : (res1 + (grow - 8192) * 512);
                C[grow * ldc + col] = acc[mf][nf][r] + bs + rs[col];
            }
        }
    }
}

// ---------------- flash attention: 8 waves, QBLK=256, in-register P ----------
// r13 flash at 80.6us; this doubles q per K/V stage: 512 threads = 8 waves x
// 32 q = 256 q/block, grid 512 = 2 blocks/CU = 4 waves/SIMD (unchanged).
// Per-CU staging bytes / async issues / barriers HALVE; LDS reads, exp,
// MFMA per wave unchanged. K/V stage = exactly 1 async16/thread.
// LDS 32KiB: Q stage (full, reclaimed) -> K dbuf 2x8K | V dbuf 2x8K.
__global__ __launch_bounds__(512, 4) void flash_attn(const bf16* __restrict__ QK,
                                                     const bf16* __restrict__ VT,
                                                     bf16* __restrict__ o)
{
    __shared__ bf16 lds[16384];          // 32 KiB

    const int t = threadIdx.x, w = t >> 6, lane = t & 63;
    const int l31 = lane & 31, hi = lane >> 5;
    const int j = blockIdx.x;
    const int hs = j & 63;               // head-set id (shares K/V); +64 = same XCD
    const int qt = j >> 6;               // 0..7 q-tile (256 rows each)
    const int h = hs & 7, b = (hs >> 3) & 3, dir = hs >> 5;
    const long qrow0  = (long)dir * 8192 + b * 2048 + qt * 256;
    const long kvrow0 = (long)(1 - dir) * 8192 + b * 2048;
    const int hc = h * 64;

    // ---- Q stage: 256 rows x 64 d = 32KB into full LDS ----
#pragma unroll
    for (int i = 0; i < 4; i++) {
        int idx = i * 512 + t, row = idx >> 3, p = idx & 7;
        async16(lds + idx * 8, QK + (qrow0 + row) * 512 + hc + ((p ^ (row & 7)) * 8));
    }
    __syncthreads();
    bf16x8 qf[4];
    {
        int qrow = w * 32 + l31;         // w in 0..7 -> rows 0..255
#pragma unroll
        for (int kd = 0; kd < 4; kd++)
            qf[kd] = *(const bf16x8*)(lds + qrow * 64 + (((kd * 2 + hi) ^ (qrow & 7)) * 8));
    }
    __syncthreads();  // all Q reads done before K/V loads overwrite

    // ---- prologue: issue K(0), V(0) into buffer 0 (1 async16/thread each) ----
    {
        int row = t >> 3, p = t & 7;
        async16(lds + t * 8, QK + (kvrow0 + row) * 512 + hc + ((p ^ (row & 7)) * 8));
        async16(lds + 8192 + t * 8, VT + (long)(hc + row) * 16384 + kvrow0 + ((p ^ (row & 7)) * 8));
    }

    f32x16 oacc[2] = {};
    f32x16 racc = {};
    bf16x8 ones;
#pragma unroll
    for (int k = 0; k < 8; k++) ones[k] = (bf16)1.0f;

    for (int kb = 0; kb < 32; kb++) {
        bf16* Kc = lds + (kb & 1) * 4096;
        bf16* Vc = lds + 8192 + (kb & 1) * 4096;

        asm volatile("s_waitcnt vmcnt(0)" ::: "memory");
        __builtin_amdgcn_s_barrier();

        if (kb < 31) {
            const long knext = kvrow0 + (kb + 1) * 64;
            bf16* Kn = lds + ((kb + 1) & 1) * 4096;
            bf16* Vn = lds + 8192 + ((kb + 1) & 1) * 4096;
            int row = t >> 3, p = t & 7;
            async16(Kn + t * 8, QK + (knext + row) * 512 + hc + ((p ^ (row & 7)) * 8));
            async16(Vn + t * 8, VT + (long)(hc + row) * 16384 + knext + ((p ^ (row & 7)) * 8));
        }

#pragma unroll
        for (int kb2 = 0; kb2 < 2; kb2++) {
            const int krow = kb2 * 32 + l31;
            const int ksw = krow & 7;
            bf16x8 kf0 = *(const bf16x8*)(Kc + krow * 64 + (((0 + hi) ^ ksw) * 8));
            bf16x8 kf1 = *(const bf16x8*)(Kc + krow * 64 + (((2 + hi) ^ ksw) * 8));
            bf16x8 kf2 = *(const bf16x8*)(Kc + krow * 64 + (((4 + hi) ^ ksw) * 8));
            bf16x8 kf3 = *(const bf16x8*)(Kc + krow * 64 + (((6 + hi) ^ ksw) * 8));

            f32x16 s0 = {};
            __builtin_amdgcn_s_setprio(1);
            s0 = mfma32(kf0, qf[0], s0);
            s0 = mfma32(kf1, qf[1], s0);
            s0 = mfma32(kf2, qf[2], s0);
            s0 = mfma32(kf3, qf[3], s0);
            __builtin_amdgcn_s_setprio(0);

#pragma unroll
            for (int r = 0; r < 16; r++) s0[r] = __builtin_amdgcn_exp2f(s0[r]);

#pragma unroll
            for (int sh = 0; sh < 2; sh++) {
                const int ks = kb2 * 2 + sh;
                unsigned a00 = cvtpk(s0[8 * sh + 0], s0[8 * sh + 1]);
                unsigned a01 = cvtpk(s0[8 * sh + 2], s0[8 * sh + 3]);
                unsigned b00 = cvtpk(s0[8 * sh + 4], s0[8 * sh + 5]);
                unsigned b01 = cvtpk(s0[8 * sh + 6], s0[8 * sh + 7]);
                pl32(a00, b00); pl32(a01, b01);
                bf16x8 pa0 = mk8(a00, a01, b00, b01);

                __builtin_amdgcn_s_setprio(1);
#pragma unroll
                for (int db = 0; db < 2; db++) {
                    const int vrow = db * 32 + l31;
                    bf16x8 vf = *(const bf16x8*)(Vc + vrow * 64 + (((ks * 2 + hi) ^ (vrow & 7)) * 8));
                    oacc[db] = mfma32(pa0, vf, oacc[db]);
                }
                racc = mfma32(pa0, ones, racc);
                __builtin_amdgcn_s_setprio(0);
            }
        }
    }

#pragma unroll
    for (int reg = 0; reg < 16; reg++) {
        const int q = (reg & 3) + 8 * (reg >> 2) + 4 * hi;
        const float inv = __builtin_amdgcn_rcpf(racc[reg]);
        const long row = qrow0 + w * 32 + q;
#pragma unroll
        for (int db = 0; db < 2; db++)
            o[row * 1024 + hc + db * 32 + l31] = (bf16)(oacc[db][reg] * inv);
    }
}

// ---------------- LayerNorm + GELU (fast erf), in-place on bf16 [16384][1024]
__global__ __launch_bounds__(256) void ln_gelu(bf16* __restrict__ H,
                                               const float* __restrict__ g,
                                               const float* __restrict__ bta)
{
    const int row = blockIdx.x, t = threadIdx.x;
    const int w = t >> 6, lane = t & 63;
    bf16* hp = H + (long)row * 1024 + t * 4;
    bf16x4 hv = *(const bf16x4*)hp;
    float h[4];
#pragma unroll
    for (int j = 0; j < 4; j++) h[j] = (float)hv[j];
    float s1 = h[0] + h[1] + h[2] + h[3];
    float s2 = h[0] * h[0] + h[1] * h[1] + h[2] * h[2] + h[3] * h[3];
#pragma unroll
    for (int d = 1; d < 64; d <<= 1) {
        s1 += __shfl_xor(s1, d);
        s2 += __shfl_xor(s2, d);
    }
    __shared__ float rbuf[8];
    if (lane == 0) { rbuf[w] = s1; rbuf[4 + w] = s2; }
    __syncthreads();
    s1 = rbuf[0] + rbuf[1] + rbuf[2] + rbuf[3];
    s2 = rbuf[4] + rbuf[5] + rbuf[6] + rbuf[7];
    const float mu = s1 * (1.f / 1024.f);
    const float var = s2 * (1.f / 1024.f) - mu * mu;
    const float rstd = rsqrtf(var + 1e-5f);
    bf16x4 out;
#pragma unroll
    for (int j = 0; j < 4; j++) {
        int c = t * 4 + j;
        float x = (h[j] - mu) * rstd * g[c] + bta[c];
        float y = 0.5f * x * (1.f + erf_fast(x * 0.70710678118654752f));
        out[j] = (bf16)y;
    }
    *(bf16x4*)hp = out;
}

extern "C" void kernel_launch(void* const* d_in, const int* in_sizes, int n_in,
                              void* d_out, int out_size, void* d_ws, size_t ws_size,
                              hipStream_t stream)
{
    const float* x0  = (const float*)d_in[0];
    const float* x1  = (const float*)d_in[1];
    const float* Wqk = (const float*)d_in[2];
    const float* bqk = (const float*)d_in[3];
    const float* Wv  = (const float*)d_in[4];
    const float* bv  = (const float*)d_in[5];
    const float* Wo  = (const float*)d_in[6];
    const float* bo  = (const float*)d_in[7];
    const float* Wf1 = (const float*)d_in[8];
    const float* bf1 = (const float*)d_in[9];
    const float* lng = (const float*)d_in[10];
    const float* lnb = (const float*)d_in[11];
    const float* Wf2 = (const float*)d_in[12];
    const float* bf2 = (const float*)d_in[13];

    char* ws = (char*)d_ws;
    bf16* Xbf   = (bf16*)ws; ws += 16384L * 1024 * 2;  // [x | m] both streams
    bf16* QKbf  = (bf16*)ws;                            // qk projection (pre-scaled)
    bf16* Hbuf  = (bf16*)ws;                            // FFN1 out (aliases QKbf+VtG)
    ws += 16384L * 512 * 2;
    bf16* VtG   = (bf16*)ws; ws += 16384L * 512 * 2;   // v proj transposed [512][16384]
    bf16* Wqkv  = (bf16*)ws; ws += 1024L * 512 * 2;    // [Wqk; Wv] bf16
    bf16* Wbig  = (bf16*)ws; ws += 1024L * 1024 * 2;   // [Wf1L | Wcomb]
    bf16* Wf1Rb = (bf16*)ws; ws += 1024L * 512 * 2;
    bf16* Wf2b  = (bf16*)ws; ws += 512L * 1024 * 2;
    bf16* WoT   = (bf16*)ws; ws += 512L * 512 * 2;
    float* bf1p = (float*)ws; ws += 1024 * 4;

    // sqrt((1/8) * log2(e)) — applied to both q and k so scores carry (1/8)*log2(e)
    const float qs = 0.42466090014400953f;

    prep<<<10560, 256, 0, stream>>>(x0, x1, Xbf, Wqk, Wv, Wf1, Wf2,
                                    Wqkv, Wbig, Wf1Rb, Wf2b, Wo, WoT, bo, bf1, bf1p);

    // Wcomb = Wf1R @ Wo -> Wbig right half  [1024,512] = Wf1Rb @ WoT^T
    gemm_bt<4><<<32, 256, 0, stream>>>(Wf1Rb, 512, WoT, 512, nullptr,
                                       Wbig + 512, 1024, nullptr, nullptr,
                                       nullptr, nullptr, 1024, 512, 512, 1.f);

    // fused QKV projection: [16384,1024] = Xbf @ Wqkv^T (256x256, 16 waves)
    pipe_gemm<5><<<256, 1024, 0, stream>>>(Xbf, 1024, Wqkv, 512, bqk,
                                           QKbf, 512, bv, VtG,
                                           16384, 1024, 512, qs);

    // cross attention -> writes m-heads directly into Xbf right half (ld 1024)
    flash_attn<<<512, 512, 0, stream>>>(QKbf, VtG, Xbf + 512);

    // FFN1 (Wo folded): [16384,1024] = [x|O] @ [Wf1L|Wcomb]^T + bf1'
    pipe_gemm<0><<<256, 1024, 0, stream>>>(Xbf, 1024, Wbig, 1024, bf1p,
                                           Hbuf, 1024, nullptr, nullptr,
                                           16384, 1024, 1024, 1.f);
    ln_gelu<<<16384, 256, 0, stream>>>(Hbuf, lng, lnb);
    // FFN2 + bias + residual -> d_out (fp32), BM=128 BN=256, 16 waves
    pipe_ffn2<<<256, 1024, 0, stream>>>(Hbuf, 1024, Wf2b, 1024, bf2,
                                        (float*)d_out, 512, x0, x1,
                                        16384, 512, 1024);
}